// Round 1
// baseline (3381.621 us; speedup 1.0000x reference)
//
#include <hip/hip_runtime.h>
#include <cstdint>

#define D_   128
#define H_   4
#define C_   3
#define G_   512
#define INF_ 74
#define EF_  11
#define T_   4   // GRU sequence length = C_+1

// ---------------------------------------------------------------------------
// Generic f32 GEMM: C[M,128] = A[M,K] @ B[K,128] (+bias). Per-blockIdx.y
// element offsets allow batching over heads. Tile: 64 rows x 128 cols,
// 256 threads, K-tiles of 16 staged in LDS (padded to 68 -> 2-way max).
// ---------------------------------------------------------------------------
__global__ __launch_bounds__(256) void k_gemm(
    const float* __restrict__ A, int lda, int aOff,
    const float* __restrict__ B, int bOff,
    float* __restrict__ C, int ldc, int cOff,
    int M, int K, const float* __restrict__ bias)
{
  A += (size_t)blockIdx.y * aOff;
  B += (size_t)blockIdx.y * bOff;
  C += (size_t)blockIdx.y * cOff;
  __shared__ float As[16][68];
  const int col = threadIdx.x & 127;
  const int rh  = threadIdx.x >> 7;      // 0/1 (row half)
  const int rowBase = blockIdx.x * 64;
  float acc[32];
#pragma unroll
  for (int i = 0; i < 32; i++) acc[i] = 0.f;

  for (int k0 = 0; k0 < K; k0 += 16) {
    const int t = threadIdx.x;
#pragma unroll
    for (int j = 0; j < 4; j++) {
      int idx = t + j * 256;             // 0..1023
      int r = idx >> 4, kk = idx & 15;
      int gr = rowBase + r, gk = k0 + kk;
      float v = 0.f;
      if (gr < M && gk < K) v = A[(size_t)gr * lda + gk];
      As[kk][r] = v;
    }
    __syncthreads();
    const int kmax = (K - k0 < 16) ? (K - k0) : 16;
    for (int kk = 0; kk < kmax; kk++) {
      float w = B[(size_t)(k0 + kk) * 128 + col];
#pragma unroll
      for (int i = 0; i < 8; i++) {
        float4 a4 = *(const float4*)&As[kk][rh * 32 + i * 4];
        acc[i * 4 + 0] += a4.x * w;
        acc[i * 4 + 1] += a4.y * w;
        acc[i * 4 + 2] += a4.z * w;
        acc[i * 4 + 3] += a4.w * w;
      }
    }
    __syncthreads();
  }
  float bv = bias ? bias[col] : 0.f;
#pragma unroll
  for (int i = 0; i < 32; i++) {
    int r = rowBase + rh * 32 + i;
    if (r < M) C[(size_t)r * ldc + col] = acc[i] + bv;
  }
}

// ---------------------------------------------------------------------------
// CSR build (by dst)
// ---------------------------------------------------------------------------
__global__ void k_hist(const int* __restrict__ dst, int* __restrict__ deg, int E)
{
  int e = blockIdx.x * blockDim.x + threadIdx.x;
  if (e < E) atomicAdd(&deg[dst[e]], 1);
}

__global__ __launch_bounds__(1024) void k_scan(const int* __restrict__ deg,
                                               int* __restrict__ rowp, int N)
{
  __shared__ int part[1024];
  int t = threadIdx.x;
  int chunk = (N + 1023) / 1024;
  int base = t * chunk;
  int s = 0;
  for (int i = 0; i < chunk; i++) { int idx = base + i; if (idx < N) s += deg[idx]; }
  part[t] = s;
  __syncthreads();
  for (int off = 1; off < 1024; off <<= 1) {
    int v = (t >= off) ? part[t - off] : 0;
    __syncthreads();
    part[t] += v;
    __syncthreads();
  }
  int run = part[t] - s;                  // exclusive prefix
  for (int i = 0; i < chunk; i++) {
    int idx = base + i;
    if (idx < N) { rowp[idx] = run; run += deg[idx]; }
  }
  if (t == 1023) rowp[N] = part[1023];
}

__global__ void k_fill(const int* __restrict__ dst, const int* __restrict__ rowp,
                       int* __restrict__ cursor, int* __restrict__ eids, int E)
{
  int e = blockIdx.x * blockDim.x + threadIdx.x;
  if (e < E) {
    int d = dst[e];
    int pos = atomicAdd(&cursor[d], 1);
    eids[rowp[d] + pos] = e;
  }
}

// ---------------------------------------------------------------------------
// Folded small weights: WeQ/WeK/WeV = We @ W{q,k,v}  [11,128] each,
// M2 = WeQ @ WeK^T [11,11]. One block per (layer,head).
// ---------------------------------------------------------------------------
__global__ __launch_bounds__(128) void k_small(
    const float* __restrict__ WeW, const float* __restrict__ WqW,
    const float* __restrict__ WkW, const float* __restrict__ WvW,
    float* __restrict__ WeQ, float* __restrict__ WeK, float* __restrict__ WeV,
    float* __restrict__ M2)
{
  int ch = blockIdx.x;                    // c*H_+h
  const float* We = WeW + (size_t)ch * EF_ * 128;
  const float* Wq = WqW + (size_t)ch * 128 * 128;
  const float* Wk = WkW + (size_t)ch * 128 * 128;
  const float* Wv = WvW + (size_t)ch * 128 * 128;
  __shared__ float sWe[EF_ * 128], sQ[EF_ * 128], sK[EF_ * 128];
  int d = threadIdx.x;
  for (int i = d; i < EF_ * 128; i += 128) sWe[i] = We[i];
  __syncthreads();
  for (int f = 0; f < EF_; f++) {
    float aq = 0.f, ak = 0.f, av = 0.f;
    for (int k = 0; k < 128; k++) {
      float w = sWe[f * 128 + k];
      aq += w * Wq[k * 128 + d];
      ak += w * Wk[k * 128 + d];
      av += w * Wv[k * 128 + d];
    }
    WeQ[(size_t)ch * EF_ * 128 + f * 128 + d] = aq;
    WeK[(size_t)ch * EF_ * 128 + f * 128 + d] = ak;
    WeV[(size_t)ch * EF_ * 128 + f * 128 + d] = av;
    sQ[f * 128 + d] = aq;
    sK[f * 128 + d] = ak;
  }
  __syncthreads();
  if (d < EF_ * EF_) {
    int a = d / EF_, b = d % EF_;
    float s = 0.f;
    for (int k = 0; k < 128; k++) s += sQ[a * 128 + k] * sK[b * 128 + k];
    M2[(size_t)ch * (EF_ * EF_) + d] = s;
  }
}

// ---------------------------------------------------------------------------
// Per-edge (e,e) attention logit: ee = e_f^T M2 e_f for all layers/heads.
// grid (ceil(E/64), C_), block 256 = 64 edges x 4 heads.
// ---------------------------------------------------------------------------
__global__ __launch_bounds__(256) void k_ee(
    const float* __restrict__ e_f, const float* __restrict__ M2,
    float* __restrict__ eeS, int E)
{
  int layer = blockIdx.y;
  int e0 = blockIdx.x * 64;
  __shared__ float efs[64 * EF_];
  int t = threadIdx.x;
  for (int i = t; i < 64 * EF_; i += 256) {
    int gidx = e0 * EF_ + i;
    efs[i] = (gidx < E * EF_) ? e_f[gidx] : 0.f;
  }
  __syncthreads();
  int el = t >> 2, h = t & 3;
  int e = e0 + el;
  if (e < E) {
    const float* m2 = M2 + (size_t)(layer * H_ + h) * (EF_ * EF_);
    const float* ef = &efs[el * EF_];
    float s = 0.f;
    for (int a = 0; a < EF_; a++) {
      float ss = 0.f;
      for (int b = 0; b < EF_; b++) ss += m2[a * EF_ + b] * ef[b];
      s += ef[a] * ss;
    }
    eeS[((size_t)layer * E + e) * H_ + h] = s;
  }
}

// ---------------------------------------------------------------------------
// B = Zq @ WeK^T, C = Zk @ WeQ^T  -> [N*H, 11]. One wave per (node, head).
// ---------------------------------------------------------------------------
__global__ __launch_bounds__(256) void k_bc(
    const float* __restrict__ Zq, const float* __restrict__ Zk,
    const float* __restrict__ WeQ, const float* __restrict__ WeK,
    float* __restrict__ Bm, float* __restrict__ Cm, int N, int layer)
{
  int wave = threadIdx.x >> 6, lane = threadIdx.x & 63;
  int task = blockIdx.x * 4 + wave;       // n*H_+h
  int n = task >> 2, h = task & 3;
  if (n >= N) return;
  size_t nb = (size_t)n * 512 + h * 128 + 2 * lane;
  float2 zq = *(const float2*)&Zq[nb];
  float2 zk = *(const float2*)&Zk[nb];
  const float* wq = WeQ + (size_t)(layer * H_ + h) * EF_ * 128;
  const float* wk = WeK + (size_t)(layer * H_ + h) * EF_ * 128;
  for (int f = 0; f < EF_; f++) {
    float2 a = *(const float2*)&wk[f * 128 + 2 * lane];
    float2 b = *(const float2*)&wq[f * 128 + 2 * lane];
    float pb = zq.x * a.x + zq.y * a.y;
    float pc = zk.x * b.x + zk.y * b.y;
#pragma unroll
    for (int m = 32; m; m >>= 1) {
      pb += __shfl_xor(pb, m, 64);
      pc += __shfl_xor(pc, m, 64);
    }
    if (lane == 0) {
      Bm[(size_t)task * EF_ + f] = pb;
      Cm[(size_t)task * EF_ + f] = pc;
    }
  }
}

// ---------------------------------------------------------------------------
// Edge aggregation, fused: per (dst,head) wave -> 3x3 attention softmax,
// weighted message, mean over in-edges, ReLU, LayerNorm. No atomics.
// ---------------------------------------------------------------------------
__global__ __launch_bounds__(256) void k_edge(
    const float* __restrict__ Zq, const float* __restrict__ Zk,
    const float* __restrict__ Zv, const float* __restrict__ Bm,
    const float* __restrict__ Cm, const float* __restrict__ eeS,
    const float* __restrict__ e_f, const int* __restrict__ rowp,
    const int* __restrict__ eids, const int* __restrict__ srcI,
    const float* __restrict__ WeV, const float* __restrict__ lng,
    const float* __restrict__ lnb, float* __restrict__ heads,
    int N, int E, int layer)
{
  int h = threadIdx.x >> 6, lane = threadIdx.x & 63;
  int n = blockIdx.x;
  size_t nb = (size_t)n * 512 + h * 128 + 2 * lane;
  float2 zq_d = *(const float2*)&Zq[nb];
  float2 zk_d = *(const float2*)&Zk[nb];
  float2 zv_d = *(const float2*)&Zv[nb];
  float Bd = 0.f, Cd = 0.f;
  if (lane < EF_) {
    Bd = Bm[(size_t)(n * H_ + h) * EF_ + lane];
    Cd = Cm[(size_t)(n * H_ + h) * EF_ + lane];
  }
  float dd = zq_d.x * zk_d.x + zq_d.y * zk_d.y;
#pragma unroll
  for (int m = 32; m; m >>= 1) dd += __shfl_xor(dd, m, 64);

  int beg = rowp[n], end = rowp[n + 1];
  float accx = 0.f, accy = 0.f, wdsum = 0.f, a11 = 0.f;

  for (int idx = beg; idx < end; idx++) {
    int e = eids[idx];
    int s = srcI[e];
    size_t sb = (size_t)s * 512 + h * 128 + 2 * lane;
    float2 zq_s = *(const float2*)&Zq[sb];
    float2 zk_s = *(const float2*)&Zk[sb];
    float2 zv_s = *(const float2*)&Zv[sb];
    float efl = 0.f, Bs = 0.f, Cs = 0.f;
    if (lane < EF_) {
      efl = e_f[(size_t)e * EF_ + lane];
      Bs = Bm[(size_t)(s * H_ + h) * EF_ + lane];
      Cs = Cm[(size_t)(s * H_ + h) * EF_ + lane];
    }
    float v[7];
    v[0] = zq_s.x * zk_s.x + zq_s.y * zk_s.y;   // (s,s)
    v[1] = zq_s.x * zk_d.x + zq_s.y * zk_d.y;   // (s,d)
    v[2] = zq_d.x * zk_s.x + zq_d.y * zk_s.y;   // (d,s)
    v[3] = Bs * efl;                            // (s,e)
    v[4] = Cs * efl;                            // (e,s)
    v[5] = Bd * efl;                            // (d,e)
    v[6] = Cd * efl;                            // (e,d)
#pragma unroll
    for (int m = 32; m; m >>= 1)
#pragma unroll
      for (int i = 0; i < 7; i++) v[i] += __shfl_xor(v[i], m, 64);

    float ee = eeS[((size_t)layer * E + e) * H_ + h];
    // S rows: [src,dst,e] x cols [src,dst,e]
    float S00 = v[0], S01 = v[1], S02 = v[3];
    float S10 = v[2], S11 = dd,   S12 = v[5];
    float S20 = v[4], S21 = v[6], S22 = ee;
    float m0 = fmaxf(fmaxf(S00, S01), S02);
    float e00 = __expf(S00 - m0), e01 = __expf(S01 - m0), e02 = __expf(S02 - m0);
    float i0 = 1.f / (e00 + e01 + e02);
    float m1 = fmaxf(fmaxf(S10, S11), S12);
    float e10 = __expf(S10 - m1), e11 = __expf(S11 - m1), e12 = __expf(S12 - m1);
    float i1 = 1.f / (e10 + e11 + e12);
    float m2r = fmaxf(fmaxf(S20, S21), S22);
    float e20 = __expf(S20 - m2r), e21 = __expf(S21 - m2r), e22 = __expf(S22 - m2r);
    float i2 = 1.f / (e20 + e21 + e22);
    float w0 = e00 * i0 + e10 * i1 + e20 * i2;   // -> V_src
    float w1 = e01 * i0 + e11 * i1 + e21 * i2;   // -> V_dst
    float w2 = e02 * i0 + e12 * i1 + e22 * i2;   // -> V_e

    accx += w0 * zv_s.x;
    accy += w0 * zv_s.y;
    wdsum += w1;
    a11 += w2 * efl;                             // lanes >= 11 add 0
  }

  float mx = accx + wdsum * zv_d.x;
  float my = accy + wdsum * zv_d.y;
  const float* wv = WeV + (size_t)(layer * H_ + h) * EF_ * 128;
#pragma unroll
  for (int f = 0; f < EF_; f++) {
    float af = __shfl(a11, f, 64);
    float2 w = *(const float2*)&wv[f * 128 + 2 * lane];
    mx += af * w.x;
    my += af * w.y;
  }
  int cnt = end - beg;
  float invc = 1.f / (float)(cnt > 0 ? cnt : 1);
  mx = fmaxf(mx * invc, 0.f);
  my = fmaxf(my * invc, 0.f);
  // LayerNorm over 128
  float s1 = mx + my;
#pragma unroll
  for (int m = 32; m; m >>= 1) s1 += __shfl_xor(s1, m, 64);
  float mean = s1 * (1.f / 128.f);
  float dx = mx - mean, dy = my - mean;
  float s2 = dx * dx + dy * dy;
#pragma unroll
  for (int m = 32; m; m >>= 1) s2 += __shfl_xor(s2, m, 64);
  float rstd = rsqrtf(s2 * (1.f / 128.f) + 1e-5f);
  int gi = (layer * H_ + h) * 128 + 2 * lane;
  float2 g2 = *(const float2*)&lng[gi];
  float2 b2 = *(const float2*)&lnb[gi];
  float2 outv;
  outv.x = dx * rstd * g2.x + b2.x;
  outv.y = dy * rstd * g2.y + b2.y;
  *(float2*)&heads[nb] = outv;
}

// ---------------------------------------------------------------------------
// Segment mean by graph id (node_gid sorted): one block per graph.
// ---------------------------------------------------------------------------
__global__ void k_gmean(const float* __restrict__ X, const int* __restrict__ gid,
                        float* __restrict__ outp, int N, int ld)
{
  int g = blockIdx.x;
  int lo = 0, hi = N;
  while (lo < hi) { int m = (lo + hi) >> 1; if (gid[m] < g) lo = m + 1; else hi = m; }
  int s0 = lo;
  lo = s0; hi = N;
  while (lo < hi) { int m = (lo + hi) >> 1; if (gid[m] < g + 1) lo = m + 1; else hi = m; }
  int s1 = lo;
  float inv = 1.f / (float)((s1 - s0) > 0 ? (s1 - s0) : 1);
  for (int d = threadIdx.x; d < ld; d += blockDim.x) {
    float s = 0.f;
    for (int n = s0; n < s1; n++) s += X[(size_t)n * ld + d];
    outp[(size_t)g * ld + d] = s * inv;
  }
}

// ---------------------------------------------------------------------------
// GRU (one direction-layer pass): block = (graph, dir), 128 threads.
// seq: [T, G, inDim]. yout (optional): [T, G, 256] written at dir*128.
// hfinal: [2, G, 128].
// ---------------------------------------------------------------------------
__global__ __launch_bounds__(128) void k_gru(
    const float* __restrict__ seq, int inDim,
    const float* __restrict__ Wih, const float* __restrict__ Whh,
    const float* __restrict__ bih, const float* __restrict__ bhh,
    float* __restrict__ yout, float* __restrict__ hfinal)
{
  int g = blockIdx.x, dir = blockIdx.y, d = threadIdx.x;
  const float* Wih_d = Wih + (size_t)dir * inDim * 384;
  const float* Whh_d = Whh + (size_t)dir * 128 * 384;
  const float* bih_d = bih + dir * 384;
  const float* bhh_d = bhh + dir * 384;
  __shared__ float xb[256];
  __shared__ float hb[128];
  float h = 0.f;
  for (int st = 0; st < T_; st++) {
    int t = dir ? (T_ - 1 - st) : st;
    for (int k = d; k < inDim; k += 128) xb[k] = seq[((size_t)t * G_ + g) * inDim + k];
    hb[d] = h;
    __syncthreads();
    float gr = bih_d[d], gz = bih_d[128 + d], gn = bih_d[256 + d];
    for (int k = 0; k < inDim; k++) {
      float xv = xb[k];
      const float* wr = Wih_d + (size_t)k * 384;
      gr += xv * wr[d];
      gz += xv * wr[128 + d];
      gn += xv * wr[256 + d];
    }
    float hr = bhh_d[d], hz = bhh_d[128 + d], hn = bhh_d[256 + d];
    for (int k = 0; k < 128; k++) {
      float hv = hb[k];
      const float* wr = Whh_d + (size_t)k * 384;
      hr += hv * wr[d];
      hz += hv * wr[128 + d];
      hn += hv * wr[256 + d];
    }
    float r  = 1.f / (1.f + __expf(-(gr + hr)));
    float zg = 1.f / (1.f + __expf(-(gz + hz)));
    float ng = tanhf(gn + r * hn);
    h = (1.f - zg) * ng + zg * h;
    if (yout) yout[((size_t)t * G_ + g) * 256 + dir * 128 + d] = h;
    __syncthreads();
  }
  hfinal[((size_t)dir * G_ + g) * 128 + d] = h;
}

__global__ void k_final(const float* __restrict__ fp, float* __restrict__ outp, int n)
{
  int i = blockIdx.x * blockDim.x + threadIdx.x;
  if (i < n) {
    outp[i] = fp[i] + fp[G_ * 128 + i] + fp[2 * G_ * 128 + i] + fp[3 * G_ * 128 + i];
  }
}

// ---------------------------------------------------------------------------
extern "C" void kernel_launch(void* const* d_in, const int* in_sizes, int n_in,
                              void* d_out, int out_size, void* d_ws, size_t ws_size,
                              hipStream_t stream)
{
  (void)n_in; (void)ws_size;
  const float* h0   = (const float*)d_in[0];
  const float* e_f  = (const float*)d_in[1];
  const int*   srcI = (const int*)d_in[2];
  const int*   dstI = (const int*)d_in[3];
  const int*   gid  = (const int*)d_in[4];
  // d_in[5] = num_graphs (device scalar) -- fixed at G_=512
  const float* lin0 = (const float*)d_in[6];
  const float* linW = (const float*)d_in[7];
  const float* WeW  = (const float*)d_in[8];
  const float* WqW  = (const float*)d_in[9];
  const float* WkW  = (const float*)d_in[10];
  const float* WvW  = (const float*)d_in[11];
  const float* lng  = (const float*)d_in[12];
  const float* lnb  = (const float*)d_in[13];
  const float* outW = (const float*)d_in[14];
  const float* outb = (const float*)d_in[15];
  const float* projW= (const float*)d_in[16];
  const float* projb= (const float*)d_in[17];
  const float* Wih0 = (const float*)d_in[18];
  const float* Whh0 = (const float*)d_in[19];
  const float* bih0 = (const float*)d_in[20];
  const float* bhh0 = (const float*)d_in[21];
  const float* Wih1 = (const float*)d_in[22];
  const float* Whh1 = (const float*)d_in[23];
  const float* bih1 = (const float*)d_in[24];
  const float* bhh1 = (const float*)d_in[25];
  float* outp = (float*)d_out;

  const int N = in_sizes[0] / INF_;
  const int E = in_sizes[2];

  char* wp = (char*)d_ws;
  auto alloc = [&](size_t bytes) -> void* {
    void* p = (void*)wp;
    wp += (bytes + 255) & ~(size_t)255;
    return p;
  };
  float* Zq   = (float*)alloc((size_t)N * 512 * 4);
  float* Zk   = (float*)alloc((size_t)N * 512 * 4);
  float* Zv   = (float*)alloc((size_t)N * 512 * 4);
  float* zh   = (float*)alloc((size_t)N * 512 * 4);   // z, then heads_out
  float* hcur = (float*)alloc((size_t)N * 128 * 4);
  float* Bm   = (float*)alloc((size_t)N * H_ * EF_ * 4);
  float* Cm   = (float*)alloc((size_t)N * H_ * EF_ * 4);
  float* eeS  = (float*)alloc((size_t)C_ * E * H_ * 4);
  float* WeQ  = (float*)alloc((size_t)C_ * H_ * EF_ * 128 * 4);
  float* WeK  = (float*)alloc((size_t)C_ * H_ * EF_ * 128 * 4);
  float* WeV  = (float*)alloc((size_t)C_ * H_ * EF_ * 128 * 4);
  float* M2   = (float*)alloc((size_t)C_ * H_ * EF_ * EF_ * 4);
  int* deg    = (int*)alloc((size_t)N * 4);
  int* cursor = (int*)alloc((size_t)N * 4);
  int* rowp   = (int*)alloc((size_t)(N + 1) * 4);
  int* eids   = (int*)alloc((size_t)E * 4);
  float* gm74 = (float*)alloc((size_t)G_ * INF_ * 4);
  float* seq  = (float*)alloc((size_t)T_ * G_ * 128 * 4);
  float* seq1 = (float*)alloc((size_t)T_ * G_ * 256 * 4);
  float* fparts=(float*)alloc((size_t)4 * G_ * 128 * 4);

  const int gM = (N + 63) / 64;

  // --- CSR build ---
  hipMemsetAsync(deg, 0, (size_t)N * 4, stream);
  hipMemsetAsync(cursor, 0, (size_t)N * 4, stream);
  k_hist<<<(E + 255) / 256, 256, 0, stream>>>(dstI, deg, E);
  k_scan<<<1, 1024, 0, stream>>>(deg, rowp, N);
  k_fill<<<(E + 255) / 256, 256, 0, stream>>>(dstI, rowp, cursor, eids, E);

  // --- folded small weights + per-edge ee logits ---
  k_small<<<C_ * H_, 128, 0, stream>>>(WeW, WqW, WkW, WvW, WeQ, WeK, WeV, M2);
  k_ee<<<dim3((E + 63) / 64, C_), 256, 0, stream>>>(e_f, M2, eeS, E);

  // --- GRU input t=0: seg-mean(h0) then proj ---
  k_gmean<<<G_, 128, 0, stream>>>(h0, gid, gm74, N, INF_);
  k_gemm<<<dim3((G_ + 63) / 64, 1), 256, 0, stream>>>(
      gm74, INF_, 0, projW, 0, seq, 128, 0, G_, INF_, projb);

  // --- conv layers ---
  for (int j = 0; j < C_; j++) {
    if (j == 0)
      k_gemm<<<dim3(gM, H_), 256, 0, stream>>>(h0, INF_, 0, lin0, INF_ * 128,
                                               zh, 512, 128, N, INF_, nullptr);
    else
      k_gemm<<<dim3(gM, H_), 256, 0, stream>>>(hcur, 128, 0,
                                               linW + (size_t)(j - 1) * H_ * 128 * 128,
                                               128 * 128, zh, 512, 128, N, 128, nullptr);
    k_gemm<<<dim3(gM, H_), 256, 0, stream>>>(zh, 512, 128,
                                             WqW + (size_t)j * H_ * 128 * 128, 128 * 128,
                                             Zq, 512, 128, N, 128, nullptr);
    k_gemm<<<dim3(gM, H_), 256, 0, stream>>>(zh, 512, 128,
                                             WkW + (size_t)j * H_ * 128 * 128, 128 * 128,
                                             Zk, 512, 128, N, 128, nullptr);
    k_gemm<<<dim3(gM, H_), 256, 0, stream>>>(zh, 512, 128,
                                             WvW + (size_t)j * H_ * 128 * 128, 128 * 128,
                                             Zv, 512, 128, N, 128, nullptr);
    k_bc<<<N, 256, 0, stream>>>(Zq, Zk, WeQ, WeK, Bm, Cm, N, j);
    k_edge<<<N, 256, 0, stream>>>(Zq, Zk, Zv, Bm, Cm, eeS, e_f, rowp, eids, srcI,
                                  WeV, lng, lnb, zh, N, E, j);
    k_gemm<<<dim3(gM, 1), 256, 0, stream>>>(zh, 512, 0,
                                            outW + (size_t)j * 512 * 128, 0,
                                            hcur, 128, 0, N, 512, outb + j * 128);
    k_gmean<<<G_, 128, 0, stream>>>(hcur, gid, seq + (size_t)(j + 1) * G_ * 128, N, 128);
  }

  // --- GRU readout ---
  k_gru<<<dim3(G_, 2), 128, 0, stream>>>(seq, 128, Wih0, Whh0, bih0, bhh0,
                                         seq1, fparts);
  k_gru<<<dim3(G_, 2), 128, 0, stream>>>(seq1, 256, Wih1, Whh1, bih1, bhh1,
                                         nullptr, fparts + 2 * G_ * 128);
  k_final<<<(out_size + 255) / 256, 256, 0, stream>>>(fparts, outp, out_size);
}

// Round 3
// 2819.542 us; speedup vs baseline: 1.1994x; 1.1994x over previous
//
#include <hip/hip_runtime.h>
#include <cstdint>

#define D_   128
#define H_   4
#define C_   3
#define G_   512
#define INF_ 74
#define EF_  11
#define T_   4   // GRU sequence length = C_+1

// ---------- bf16 helpers (manual, RNE) ----------
__device__ inline unsigned short f2bf(float x) {
  unsigned u = __float_as_uint(x);
  unsigned r = u + 0x7fffu + ((u >> 16) & 1u);
  return (unsigned short)(r >> 16);
}
__device__ inline void unpack8(uint4 u, float* f) {
  f[0] = __uint_as_float(u.x << 16); f[1] = __uint_as_float(u.x & 0xffff0000u);
  f[2] = __uint_as_float(u.y << 16); f[3] = __uint_as_float(u.y & 0xffff0000u);
  f[4] = __uint_as_float(u.z << 16); f[5] = __uint_as_float(u.z & 0xffff0000u);
  f[6] = __uint_as_float(u.w << 16); f[7] = __uint_as_float(u.w & 0xffff0000u);
}

// ---------------------------------------------------------------------------
// Generic f32 GEMM (kept for proj + out): C[M,128] = A[M,K] @ B[K,128] (+bias)
// ---------------------------------------------------------------------------
__global__ __launch_bounds__(256) void k_gemm(
    const float* __restrict__ A, int lda, int aOff,
    const float* __restrict__ B, int bOff,
    float* __restrict__ C, int ldc, int cOff,
    int M, int K, const float* __restrict__ bias)
{
  A += (size_t)blockIdx.y * aOff;
  B += (size_t)blockIdx.y * bOff;
  C += (size_t)blockIdx.y * cOff;
  __shared__ float As[16][68];
  const int col = threadIdx.x & 127;
  const int rh  = threadIdx.x >> 7;
  const int rowBase = blockIdx.x * 64;
  float acc[32];
#pragma unroll
  for (int i = 0; i < 32; i++) acc[i] = 0.f;

  for (int k0 = 0; k0 < K; k0 += 16) {
    const int t = threadIdx.x;
#pragma unroll
    for (int j = 0; j < 4; j++) {
      int idx = t + j * 256;
      int r = idx >> 4, kk = idx & 15;
      int gr = rowBase + r, gk = k0 + kk;
      float v = 0.f;
      if (gr < M && gk < K) v = A[(size_t)gr * lda + gk];
      As[kk][r] = v;
    }
    __syncthreads();
    const int kmax = (K - k0 < 16) ? (K - k0) : 16;
    for (int kk = 0; kk < kmax; kk++) {
      float w = B[(size_t)(k0 + kk) * 128 + col];
#pragma unroll
      for (int i = 0; i < 8; i++) {
        float4 a4 = *(const float4*)&As[kk][rh * 32 + i * 4];
        acc[i * 4 + 0] += a4.x * w;
        acc[i * 4 + 1] += a4.y * w;
        acc[i * 4 + 2] += a4.z * w;
        acc[i * 4 + 3] += a4.w * w;
      }
    }
    __syncthreads();
  }
  float bv = bias ? bias[col] : 0.f;
#pragma unroll
  for (int i = 0; i < 32; i++) {
    int r = rowBase + rh * 32 + i;
    if (r < M) C[(size_t)r * ldc + col] = acc[i] + bv;
  }
}

// ---------------------------------------------------------------------------
// Fused lin GEMM over 4 heads: zh[M, b*128+col] = A[M,K] @ Bb[K,128]
// block 512: col = t&127, rq = t>>7 selects 16-row strip. 64 FMA : 4 ds_read.
// ---------------------------------------------------------------------------
__global__ __launch_bounds__(512) void k_gemm4(
    const float* __restrict__ A, int lda,
    const float* __restrict__ B0, const float* __restrict__ B1,
    const float* __restrict__ B2, const float* __restrict__ B3,
    float* __restrict__ C, int M, int K)
{
  __shared__ float As[16][68];
  const int col = threadIdx.x & 127;
  const int rq  = threadIdx.x >> 7;     // 0..3
  const int rowBase = blockIdx.x * 64;
  float acc[4][16];
#pragma unroll
  for (int b = 0; b < 4; b++)
#pragma unroll
    for (int i = 0; i < 16; i++) acc[b][i] = 0.f;

  for (int k0 = 0; k0 < K; k0 += 16) {
    const int t = threadIdx.x;
#pragma unroll
    for (int j = 0; j < 2; j++) {
      int idx = t + j * 512;
      int r = idx >> 4, kk = idx & 15;
      int gr = rowBase + r, gk = k0 + kk;
      float v = 0.f;
      if (gr < M && gk < K) v = A[(size_t)gr * lda + gk];
      As[kk][r] = v;
    }
    __syncthreads();
    const int kmax = (K - k0 < 16) ? (K - k0) : 16;
    for (int kk = 0; kk < kmax; kk++) {
      size_t bo = (size_t)(k0 + kk) * 128 + col;
      float w0 = B0[bo], w1 = B1[bo], w2 = B2[bo], w3 = B3[bo];
#pragma unroll
      for (int i = 0; i < 4; i++) {
        float4 a4 = *(const float4*)&As[kk][rq * 16 + i * 4];
#pragma unroll
        for (int c2 = 0; c2 < 4; c2++) {
          float av = (c2 == 0) ? a4.x : (c2 == 1) ? a4.y : (c2 == 2) ? a4.z : a4.w;
          acc[0][i * 4 + c2] += av * w0;
          acc[1][i * 4 + c2] += av * w1;
          acc[2][i * 4 + c2] += av * w2;
          acc[3][i * 4 + c2] += av * w3;
        }
      }
    }
    __syncthreads();
  }
#pragma unroll
  for (int b = 0; b < 4; b++)
#pragma unroll
    for (int i = 0; i < 16; i++) {
      int r = rowBase + rq * 16 + i;
      if (r < M) C[(size_t)r * 512 + b * 128 + col] = acc[b][i];
    }
}

// ---------------------------------------------------------------------------
// Fused q/k/v GEMM per head: Zq/Zk (bf16) and Zv (f32) from zh col-block.
// grid (gM, H). 96 FMA : 8 ds_read per k-step.
// ---------------------------------------------------------------------------
__global__ __launch_bounds__(256) void k_gemm3(
    const float* __restrict__ A, int lda, int aOff,
    const float* __restrict__ B0, const float* __restrict__ B1,
    const float* __restrict__ B2, int bOff,
    unsigned short* __restrict__ Cq, unsigned short* __restrict__ Ck,
    float* __restrict__ Cv, int ldc, int cOff, int M, int K)
{
  const int by = blockIdx.y;
  A  += (size_t)by * aOff;
  B0 += (size_t)by * bOff;
  B1 += (size_t)by * bOff;
  B2 += (size_t)by * bOff;
  const size_t cbase = (size_t)by * cOff;
  __shared__ float As[16][68];
  const int col = threadIdx.x & 127;
  const int rh  = threadIdx.x >> 7;
  const int rowBase = blockIdx.x * 64;
  float a0[32], a1[32], a2[32];
#pragma unroll
  for (int i = 0; i < 32; i++) { a0[i] = 0.f; a1[i] = 0.f; a2[i] = 0.f; }

  for (int k0 = 0; k0 < K; k0 += 16) {
    const int t = threadIdx.x;
#pragma unroll
    for (int j = 0; j < 4; j++) {
      int idx = t + j * 256;
      int r = idx >> 4, kk = idx & 15;
      int gr = rowBase + r, gk = k0 + kk;
      float v = 0.f;
      if (gr < M && gk < K) v = A[(size_t)gr * lda + gk];
      As[kk][r] = v;
    }
    __syncthreads();
    const int kmax = (K - k0 < 16) ? (K - k0) : 16;
    for (int kk = 0; kk < kmax; kk++) {
      size_t bo = (size_t)(k0 + kk) * 128 + col;
      float w0 = B0[bo], w1 = B1[bo], w2 = B2[bo];
#pragma unroll
      for (int i = 0; i < 8; i++) {
        float4 a4 = *(const float4*)&As[kk][rh * 32 + i * 4];
#pragma unroll
        for (int c2 = 0; c2 < 4; c2++) {
          float av = (c2 == 0) ? a4.x : (c2 == 1) ? a4.y : (c2 == 2) ? a4.z : a4.w;
          a0[i * 4 + c2] += av * w0;
          a1[i * 4 + c2] += av * w1;
          a2[i * 4 + c2] += av * w2;
        }
      }
    }
    __syncthreads();
  }
#pragma unroll
  for (int i = 0; i < 32; i++) {
    int r = rowBase + rh * 32 + i;
    if (r < M) {
      size_t o = (size_t)r * ldc + cbase + col;
      Cq[o] = f2bf(a0[i]);
      Ck[o] = f2bf(a1[i]);
      Cv[o] = a2[i];
    }
  }
}

// ---------------------------------------------------------------------------
// CSR build (by dst) + permuted metadata
// ---------------------------------------------------------------------------
__global__ void k_hist(const int* __restrict__ dst, int* __restrict__ deg, int E)
{
  int e = blockIdx.x * blockDim.x + threadIdx.x;
  if (e < E) atomicAdd(&deg[dst[e]], 1);
}

__global__ __launch_bounds__(1024) void k_scan(const int* __restrict__ deg,
                                               int* __restrict__ rowp, int N)
{
  __shared__ int part[1024];
  int t = threadIdx.x;
  int chunk = (N + 1023) / 1024;
  int base = t * chunk;
  int s = 0;
  for (int i = 0; i < chunk; i++) { int idx = base + i; if (idx < N) s += deg[idx]; }
  part[t] = s;
  __syncthreads();
  for (int off = 1; off < 1024; off <<= 1) {
    int v = (t >= off) ? part[t - off] : 0;
    __syncthreads();
    part[t] += v;
    __syncthreads();
  }
  int run = part[t] - s;
  for (int i = 0; i < chunk; i++) {
    int idx = base + i;
    if (idx < N) { rowp[idx] = run; run += deg[idx]; }
  }
  if (t == 1023) rowp[N] = part[1023];
}

__global__ void k_fill(const int* __restrict__ src, const int* __restrict__ dst,
                       const int* __restrict__ rowp, int* __restrict__ cursor,
                       int* __restrict__ eids, int* __restrict__ src_perm,
                       int* __restrict__ dst_perm, int E)
{
  int e = blockIdx.x * blockDim.x + threadIdx.x;
  if (e < E) {
    int d = dst[e];
    int pos = atomicAdd(&cursor[d], 1);
    int slot = rowp[d] + pos;
    eids[slot] = e;
    src_perm[slot] = src[e];
    dst_perm[slot] = d;
  }
}

__global__ void k_efperm(const float* __restrict__ e_f, const int* __restrict__ eids,
                         float* __restrict__ ef_perm, int E)
{
  int i = blockIdx.x * blockDim.x + threadIdx.x;
  if (i < E * EF_) {
    int idx = i / EF_, f = i - idx * EF_;
    ef_perm[i] = e_f[(size_t)eids[idx] * EF_ + f];
  }
}

// ---------------------------------------------------------------------------
// Folded small weights: WeQ/WeK/WeV = We @ W{q,k,v} [11,128], M2 = WeQ@WeK^T
// ---------------------------------------------------------------------------
__global__ __launch_bounds__(128) void k_small(
    const float* __restrict__ WeW, const float* __restrict__ WqW,
    const float* __restrict__ WkW, const float* __restrict__ WvW,
    float* __restrict__ WeQ, float* __restrict__ WeK, float* __restrict__ WeV,
    float* __restrict__ M2)
{
  int ch = blockIdx.x;
  const float* We = WeW + (size_t)ch * EF_ * 128;
  const float* Wq = WqW + (size_t)ch * 128 * 128;
  const float* Wk = WkW + (size_t)ch * 128 * 128;
  const float* Wv = WvW + (size_t)ch * 128 * 128;
  __shared__ float sWe[EF_ * 128], sQ[EF_ * 128], sK[EF_ * 128];
  int d = threadIdx.x;
  for (int i = d; i < EF_ * 128; i += 128) sWe[i] = We[i];
  __syncthreads();
  for (int f = 0; f < EF_; f++) {
    float aq = 0.f, ak = 0.f, av = 0.f;
    for (int k = 0; k < 128; k++) {
      float w = sWe[f * 128 + k];
      aq += w * Wq[k * 128 + d];
      ak += w * Wk[k * 128 + d];
      av += w * Wv[k * 128 + d];
    }
    WeQ[(size_t)ch * EF_ * 128 + f * 128 + d] = aq;
    WeK[(size_t)ch * EF_ * 128 + f * 128 + d] = ak;
    WeV[(size_t)ch * EF_ * 128 + f * 128 + d] = av;
    sQ[f * 128 + d] = aq;
    sK[f * 128 + d] = ak;
  }
  __syncthreads();
  if (d < EF_ * EF_) {
    int a = d / EF_, b = d % EF_;
    float s = 0.f;
    for (int k = 0; k < 128; k++) s += sQ[a * 128 + k] * sK[b * 128 + k];
    M2[(size_t)ch * (EF_ * EF_) + d] = s;
  }
}

// ---------------------------------------------------------------------------
// B = Zq @ WeK^T, C = Zk @ WeQ^T -> [N*H,11]; ss[n,h] = Zq.Zk.
// One wave per (node, head); inputs are bf16.
// ---------------------------------------------------------------------------
__global__ __launch_bounds__(256) void k_bc(
    const unsigned short* __restrict__ Zqh, const unsigned short* __restrict__ Zkh,
    const float* __restrict__ WeQ, const float* __restrict__ WeK,
    float* __restrict__ Bm, float* __restrict__ Cm, float* __restrict__ ss,
    int N, int layer)
{
  int wave = threadIdx.x >> 6, lane = threadIdx.x & 63;
  int n = blockIdx.x, h = wave;
  size_t nb = (size_t)n * 512 + h * 128 + 2 * lane;
  unsigned uq = *(const unsigned*)(Zqh + nb);
  unsigned uk = *(const unsigned*)(Zkh + nb);
  float2 zq, zk;
  zq.x = __uint_as_float(uq << 16); zq.y = __uint_as_float(uq & 0xffff0000u);
  zk.x = __uint_as_float(uk << 16); zk.y = __uint_as_float(uk & 0xffff0000u);
  const float* wq = WeQ + (size_t)(layer * H_ + h) * EF_ * 128;
  const float* wk = WeK + (size_t)(layer * H_ + h) * EF_ * 128;
  int task = n * H_ + h;
  float pss = zq.x * zk.x + zq.y * zk.y;
#pragma unroll
  for (int m = 32; m; m >>= 1) pss += __shfl_xor(pss, m, 64);
  if (lane == 0) ss[task] = pss;
  for (int f = 0; f < EF_; f++) {
    float2 a = *(const float2*)&wk[f * 128 + 2 * lane];
    float2 b = *(const float2*)&wq[f * 128 + 2 * lane];
    float pb = zq.x * a.x + zq.y * a.y;
    float pc = zk.x * b.x + zk.y * b.y;
#pragma unroll
    for (int m = 32; m; m >>= 1) {
      pb += __shfl_xor(pb, m, 64);
      pc += __shfl_xor(pc, m, 64);
    }
    if (lane == 0) {
      Bm[(size_t)task * EF_ + f] = pb;
      Cm[(size_t)task * EF_ + f] = pc;
    }
  }
}

// ---------------------------------------------------------------------------
// Per-edge precomputed logits (CSR order): elog[idx][h][6] =
// {ss_s(S00), se(S02), de(S12), es(S20), ed(S21), ee(S22)}
// ---------------------------------------------------------------------------
__global__ __launch_bounds__(256) void k_elog(
    const float* __restrict__ Bm, const float* __restrict__ Cm,
    const float* __restrict__ ss, const float* __restrict__ M2,
    const float* __restrict__ ef_perm, const int* __restrict__ src_perm,
    const int* __restrict__ dst_perm, float* __restrict__ elog,
    int E, int layer)
{
  int i0 = blockIdx.x * 64;
  __shared__ float efs[64 * EF_];
  __shared__ float m2s[4 * EF_ * EF_];
  int t = threadIdx.x;
  for (int i = t; i < 64 * EF_; i += 256) {
    int gi = i0 * EF_ + i;
    efs[i] = (gi < E * EF_) ? ef_perm[gi] : 0.f;
  }
  for (int i = t; i < 4 * EF_ * EF_; i += 256)
    m2s[i] = M2[(size_t)layer * 4 * EF_ * EF_ + i];
  __syncthreads();
  int sl = t >> 2, h = t & 3;
  int idx = i0 + sl;
  if (idx < E) {
    int s = src_perm[idx], d = dst_perm[idx];
    const float* ef = &efs[sl * EF_];
    const float* m2 = &m2s[h * EF_ * EF_];
    float ee = 0.f;
#pragma unroll
    for (int a = 0; a < EF_; a++) {
      float r = 0.f;
#pragma unroll
      for (int b = 0; b < EF_; b++) r += m2[a * EF_ + b] * ef[b];
      ee += ef[a] * r;
    }
    const float* bs = Bm + (size_t)(s * H_ + h) * EF_;
    const float* cs = Cm + (size_t)(s * H_ + h) * EF_;
    const float* bd = Bm + (size_t)(d * H_ + h) * EF_;
    const float* cd = Cm + (size_t)(d * H_ + h) * EF_;
    float se = 0.f, es = 0.f, de = 0.f, ed = 0.f;
#pragma unroll
    for (int f = 0; f < EF_; f++) {
      float e = ef[f];
      se += bs[f] * e;
      es += cs[f] * e;
      de += bd[f] * e;
      ed += cd[f] * e;
    }
    float* o = elog + ((size_t)idx * H_ + h) * 6;
    o[0] = ss[s * H_ + h];
    o[1] = se; o[2] = de; o[3] = es; o[4] = ed; o[5] = ee;
  }
}

// ---------------------------------------------------------------------------
// Edge aggregation: wave per (dst,head); 16-lane groups process 4 edges at a
// time; only the 2 cross logits (Qs.Kd, Qd.Ks) computed here; softmax + mean
// + ReLU + LayerNorm fused. No atomics.
// ---------------------------------------------------------------------------
__global__ __launch_bounds__(256) void k_edge(
    const unsigned short* __restrict__ Zqh, const unsigned short* __restrict__ Zkh,
    const float* __restrict__ Zv, const float* __restrict__ ss,
    const float* __restrict__ elog, const float* __restrict__ ef_perm,
    const int* __restrict__ rowp, const int* __restrict__ src_perm,
    const float* __restrict__ WeV, const float* __restrict__ lng,
    const float* __restrict__ lnb, float* __restrict__ heads,
    int N, int layer)
{
  const int h = threadIdx.x >> 6;
  const int lane = threadIdx.x & 63;
  const int q = lane & 15;        // d-slice index (8 floats each)
  const int g = lane >> 4;        // edge group 0..3
  const int lb = lane & 48;       // group base lane
  const int n = blockIdx.x;
  const size_t nb = (size_t)n * 512 + h * 128 + q * 8;

  float zqd[8], zkd[8], zvd[8];
  unpack8(*(const uint4*)(Zqh + nb), zqd);
  unpack8(*(const uint4*)(Zkh + nb), zkd);
  {
    float4 a = *(const float4*)(Zv + nb);
    float4 b = *(const float4*)(Zv + nb + 4);
    zvd[0] = a.x; zvd[1] = a.y; zvd[2] = a.z; zvd[3] = a.w;
    zvd[4] = b.x; zvd[5] = b.y; zvd[6] = b.z; zvd[7] = b.w;
  }
  const float ssd = ss[n * H_ + h];
  const int beg = rowp[n], end = rowp[n + 1];
  float acc[8];
#pragma unroll
  for (int i = 0; i < 8; i++) acc[i] = 0.f;
  float wdsum = 0.f, a11 = 0.f;

  for (int idx0 = beg; idx0 < end; idx0 += 4) {
    int idxg = idx0 + g;
    bool act = idxg < end;
    int idxc = act ? idxg : beg;
    int s = src_perm[idxc];
    size_t sb = (size_t)s * 512 + h * 128 + q * 8;
    float zqs[8], zks[8], zvs[8];
    unpack8(*(const uint4*)(Zqh + sb), zqs);
    unpack8(*(const uint4*)(Zkh + sb), zks);
    {
      float4 a = *(const float4*)(Zv + sb);
      float4 b = *(const float4*)(Zv + sb + 4);
      zvs[0] = a.x; zvs[1] = a.y; zvs[2] = a.z; zvs[3] = a.w;
      zvs[4] = b.x; zvs[5] = b.y; zvs[6] = b.z; zvs[7] = b.w;
    }
    float v1 = 0.f, v2 = 0.f;
#pragma unroll
    for (int i = 0; i < 8; i++) {
      v1 += zqs[i] * zkd[i];
      v2 += zqd[i] * zks[i];
    }
#pragma unroll
    for (int m = 1; m < 16; m <<= 1) {
      v1 += __shfl_xor(v1, m, 64);
      v2 += __shfl_xor(v2, m, 64);
    }
    float lv = (q < 6) ? elog[((size_t)idxc * H_ + h) * 6 + q] : 0.f;
    float S00 = __shfl(lv, lb + 0, 64);
    float S02 = __shfl(lv, lb + 1, 64);
    float S12 = __shfl(lv, lb + 2, 64);
    float S20 = __shfl(lv, lb + 3, 64);
    float S21 = __shfl(lv, lb + 4, 64);
    float S22 = __shfl(lv, lb + 5, 64);
    // rows: [s: S00 v1 S02] [d: v2 ssd S12] [e: S20 S21 S22]
    float m0 = fmaxf(fmaxf(S00, v1), S02);
    float e00 = __expf(S00 - m0), e01 = __expf(v1 - m0), e02 = __expf(S02 - m0);
    float i0r = 1.f / (e00 + e01 + e02);
    float m1 = fmaxf(fmaxf(v2, ssd), S12);
    float e10 = __expf(v2 - m1), e11 = __expf(ssd - m1), e12 = __expf(S12 - m1);
    float i1r = 1.f / (e10 + e11 + e12);
    float m2 = fmaxf(fmaxf(S20, S21), S22);
    float e20 = __expf(S20 - m2), e21 = __expf(S21 - m2), e22 = __expf(S22 - m2);
    float i2r = 1.f / (e20 + e21 + e22);
    float w0 = e00 * i0r + e10 * i1r + e20 * i2r;
    float w1 = e01 * i0r + e11 * i1r + e21 * i2r;
    float w2 = e02 * i0r + e12 * i1r + e22 * i2r;
    if (!act) { w0 = 0.f; w1 = 0.f; w2 = 0.f; }
#pragma unroll
    for (int i = 0; i < 8; i++) acc[i] += w0 * zvs[i];
    wdsum += w1;
    float efl = (q < EF_) ? ef_perm[(size_t)idxc * EF_ + q] : 0.f;
    a11 += w2 * efl;
  }
  // reduce across the 4 edge-groups
#pragma unroll
  for (int m = 16; m < 64; m <<= 1) {
#pragma unroll
    for (int i = 0; i < 8; i++) acc[i] += __shfl_xor(acc[i], m, 64);
    wdsum += __shfl_xor(wdsum, m, 64);
    a11 += __shfl_xor(a11, m, 64);
  }
#pragma unroll
  for (int i = 0; i < 8; i++) acc[i] += wdsum * zvd[i];
  const float* wv = WeV + (size_t)(layer * H_ + h) * EF_ * 128;
#pragma unroll
  for (int f = 0; f < EF_; f++) {
    float af = __shfl(a11, f, 64);
    float4 wa = *(const float4*)(wv + f * 128 + q * 8);
    float4 wb = *(const float4*)(wv + f * 128 + q * 8 + 4);
    acc[0] += af * wa.x; acc[1] += af * wa.y; acc[2] += af * wa.z; acc[3] += af * wa.w;
    acc[4] += af * wb.x; acc[5] += af * wb.y; acc[6] += af * wb.z; acc[7] += af * wb.w;
  }
  int cnt = end - beg;
  float invc = (cnt > 0) ? 1.f / (float)cnt : 1.f;
  float mv[8];
  float s1 = 0.f;
#pragma unroll
  for (int i = 0; i < 8; i++) { mv[i] = fmaxf(acc[i] * invc, 0.f); s1 += mv[i]; }
#pragma unroll
  for (int m = 1; m < 16; m <<= 1) s1 += __shfl_xor(s1, m, 64);
  float mean = s1 * (1.f / 128.f);
  float s2 = 0.f;
#pragma unroll
  for (int i = 0; i < 8; i++) { float d = mv[i] - mean; s2 += d * d; }
#pragma unroll
  for (int m = 1; m < 16; m <<= 1) s2 += __shfl_xor(s2, m, 64);
  float rstd = rsqrtf(s2 * (1.f / 128.f) + 1e-5f);
  if (g == 0) {
    int gi = (layer * H_ + h) * 128 + q * 8;
    float4 ga = *(const float4*)(lng + gi);
    float4 gb = *(const float4*)(lng + gi + 4);
    float4 ba = *(const float4*)(lnb + gi);
    float4 bb = *(const float4*)(lnb + gi + 4);
    float4 o1, o2;
    o1.x = (mv[0] - mean) * rstd * ga.x + ba.x;
    o1.y = (mv[1] - mean) * rstd * ga.y + ba.y;
    o1.z = (mv[2] - mean) * rstd * ga.z + ba.z;
    o1.w = (mv[3] - mean) * rstd * ga.w + ba.w;
    o2.x = (mv[4] - mean) * rstd * gb.x + bb.x;
    o2.y = (mv[5] - mean) * rstd * gb.y + bb.y;
    o2.z = (mv[6] - mean) * rstd * gb.z + bb.z;
    o2.w = (mv[7] - mean) * rstd * gb.w + bb.w;
    *(float4*)(heads + nb) = o1;
    *(float4*)(heads + nb + 4) = o2;
  }
}

// ---------------------------------------------------------------------------
// Segment mean by graph id (node_gid sorted): one block per graph.
// ---------------------------------------------------------------------------
__global__ void k_gmean(const float* __restrict__ X, const int* __restrict__ gid,
                        float* __restrict__ outp, int N, int ld)
{
  int g = blockIdx.x;
  int lo = 0, hi = N;
  while (lo < hi) { int m = (lo + hi) >> 1; if (gid[m] < g) lo = m + 1; else hi = m; }
  int s0 = lo;
  lo = s0; hi = N;
  while (lo < hi) { int m = (lo + hi) >> 1; if (gid[m] < g + 1) lo = m + 1; else hi = m; }
  int s1 = lo;
  float inv = 1.f / (float)((s1 - s0) > 0 ? (s1 - s0) : 1);
  for (int d = threadIdx.x; d < ld; d += blockDim.x) {
    float s = 0.f;
    for (int n = s0; n < s1; n++) s += X[(size_t)n * ld + d];
    outp[(size_t)g * ld + d] = s * inv;
  }
}

// ---------------------------------------------------------------------------
// GRU pass: block = (graph, dir), 128 threads.
// ---------------------------------------------------------------------------
__global__ __launch_bounds__(128) void k_gru(
    const float* __restrict__ seq, int inDim,
    const float* __restrict__ Wih, const float* __restrict__ Whh,
    const float* __restrict__ bih, const float* __restrict__ bhh,
    float* __restrict__ yout, float* __restrict__ hfinal)
{
  int g = blockIdx.x, dir = blockIdx.y, d = threadIdx.x;
  const float* Wih_d = Wih + (size_t)dir * inDim * 384;
  const float* Whh_d = Whh + (size_t)dir * 128 * 384;
  const float* bih_d = bih + dir * 384;
  const float* bhh_d = bhh + dir * 384;
  __shared__ float xb[256];
  __shared__ float hb[128];
  float h = 0.f;
  for (int st = 0; st < T_; st++) {
    int t = dir ? (T_ - 1 - st) : st;
    for (int k = d; k < inDim; k += 128) xb[k] = seq[((size_t)t * G_ + g) * inDim + k];
    hb[d] = h;
    __syncthreads();
    float gr = bih_d[d], gz = bih_d[128 + d], gn = bih_d[256 + d];
    for (int k = 0; k < inDim; k++) {
      float xv = xb[k];
      const float* wr = Wih_d + (size_t)k * 384;
      gr += xv * wr[d];
      gz += xv * wr[128 + d];
      gn += xv * wr[256 + d];
    }
    float hr = bhh_d[d], hz = bhh_d[128 + d], hn = bhh_d[256 + d];
    for (int k = 0; k < 128; k++) {
      float hv = hb[k];
      const float* wr = Whh_d + (size_t)k * 384;
      hr += hv * wr[d];
      hz += hv * wr[128 + d];
      hn += hv * wr[256 + d];
    }
    float r  = 1.f / (1.f + __expf(-(gr + hr)));
    float zg = 1.f / (1.f + __expf(-(gz + hz)));
    float ng = tanhf(gn + r * hn);
    h = (1.f - zg) * ng + zg * h;
    if (yout) yout[((size_t)t * G_ + g) * 256 + dir * 128 + d] = h;
    __syncthreads();
  }
  hfinal[((size_t)dir * G_ + g) * 128 + d] = h;
}

__global__ void k_final(const float* __restrict__ fp, float* __restrict__ outp, int n)
{
  int i = blockIdx.x * blockDim.x + threadIdx.x;
  if (i < n) {
    outp[i] = fp[i] + fp[G_ * 128 + i] + fp[2 * G_ * 128 + i] + fp[3 * G_ * 128 + i];
  }
}

// ---------------------------------------------------------------------------
extern "C" void kernel_launch(void* const* d_in, const int* in_sizes, int n_in,
                              void* d_out, int out_size, void* d_ws, size_t ws_size,
                              hipStream_t stream)
{
  (void)n_in; (void)ws_size;
  const float* h0   = (const float*)d_in[0];
  const float* e_f  = (const float*)d_in[1];
  const int*   srcI = (const int*)d_in[2];
  const int*   dstI = (const int*)d_in[3];
  const int*   gid  = (const int*)d_in[4];
  const float* lin0 = (const float*)d_in[6];
  const float* linW = (const float*)d_in[7];
  const float* WeW  = (const float*)d_in[8];
  const float* WqW  = (const float*)d_in[9];
  const float* WkW  = (const float*)d_in[10];
  const float* WvW  = (const float*)d_in[11];
  const float* lng  = (const float*)d_in[12];
  const float* lnb  = (const float*)d_in[13];
  const float* outW = (const float*)d_in[14];
  const float* outb = (const float*)d_in[15];
  const float* projW= (const float*)d_in[16];
  const float* projb= (const float*)d_in[17];
  const float* Wih0 = (const float*)d_in[18];
  const float* Whh0 = (const float*)d_in[19];
  const float* bih0 = (const float*)d_in[20];
  const float* bhh0 = (const float*)d_in[21];
  const float* Wih1 = (const float*)d_in[22];
  const float* Whh1 = (const float*)d_in[23];
  const float* bih1 = (const float*)d_in[24];
  const float* bhh1 = (const float*)d_in[25];
  float* outp = (float*)d_out;

  const int N = in_sizes[0] / INF_;
  const int E = in_sizes[2];

  char* wp = (char*)d_ws;
  auto alloc = [&](size_t bytes) -> void* {
    void* p = (void*)wp;
    wp += (bytes + 255) & ~(size_t)255;
    return p;
  };
  float* Zv   = (float*)alloc((size_t)N * 512 * 4);
  float* zh   = (float*)alloc((size_t)N * 512 * 4);       // z, then heads_out
  unsigned short* Zqh = (unsigned short*)alloc((size_t)N * 512 * 2);
  unsigned short* Zkh = (unsigned short*)alloc((size_t)N * 512 * 2);
  float* hcur = (float*)alloc((size_t)N * 128 * 4);
  float* Bm   = (float*)alloc((size_t)N * H_ * EF_ * 4);
  float* Cm   = (float*)alloc((size_t)N * H_ * EF_ * 4);
  float* ssb  = (float*)alloc((size_t)N * H_ * 4);
  float* elog = (float*)alloc((size_t)E * H_ * 6 * 4);
  float* efp  = (float*)alloc((size_t)E * EF_ * 4);
  float* WeQ  = (float*)alloc((size_t)C_ * H_ * EF_ * 128 * 4);
  float* WeK  = (float*)alloc((size_t)C_ * H_ * EF_ * 128 * 4);
  float* WeV  = (float*)alloc((size_t)C_ * H_ * EF_ * 128 * 4);
  float* M2   = (float*)alloc((size_t)C_ * H_ * EF_ * EF_ * 4);
  int* deg    = (int*)alloc((size_t)N * 4);
  int* cursor = (int*)alloc((size_t)N * 4);
  int* rowp   = (int*)alloc((size_t)(N + 1) * 4);
  int* eids   = (int*)alloc((size_t)E * 4);
  int* srcp   = (int*)alloc((size_t)E * 4);
  int* dstp   = (int*)alloc((size_t)E * 4);
  float* gm74 = (float*)alloc((size_t)G_ * INF_ * 4);
  float* seq  = (float*)alloc((size_t)T_ * G_ * 128 * 4);
  float* seq1 = (float*)alloc((size_t)T_ * G_ * 256 * 4);
  float* fparts=(float*)alloc((size_t)4 * G_ * 128 * 4);

  const int gM = (N + 63) / 64;

  // --- CSR build + permuted metadata ---
  hipMemsetAsync(deg, 0, (size_t)N * 4, stream);
  hipMemsetAsync(cursor, 0, (size_t)N * 4, stream);
  k_hist<<<(E + 255) / 256, 256, 0, stream>>>(dstI, deg, E);
  k_scan<<<1, 1024, 0, stream>>>(deg, rowp, N);
  k_fill<<<(E + 255) / 256, 256, 0, stream>>>(srcI, dstI, rowp, cursor,
                                              eids, srcp, dstp, E);
  k_efperm<<<(E * EF_ + 255) / 256, 256, 0, stream>>>(e_f, eids, efp, E);

  // --- folded small weights ---
  k_small<<<C_ * H_, 128, 0, stream>>>(WeW, WqW, WkW, WvW, WeQ, WeK, WeV, M2);

  // --- GRU input t=0: seg-mean(h0) then proj ---
  k_gmean<<<G_, 128, 0, stream>>>(h0, gid, gm74, N, INF_);
  k_gemm<<<dim3((G_ + 63) / 64, 1), 256, 0, stream>>>(
      gm74, INF_, 0, projW, 0, seq, 128, 0, G_, INF_, projb);

  // --- conv layers ---
  for (int j = 0; j < C_; j++) {
    if (j == 0) {
      k_gemm4<<<gM, 512, 0, stream>>>(h0, INF_,
          lin0, lin0 + (size_t)INF_ * 128, lin0 + (size_t)2 * INF_ * 128,
          lin0 + (size_t)3 * INF_ * 128, zh, N, INF_);
    } else {
      const float* lb = linW + (size_t)(j - 1) * H_ * 128 * 128;
      k_gemm4<<<gM, 512, 0, stream>>>(hcur, 128,
          lb, lb + 16384, lb + 2 * 16384, lb + 3 * 16384, zh, N, 128);
    }
    k_gemm3<<<dim3(gM, H_), 256, 0, stream>>>(
        zh, 512, 128,
        WqW + (size_t)j * H_ * 16384, WkW + (size_t)j * H_ * 16384,
        WvW + (size_t)j * H_ * 16384, 16384,
        Zqh, Zkh, Zv, 512, 128, N, 128);
    k_bc<<<N, 256, 0, stream>>>(Zqh, Zkh, WeQ, WeK, Bm, Cm, ssb, N, j);
    k_elog<<<(E + 63) / 64, 256, 0, stream>>>(Bm, Cm, ssb, M2, efp, srcp, dstp,
                                              elog, E, j);
    k_edge<<<N, 256, 0, stream>>>(Zqh, Zkh, Zv, ssb, elog, efp, rowp, srcp,
                                  WeV, lng, lnb, zh, N, j);
    k_gemm<<<dim3(gM, 1), 256, 0, stream>>>(zh, 512, 0,
                                            outW + (size_t)j * 512 * 128, 0,
                                            hcur, 128, 0, N, 512, outb + j * 128);
    k_gmean<<<G_, 128, 0, stream>>>(hcur, gid, seq + (size_t)(j + 1) * G_ * 128, N, 128);
  }

  // --- GRU readout ---
  k_gru<<<dim3(G_, 2), 128, 0, stream>>>(seq, 128, Wih0, Whh0, bih0, bhh0,
                                         seq1, fparts);
  k_gru<<<dim3(G_, 2), 128, 0, stream>>>(seq1, 256, Wih1, Whh1, bih1, bhh1,
                                         nullptr, fparts + 2 * G_ * 128);
  k_final<<<(out_size + 255) / 256, 256, 0, stream>>>(fparts, outp, out_size);
}

// Round 4
// 1800.617 us; speedup vs baseline: 1.8780x; 1.5659x over previous
//
#include <hip/hip_runtime.h>
#include <cstdint>

#define D_   128
#define H_   4
#define C_   3
#define G_   512
#define INF_ 74
#define EF_  11
#define T_   4   // GRU sequence length = C_+1
#define NW_  52

typedef __attribute__((ext_vector_type(8))) short bf16x8;
typedef __attribute__((ext_vector_type(4))) float f32x4;

// ---------- bf16 helpers (manual, RNE) ----------
__device__ inline unsigned short f2bf(float x) {
  unsigned u = __float_as_uint(x);
  unsigned r = u + 0x7fffu + ((u >> 16) & 1u);
  return (unsigned short)(r >> 16);
}
__device__ inline void unpack8(uint4 u, float* f) {
  f[0] = __uint_as_float(u.x << 16); f[1] = __uint_as_float(u.x & 0xffff0000u);
  f[2] = __uint_as_float(u.y << 16); f[3] = __uint_as_float(u.y & 0xffff0000u);
  f[4] = __uint_as_float(u.z << 16); f[5] = __uint_as_float(u.z & 0xffff0000u);
  f[6] = __uint_as_float(u.w << 16); f[7] = __uint_as_float(u.w & 0xffff0000u);
}

// ---------------------------------------------------------------------------
// Weight transpose+convert: dst[d*K + k] = bf16(src[k*D + d]) for NW_ mats.
// ---------------------------------------------------------------------------
struct WDesc { const float* src; unsigned short* dst; int K; int D; };
struct WPack { WDesc d[NW_]; };

__global__ __launch_bounds__(256) void k_wcvt(WPack wp)
{
  WDesc w = wp.d[blockIdx.y];
  int tot = w.K * w.D;
  for (int i = blockIdx.x * 256 + threadIdx.x; i < tot; i += gridDim.x * 256) {
    int d = i / w.K, k = i - d * w.K;
    w.dst[i] = f2bf(w.src[(size_t)k * w.D + d]);
  }
}

// ---------------------------------------------------------------------------
// MFMA bf16 GEMM: C = A[M,K](f32, converted in staging) @ Bt[N=128/block][K]
// (bf16, N-major). 128x128 tile, 256 thr = 4 waves (2x2 quadrants of 64x64),
// mfma_f32_16x16x32_bf16, acc 4x4 frags. Output: f32 (+bias) or bf16 (qkv,
// interleaved ZQKV). Layout per m97-verified mapping.
// ---------------------------------------------------------------------------
__global__ __launch_bounds__(256) void k_mfma(
    const float* __restrict__ A, int lda, int aOffZ, int M, int K,
    const unsigned short* __restrict__ Bt, int btOffY, int btOffZ,
    float* __restrict__ outF, int ldc, int cOffY,
    const float* __restrict__ bias,
    unsigned short* __restrict__ outH, int hStride, int hOffY, int hOffZ)
{
  const int bx = blockIdx.x, by = blockIdx.y, bz = blockIdx.z;
  A += (size_t)bz * aOffZ;
  const unsigned short* Bp = Bt + (size_t)by * btOffY + (size_t)bz * btOffZ;
  const int rowBase = bx * 128;
  __shared__ unsigned short As[128][40];   // pad->40: 2-way LDS conflicts (free)
  __shared__ unsigned short Bs[128][40];
  const int t = threadIdx.x;
  const int w = t >> 6, l = t & 63;
  const int wr = w >> 1, wc = w & 1;
  const int fr = l & 15, fq = l >> 4;
  f32x4 acc[4][4];
#pragma unroll
  for (int m = 0; m < 4; m++)
#pragma unroll
    for (int n = 0; n < 4; n++) acc[m][n] = (f32x4){0.f, 0.f, 0.f, 0.f};

  const int sr = t >> 1, sh = t & 1;
  const int arow = rowBase + sr;
  const float* aBase = A + (size_t)arow * lda;

  for (int k0 = 0; k0 < K; k0 += 32) {
    // stage A (f32 -> bf16), rows rowBase..+127, k0..k0+31
    {
      unsigned short tmp[16];
      int kb = k0 + sh * 16;
      if (arow < M && kb + 16 <= K) {
        const float* ap = aBase + kb;
#pragma unroll
        for (int i = 0; i < 16; i++) tmp[i] = f2bf(ap[i]);
      } else {
#pragma unroll
        for (int i = 0; i < 16; i++) {
          int gk = kb + i;
          float v = (arow < M && gk < K) ? aBase[gk] : 0.f;
          tmp[i] = f2bf(v);
        }
      }
      *(uint4*)&As[sr][sh * 16]     = *(const uint4*)&tmp[0];
      *(uint4*)&As[sr][sh * 16 + 8] = *(const uint4*)&tmp[8];
    }
    // stage Bt (already bf16): row t (= output col), k0..k0+31
    if (t < 128) {
      unsigned short tmp[32];
      if (k0 + 32 <= K) {
        const unsigned short* bp = Bp + (size_t)t * K + k0;
#pragma unroll
        for (int i = 0; i < 32; i++) tmp[i] = bp[i];
      } else {
#pragma unroll
        for (int i = 0; i < 32; i++) {
          int gk = k0 + i;
          tmp[i] = (gk < K) ? Bp[(size_t)t * K + gk] : (unsigned short)0;
        }
      }
#pragma unroll
      for (int i = 0; i < 4; i++) *(uint4*)&Bs[t][i * 8] = *(const uint4*)&tmp[i * 8];
    }
    __syncthreads();
    bf16x8 af[4], bfr[4];
#pragma unroll
    for (int m = 0; m < 4; m++) af[m]  = *(const bf16x8*)&As[wr * 64 + m * 16 + fr][fq * 8];
#pragma unroll
    for (int n = 0; n < 4; n++) bfr[n] = *(const bf16x8*)&Bs[wc * 64 + n * 16 + fr][fq * 8];
#pragma unroll
    for (int m = 0; m < 4; m++)
#pragma unroll
      for (int n = 0; n < 4; n++)
        acc[m][n] = __builtin_amdgcn_mfma_f32_16x16x32_bf16(af[m], bfr[n], acc[m][n], 0, 0, 0);
    __syncthreads();
  }
  // epilogue: C col = fr, row = fq*4 + r within 16x16 frag
#pragma unroll
  for (int m = 0; m < 4; m++) {
    int row0 = rowBase + wr * 64 + m * 16 + fq * 4;
#pragma unroll
    for (int n = 0; n < 4; n++) {
      int col = wc * 64 + n * 16 + fr;
#pragma unroll
      for (int r = 0; r < 4; r++) {
        int row = row0 + r;
        if (row < M) {
          float v = acc[m][n][r];
          if (outH) {
            outH[(size_t)row * hStride + by * hOffY + bz * hOffZ + col] = f2bf(v);
          } else {
            if (bias) v += bias[col];
            outF[(size_t)row * ldc + by * cOffY + col] = v;
          }
        }
      }
    }
  }
}

// ---------------------------------------------------------------------------
// CSR build (by dst) + permuted metadata
// ---------------------------------------------------------------------------
__global__ void k_hist(const int* __restrict__ dst, int* __restrict__ deg, int E)
{
  int e = blockIdx.x * blockDim.x + threadIdx.x;
  if (e < E) atomicAdd(&deg[dst[e]], 1);
}

__global__ __launch_bounds__(1024) void k_scan(const int* __restrict__ deg,
                                               int* __restrict__ rowp, int N)
{
  __shared__ int part[1024];
  int t = threadIdx.x;
  int chunk = (N + 1023) / 1024;
  int base = t * chunk;
  int s = 0;
  for (int i = 0; i < chunk; i++) { int idx = base + i; if (idx < N) s += deg[idx]; }
  part[t] = s;
  __syncthreads();
  for (int off = 1; off < 1024; off <<= 1) {
    int v = (t >= off) ? part[t - off] : 0;
    __syncthreads();
    part[t] += v;
    __syncthreads();
  }
  int run = part[t] - s;
  for (int i = 0; i < chunk; i++) {
    int idx = base + i;
    if (idx < N) { rowp[idx] = run; run += deg[idx]; }
  }
  if (t == 1023) rowp[N] = part[1023];
}

__global__ void k_fill(const int* __restrict__ src, const int* __restrict__ dst,
                       const int* __restrict__ rowp, int* __restrict__ cursor,
                       int* __restrict__ eids, int* __restrict__ src_perm,
                       int* __restrict__ dst_perm, int E)
{
  int e = blockIdx.x * blockDim.x + threadIdx.x;
  if (e < E) {
    int d = dst[e];
    int pos = atomicAdd(&cursor[d], 1);
    int slot = rowp[d] + pos;
    eids[slot] = e;
    src_perm[slot] = src[e];
    dst_perm[slot] = d;
  }
}

__global__ void k_efperm(const float* __restrict__ e_f, const int* __restrict__ eids,
                         float* __restrict__ ef_perm, int E)
{
  int i = blockIdx.x * blockDim.x + threadIdx.x;
  if (i < E * EF_) {
    int idx = i / EF_, f = i - idx * EF_;
    ef_perm[i] = e_f[(size_t)eids[idx] * EF_ + f];
  }
}

// ---------------------------------------------------------------------------
// Folded small weights: WeQ/WeK/WeV = We @ W{q,k,v} [11,128], M2 = WeQ@WeK^T
// ---------------------------------------------------------------------------
__global__ __launch_bounds__(128) void k_small(
    const float* __restrict__ WeW, const float* __restrict__ WqW,
    const float* __restrict__ WkW, const float* __restrict__ WvW,
    float* __restrict__ WeQ, float* __restrict__ WeK, float* __restrict__ WeV,
    float* __restrict__ M2)
{
  int ch = blockIdx.x;
  const float* We = WeW + (size_t)ch * EF_ * 128;
  const float* Wq = WqW + (size_t)ch * 128 * 128;
  const float* Wk = WkW + (size_t)ch * 128 * 128;
  const float* Wv = WvW + (size_t)ch * 128 * 128;
  __shared__ float sWe[EF_ * 128], sQ[EF_ * 128], sK[EF_ * 128];
  int d = threadIdx.x;
  for (int i = d; i < EF_ * 128; i += 128) sWe[i] = We[i];
  __syncthreads();
  for (int f = 0; f < EF_; f++) {
    float aq = 0.f, ak = 0.f, av = 0.f;
    for (int k = 0; k < 128; k++) {
      float w = sWe[f * 128 + k];
      aq += w * Wq[k * 128 + d];
      ak += w * Wk[k * 128 + d];
      av += w * Wv[k * 128 + d];
    }
    WeQ[(size_t)ch * EF_ * 128 + f * 128 + d] = aq;
    WeK[(size_t)ch * EF_ * 128 + f * 128 + d] = ak;
    WeV[(size_t)ch * EF_ * 128 + f * 128 + d] = av;
    sQ[f * 128 + d] = aq;
    sK[f * 128 + d] = ak;
  }
  __syncthreads();
  if (d < EF_ * EF_) {
    int a = d / EF_, b = d % EF_;
    float s = 0.f;
    for (int k = 0; k < 128; k++) s += sQ[a * 128 + k] * sK[b * 128 + k];
    M2[(size_t)ch * (EF_ * EF_) + d] = s;
  }
}

// ---------------------------------------------------------------------------
// B = Zq @ WeK^T, C = Zk @ WeQ^T -> [N*H,11]; ss[n,h] = Zq.Zk.
// Z is interleaved bf16 ZQKV [N][H][3][128].
// ---------------------------------------------------------------------------
__global__ __launch_bounds__(256) void k_bc(
    const unsigned short* __restrict__ Z,
    const float* __restrict__ WeQ, const float* __restrict__ WeK,
    float* __restrict__ Bm, float* __restrict__ Cm, float* __restrict__ ss,
    int N, int layer)
{
  int wave = threadIdx.x >> 6, lane = threadIdx.x & 63;
  int n = blockIdx.x, h = wave;
  size_t nb = (size_t)n * 1536 + h * 384 + 2 * lane;
  unsigned uq = *(const unsigned*)(Z + nb);
  unsigned uk = *(const unsigned*)(Z + nb + 128);
  float2 zq, zk;
  zq.x = __uint_as_float(uq << 16); zq.y = __uint_as_float(uq & 0xffff0000u);
  zk.x = __uint_as_float(uk << 16); zk.y = __uint_as_float(uk & 0xffff0000u);
  const float* wq = WeQ + (size_t)(layer * H_ + h) * EF_ * 128;
  const float* wk = WeK + (size_t)(layer * H_ + h) * EF_ * 128;
  int task = n * H_ + h;
  float pss = zq.x * zk.x + zq.y * zk.y;
#pragma unroll
  for (int m = 32; m; m >>= 1) pss += __shfl_xor(pss, m, 64);
  if (lane == 0) ss[task] = pss;
  for (int f = 0; f < EF_; f++) {
    float2 a = *(const float2*)&wk[f * 128 + 2 * lane];
    float2 b = *(const float2*)&wq[f * 128 + 2 * lane];
    float pb = zq.x * a.x + zq.y * a.y;
    float pc = zk.x * b.x + zk.y * b.y;
#pragma unroll
    for (int m = 32; m; m >>= 1) {
      pb += __shfl_xor(pb, m, 64);
      pc += __shfl_xor(pc, m, 64);
    }
    if (lane == 0) {
      Bm[(size_t)task * EF_ + f] = pb;
      Cm[(size_t)task * EF_ + f] = pc;
    }
  }
}

// ---------------------------------------------------------------------------
// Per-edge precomputed logits (CSR order): elog[idx][h][6] =
// {ss_s(S00), se(S02), de(S12), es(S20), ed(S21), ee(S22)}
// ---------------------------------------------------------------------------
__global__ __launch_bounds__(256) void k_elog(
    const float* __restrict__ Bm, const float* __restrict__ Cm,
    const float* __restrict__ ss, const float* __restrict__ M2,
    const float* __restrict__ ef_perm, const int* __restrict__ src_perm,
    const int* __restrict__ dst_perm, float* __restrict__ elog,
    int E, int layer)
{
  int i0 = blockIdx.x * 64;
  __shared__ float efs[64 * EF_];
  __shared__ float m2s[4 * EF_ * EF_];
  int t = threadIdx.x;
  for (int i = t; i < 64 * EF_; i += 256) {
    int gi = i0 * EF_ + i;
    efs[i] = (gi < E * EF_) ? ef_perm[gi] : 0.f;
  }
  for (int i = t; i < 4 * EF_ * EF_; i += 256)
    m2s[i] = M2[(size_t)layer * 4 * EF_ * EF_ + i];
  __syncthreads();
  int sl = t >> 2, h = t & 3;
  int idx = i0 + sl;
  if (idx < E) {
    int s = src_perm[idx], d = dst_perm[idx];
    const float* ef = &efs[sl * EF_];
    const float* m2 = &m2s[h * EF_ * EF_];
    float ee = 0.f;
#pragma unroll
    for (int a = 0; a < EF_; a++) {
      float r = 0.f;
#pragma unroll
      for (int b = 0; b < EF_; b++) r += m2[a * EF_ + b] * ef[b];
      ee += ef[a] * r;
    }
    const float* bs = Bm + (size_t)(s * H_ + h) * EF_;
    const float* cs = Cm + (size_t)(s * H_ + h) * EF_;
    const float* bd = Bm + (size_t)(d * H_ + h) * EF_;
    const float* cd = Cm + (size_t)(d * H_ + h) * EF_;
    float se = 0.f, es = 0.f, de = 0.f, ed = 0.f;
#pragma unroll
    for (int f = 0; f < EF_; f++) {
      float e = ef[f];
      se += bs[f] * e;
      es += cs[f] * e;
      de += bd[f] * e;
      ed += cd[f] * e;
    }
    float* o = elog + ((size_t)idx * H_ + h) * 6;
    o[0] = ss[s * H_ + h];
    o[1] = se; o[2] = de; o[3] = es; o[4] = ed; o[5] = ee;
  }
}

// ---------------------------------------------------------------------------
// Edge aggregation: wave per (dst,head); 16-lane groups x 4 edges; fused
// softmax + mean + ReLU + LayerNorm. ZQKV interleaved bf16.
// ---------------------------------------------------------------------------
__global__ __launch_bounds__(256) void k_edge(
    const unsigned short* __restrict__ Z, const float* __restrict__ ss,
    const float* __restrict__ elog, const float* __restrict__ ef_perm,
    const int* __restrict__ rowp, const int* __restrict__ src_perm,
    const float* __restrict__ WeV, const float* __restrict__ lng,
    const float* __restrict__ lnb, float* __restrict__ heads,
    int N, int layer)
{
  const int h = threadIdx.x >> 6;
  const int lane = threadIdx.x & 63;
  const int q = lane & 15;        // d-slice index (8 floats each)
  const int g = lane >> 4;        // edge group 0..3
  const int lb = lane & 48;       // group base lane
  const int n = blockIdx.x;
  const size_t nb3 = (size_t)n * 1536 + h * 384 + q * 8;

  float zqd[8], zkd[8], zvd[8];
  unpack8(*(const uint4*)(Z + nb3), zqd);
  unpack8(*(const uint4*)(Z + nb3 + 128), zkd);
  unpack8(*(const uint4*)(Z + nb3 + 256), zvd);
  const float ssd = ss[n * H_ + h];
  const int beg = rowp[n], end = rowp[n + 1];
  float acc[8];
#pragma unroll
  for (int i = 0; i < 8; i++) acc[i] = 0.f;
  float wdsum = 0.f, a11 = 0.f;

  for (int idx0 = beg; idx0 < end; idx0 += 4) {
    int idxg = idx0 + g;
    bool act = idxg < end;
    int idxc = act ? idxg : beg;
    int s = src_perm[idxc];
    size_t sb3 = (size_t)s * 1536 + h * 384 + q * 8;
    float zqs[8], zks[8], zvs[8];
    unpack8(*(const uint4*)(Z + sb3), zqs);
    unpack8(*(const uint4*)(Z + sb3 + 128), zks);
    unpack8(*(const uint4*)(Z + sb3 + 256), zvs);
    float v1 = 0.f, v2 = 0.f;
#pragma unroll
    for (int i = 0; i < 8; i++) {
      v1 += zqs[i] * zkd[i];
      v2 += zqd[i] * zks[i];
    }
#pragma unroll
    for (int m = 1; m < 16; m <<= 1) {
      v1 += __shfl_xor(v1, m, 64);
      v2 += __shfl_xor(v2, m, 64);
    }
    float lv = (q < 6) ? elog[((size_t)idxc * H_ + h) * 6 + q] : 0.f;
    float S00 = __shfl(lv, lb + 0, 64);
    float S02 = __shfl(lv, lb + 1, 64);
    float S12 = __shfl(lv, lb + 2, 64);
    float S20 = __shfl(lv, lb + 3, 64);
    float S21 = __shfl(lv, lb + 4, 64);
    float S22 = __shfl(lv, lb + 5, 64);
    // rows: [s: S00 v1 S02] [d: v2 ssd S12] [e: S20 S21 S22]
    float m0 = fmaxf(fmaxf(S00, v1), S02);
    float e00 = __expf(S00 - m0), e01 = __expf(v1 - m0), e02 = __expf(S02 - m0);
    float i0r = 1.f / (e00 + e01 + e02);
    float m1 = fmaxf(fmaxf(v2, ssd), S12);
    float e10 = __expf(v2 - m1), e11 = __expf(ssd - m1), e12 = __expf(S12 - m1);
    float i1r = 1.f / (e10 + e11 + e12);
    float m2 = fmaxf(fmaxf(S20, S21), S22);
    float e20 = __expf(S20 - m2), e21 = __expf(S21 - m2), e22 = __expf(S22 - m2);
    float i2r = 1.f / (e20 + e21 + e22);
    float w0 = e00 * i0r + e10 * i1r + e20 * i2r;
    float w1 = e01 * i0r + e11 * i1r + e21 * i2r;
    float w2 = e02 * i0r + e12 * i1r + e22 * i2r;
    if (!act) { w0 = 0.f; w1 = 0.f; w2 = 0.f; }
#pragma unroll
    for (int i = 0; i < 8; i++) acc[i] += w0 * zvs[i];
    wdsum += w1;
    float efl = (q < EF_) ? ef_perm[(size_t)idxc * EF_ + q] : 0.f;
    a11 += w2 * efl;
  }
  // reduce across the 4 edge-groups
#pragma unroll
  for (int m = 16; m < 64; m <<= 1) {
#pragma unroll
    for (int i = 0; i < 8; i++) acc[i] += __shfl_xor(acc[i], m, 64);
    wdsum += __shfl_xor(wdsum, m, 64);
    a11 += __shfl_xor(a11, m, 64);
  }
#pragma unroll
  for (int i = 0; i < 8; i++) acc[i] += wdsum * zvd[i];
  const float* wv = WeV + (size_t)(layer * H_ + h) * EF_ * 128;
#pragma unroll
  for (int f = 0; f < EF_; f++) {
    float af = __shfl(a11, f, 64);
    float4 wa = *(const float4*)(wv + f * 128 + q * 8);
    float4 wb = *(const float4*)(wv + f * 128 + q * 8 + 4);
    acc[0] += af * wa.x; acc[1] += af * wa.y; acc[2] += af * wa.z; acc[3] += af * wa.w;
    acc[4] += af * wb.x; acc[5] += af * wb.y; acc[6] += af * wb.z; acc[7] += af * wb.w;
  }
  int cnt = end - beg;
  float invc = (cnt > 0) ? 1.f / (float)cnt : 1.f;
  float mv[8];
  float s1 = 0.f;
#pragma unroll
  for (int i = 0; i < 8; i++) { mv[i] = fmaxf(acc[i] * invc, 0.f); s1 += mv[i]; }
#pragma unroll
  for (int m = 1; m < 16; m <<= 1) s1 += __shfl_xor(s1, m, 64);
  float mean = s1 * (1.f / 128.f);
  float s2 = 0.f;
#pragma unroll
  for (int i = 0; i < 8; i++) { float d = mv[i] - mean; s2 += d * d; }
#pragma unroll
  for (int m = 1; m < 16; m <<= 1) s2 += __shfl_xor(s2, m, 64);
  float rstd = rsqrtf(s2 * (1.f / 128.f) + 1e-5f);
  if (g == 0) {
    int gi = (layer * H_ + h) * 128 + q * 8;
    float4 ga = *(const float4*)(lng + gi);
    float4 gb = *(const float4*)(lng + gi + 4);
    float4 ba = *(const float4*)(lnb + gi);
    float4 bb = *(const float4*)(lnb + gi + 4);
    float4 o1, o2;
    o1.x = (mv[0] - mean) * rstd * ga.x + ba.x;
    o1.y = (mv[1] - mean) * rstd * ga.y + ba.y;
    o1.z = (mv[2] - mean) * rstd * ga.z + ba.z;
    o1.w = (mv[3] - mean) * rstd * ga.w + ba.w;
    o2.x = (mv[4] - mean) * rstd * gb.x + bb.x;
    o2.y = (mv[5] - mean) * rstd * gb.y + bb.y;
    o2.z = (mv[6] - mean) * rstd * gb.z + bb.z;
    o2.w = (mv[7] - mean) * rstd * gb.w + bb.w;
    size_t ob = (size_t)n * 512 + h * 128 + q * 8;
    *(float4*)(heads + ob) = o1;
    *(float4*)(heads + ob + 4) = o2;
  }
}

// ---------------------------------------------------------------------------
// Segment mean by graph id (node_gid sorted): one block per graph.
// ---------------------------------------------------------------------------
__global__ void k_gmean(const float* __restrict__ X, const int* __restrict__ gid,
                        float* __restrict__ outp, int N, int ld)
{
  int g = blockIdx.x;
  int lo = 0, hi = N;
  while (lo < hi) { int m = (lo + hi) >> 1; if (gid[m] < g) lo = m + 1; else hi = m; }
  int s0 = lo;
  lo = s0; hi = N;
  while (lo < hi) { int m = (lo + hi) >> 1; if (gid[m] < g + 1) lo = m + 1; else hi = m; }
  int s1 = lo;
  float inv = 1.f / (float)((s1 - s0) > 0 ? (s1 - s0) : 1);
  for (int d = threadIdx.x; d < ld; d += blockDim.x) {
    float s = 0.f;
    for (int n = s0; n < s1; n++) s += X[(size_t)n * ld + d];
    outp[(size_t)g * ld + d] = s * inv;
  }
}

// ---------------------------------------------------------------------------
// GRU pass: block = (graph, dir), 128 threads.
// ---------------------------------------------------------------------------
__global__ __launch_bounds__(128) void k_gru(
    const float* __restrict__ seq, int inDim,
    const float* __restrict__ Wih, const float* __restrict__ Whh,
    const float* __restrict__ bih, const float* __restrict__ bhh,
    float* __restrict__ yout, float* __restrict__ hfinal)
{
  int g = blockIdx.x, dir = blockIdx.y, d = threadIdx.x;
  const float* Wih_d = Wih + (size_t)dir * inDim * 384;
  const float* Whh_d = Whh + (size_t)dir * 128 * 384;
  const float* bih_d = bih + dir * 384;
  const float* bhh_d = bhh + dir * 384;
  __shared__ float xb[256];
  __shared__ float hb[128];
  float h = 0.f;
  for (int st = 0; st < T_; st++) {
    int t = dir ? (T_ - 1 - st) : st;
    for (int k = d; k < inDim; k += 128) xb[k] = seq[((size_t)t * G_ + g) * inDim + k];
    hb[d] = h;
    __syncthreads();
    float gr = bih_d[d], gz = bih_d[128 + d], gn = bih_d[256 + d];
    for (int k = 0; k < inDim; k++) {
      float xv = xb[k];
      const float* wr = Wih_d + (size_t)k * 384;
      gr += xv * wr[d];
      gz += xv * wr[128 + d];
      gn += xv * wr[256 + d];
    }
    float hr = bhh_d[d], hz = bhh_d[128 + d], hn = bhh_d[256 + d];
    for (int k = 0; k < 128; k++) {
      float hv = hb[k];
      const float* wr = Whh_d + (size_t)k * 384;
      hr += hv * wr[d];
      hz += hv * wr[128 + d];
      hn += hv * wr[256 + d];
    }
    float r  = 1.f / (1.f + __expf(-(gr + hr)));
    float zg = 1.f / (1.f + __expf(-(gz + hz)));
    float ng = tanhf(gn + r * hn);
    h = (1.f - zg) * ng + zg * h;
    if (yout) yout[((size_t)t * G_ + g) * 256 + dir * 128 + d] = h;
    __syncthreads();
  }
  hfinal[((size_t)dir * G_ + g) * 128 + d] = h;
}

__global__ void k_final(const float* __restrict__ fp, float* __restrict__ outp, int n)
{
  int i = blockIdx.x * blockDim.x + threadIdx.x;
  if (i < n) {
    outp[i] = fp[i] + fp[G_ * 128 + i] + fp[2 * G_ * 128 + i] + fp[3 * G_ * 128 + i];
  }
}

// ---------------------------------------------------------------------------
extern "C" void kernel_launch(void* const* d_in, const int* in_sizes, int n_in,
                              void* d_out, int out_size, void* d_ws, size_t ws_size,
                              hipStream_t stream)
{
  (void)n_in; (void)ws_size;
  const float* h0   = (const float*)d_in[0];
  const float* e_f  = (const float*)d_in[1];
  const int*   srcI = (const int*)d_in[2];
  const int*   dstI = (const int*)d_in[3];
  const int*   gid  = (const int*)d_in[4];
  const float* lin0 = (const float*)d_in[6];
  const float* linW = (const float*)d_in[7];
  const float* WeW  = (const float*)d_in[8];
  const float* WqW  = (const float*)d_in[9];
  const float* WkW  = (const float*)d_in[10];
  const float* WvW  = (const float*)d_in[11];
  const float* lng  = (const float*)d_in[12];
  const float* lnb  = (const float*)d_in[13];
  const float* outW = (const float*)d_in[14];
  const float* outb = (const float*)d_in[15];
  const float* projW= (const float*)d_in[16];
  const float* projb= (const float*)d_in[17];
  const float* Wih0 = (const float*)d_in[18];
  const float* Whh0 = (const float*)d_in[19];
  const float* bih0 = (const float*)d_in[20];
  const float* bhh0 = (const float*)d_in[21];
  const float* Wih1 = (const float*)d_in[22];
  const float* Whh1 = (const float*)d_in[23];
  const float* bih1 = (const float*)d_in[24];
  const float* bhh1 = (const float*)d_in[25];
  float* outp = (float*)d_out;

  const int N = in_sizes[0] / INF_;
  const int E = in_sizes[2];

  char* wp = (char*)d_ws;
  auto alloc = [&](size_t bytes) -> void* {
    void* p = (void*)wp;
    wp += (bytes + 255) & ~(size_t)255;
    return p;
  };
  unsigned short* ZQKV = (unsigned short*)alloc((size_t)N * 1536 * 2);
  float* zh   = (float*)alloc((size_t)N * 512 * 4);       // z, then heads_out
  float* hcur = (float*)alloc((size_t)N * 128 * 4);
  float* Bm   = (float*)alloc((size_t)N * H_ * EF_ * 4);
  float* Cm   = (float*)alloc((size_t)N * H_ * EF_ * 4);
  float* ssb  = (float*)alloc((size_t)N * H_ * 4);
  float* elog = (float*)alloc((size_t)E * H_ * 6 * 4);
  float* efp  = (float*)alloc((size_t)E * EF_ * 4);
  float* WeQ  = (float*)alloc((size_t)C_ * H_ * EF_ * 128 * 4);
  float* WeK  = (float*)alloc((size_t)C_ * H_ * EF_ * 128 * 4);
  float* WeV  = (float*)alloc((size_t)C_ * H_ * EF_ * 128 * 4);
  float* M2   = (float*)alloc((size_t)C_ * H_ * EF_ * EF_ * 4);
  // bf16 transposed weights
  unsigned short* linBt0 = (unsigned short*)alloc((size_t)4 * 128 * INF_ * 2);
  unsigned short* linBt12= (unsigned short*)alloc((size_t)2 * 512 * 128 * 2);
  unsigned short* qkvBt  = (unsigned short*)alloc((size_t)C_ * H_ * 3 * 128 * 128 * 2);
  unsigned short* outBt  = (unsigned short*)alloc((size_t)C_ * 128 * 512 * 2);
  unsigned short* projBt = (unsigned short*)alloc((size_t)128 * INF_ * 2);
  int* deg    = (int*)alloc((size_t)N * 4);
  int* cursor = (int*)alloc((size_t)N * 4);
  int* rowp   = (int*)alloc((size_t)(N + 1) * 4);
  int* eids   = (int*)alloc((size_t)E * 4);
  int* srcp   = (int*)alloc((size_t)E * 4);
  int* dstp   = (int*)alloc((size_t)E * 4);
  float* gm74 = (float*)alloc((size_t)G_ * INF_ * 4);
  float* seq  = (float*)alloc((size_t)T_ * G_ * 128 * 4);
  float* seq1 = (float*)alloc((size_t)T_ * G_ * 256 * 4);
  float* fparts=(float*)alloc((size_t)4 * G_ * 128 * 4);

  const int gM = (N + 127) / 128;

  // --- CSR build + permuted metadata ---
  hipMemsetAsync(deg, 0, (size_t)N * 4, stream);
  hipMemsetAsync(cursor, 0, (size_t)N * 4, stream);
  k_hist<<<(E + 255) / 256, 256, 0, stream>>>(dstI, deg, E);
  k_scan<<<1, 1024, 0, stream>>>(deg, rowp, N);
  k_fill<<<(E + 255) / 256, 256, 0, stream>>>(srcI, dstI, rowp, cursor,
                                              eids, srcp, dstp, E);
  k_efperm<<<(E * EF_ + 255) / 256, 256, 0, stream>>>(e_f, eids, efp, E);

  // --- folded small weights ---
  k_small<<<C_ * H_, 128, 0, stream>>>(WeW, WqW, WkW, WvW, WeQ, WeK, WeV, M2);

  // --- transpose+convert all GEMM weights to bf16 [N][K] ---
  WPack wpk;
  int nw = 0;
  auto addw = [&](const float* s, unsigned short* d, int K, int D) {
    wpk.d[nw].src = s; wpk.d[nw].dst = d; wpk.d[nw].K = K; wpk.d[nw].D = D; nw++;
  };
  for (int h = 0; h < 4; h++)
    addw(lin0 + (size_t)h * INF_ * 128, linBt0 + (size_t)h * 128 * INF_, INF_, 128);
  for (int j = 1; j < 3; j++)
    for (int h = 0; h < 4; h++)
      addw(linW + ((size_t)(j - 1) * 4 + h) * 16384,
           linBt12 + (size_t)(j - 1) * 65536 + (size_t)h * 16384, 128, 128);
  for (int j = 0; j < 3; j++)
    for (int h = 0; h < 4; h++) {
      size_t ch = (size_t)j * 4 + h;
      addw(WqW + ch * 16384, qkvBt + (ch * 3 + 0) * 16384, 128, 128);
      addw(WkW + ch * 16384, qkvBt + (ch * 3 + 1) * 16384, 128, 128);
      addw(WvW + ch * 16384, qkvBt + (ch * 3 + 2) * 16384, 128, 128);
    }
  for (int j = 0; j < 3; j++)
    addw(outW + (size_t)j * 65536, outBt + (size_t)j * 65536, 512, 128);
  addw(projW, projBt, INF_, 128);
  k_wcvt<<<dim3(32, NW_), 256, 0, stream>>>(wpk);

  // --- GRU input t=0: seg-mean(h0) then proj ---
  k_gmean<<<G_, 128, 0, stream>>>(h0, gid, gm74, N, INF_);
  k_mfma<<<dim3(4, 1, 1), 256, 0, stream>>>(
      gm74, INF_, 0, G_, INF_, projBt, 0, 0,
      seq, 128, 0, projb, nullptr, 0, 0, 0);

  // --- conv layers ---
  for (int j = 0; j < C_; j++) {
    // lin: zh[N,512] = A @ linBt (4 col-blocks)
    if (j == 0)
      k_mfma<<<dim3(gM, 4, 1), 256, 0, stream>>>(
          h0, INF_, 0, N, INF_, linBt0, 128 * INF_, 0,
          zh, 512, 128, nullptr, nullptr, 0, 0, 0);
    else
      k_mfma<<<dim3(gM, 4, 1), 256, 0, stream>>>(
          hcur, 128, 0, N, 128, linBt12 + (size_t)(j - 1) * 65536, 16384, 0,
          zh, 512, 128, nullptr, nullptr, 0, 0, 0);
    // qkv: ZQKV[N][H][3][128] bf16; y = q/k/v, z = head
    k_mfma<<<dim3(gM, 3, 4), 256, 0, stream>>>(
        zh, 512, 128, N, 128, qkvBt + (size_t)j * 4 * 3 * 16384, 16384, 3 * 16384,
        nullptr, 0, 0, nullptr, ZQKV, 1536, 128, 384);
    k_bc<<<N, 256, 0, stream>>>(ZQKV, WeQ, WeK, Bm, Cm, ssb, N, j);
    k_elog<<<(E + 63) / 64, 256, 0, stream>>>(Bm, Cm, ssb, M2, efp, srcp, dstp,
                                              elog, E, j);
    k_edge<<<N, 256, 0, stream>>>(ZQKV, ssb, elog, efp, rowp, srcp,
                                  WeV, lng, lnb, zh, N, j);
    // out: hcur[N,128] = zh @ outBt + bias
    k_mfma<<<dim3(gM, 1, 1), 256, 0, stream>>>(
        zh, 512, 0, N, 512, outBt + (size_t)j * 65536, 0, 0,
        hcur, 128, 0, outb + j * 128, nullptr, 0, 0, 0);
    k_gmean<<<G_, 128, 0, stream>>>(hcur, gid, seq + (size_t)(j + 1) * G_ * 128, N, 128);
  }

  // --- GRU readout ---
  k_gru<<<dim3(G_, 2), 128, 0, stream>>>(seq, 128, Wih0, Whh0, bih0, bhh0,
                                         seq1, fparts);
  k_gru<<<dim3(G_, 2), 128, 0, stream>>>(seq1, 256, Wih1, Whh1, bih1, bhh1,
                                         nullptr, fparts + 2 * G_ * 128);
  k_final<<<(out_size + 255) / 256, 256, 0, stream>>>(fparts, outp, out_size);
}

// Round 5
// 1647.467 us; speedup vs baseline: 2.0526x; 1.0930x over previous
//
#include <hip/hip_runtime.h>
#include <cstdint>

#define D_   128
#define H_   4
#define C_   3
#define G_   512
#define INF_ 74
#define EF_  11
#define T_   4
#define NW_  48

typedef __attribute__((ext_vector_type(8))) short bf16x8;
typedef __attribute__((ext_vector_type(4))) float f32x4;

__device__ inline unsigned short f2bf(float x) {
  unsigned u = __float_as_uint(x);
  unsigned r = u + 0x7fffu + ((u >> 16) & 1u);
  return (unsigned short)(r >> 16);
}
__device__ inline void unpack8(uint4 u, float* f) {
  f[0] = __uint_as_float(u.x << 16); f[1] = __uint_as_float(u.x & 0xffff0000u);
  f[2] = __uint_as_float(u.y << 16); f[3] = __uint_as_float(u.y & 0xffff0000u);
  f[4] = __uint_as_float(u.z << 16); f[5] = __uint_as_float(u.z & 0xffff0000u);
  f[6] = __uint_as_float(u.w << 16); f[7] = __uint_as_float(u.w & 0xffff0000u);
}

// ---------------------------------------------------------------------------
// Weight convert: trans ? dst[d*K+k]=bf16(src[k*D+d]) : dst[i]=bf16(src[i])
// ---------------------------------------------------------------------------
struct WDesc { const float* src; unsigned short* dst; int K; int D; int trans; };
struct WPack { WDesc d[NW_]; };

__global__ __launch_bounds__(256) void k_wcvt(WPack wp)
{
  WDesc w = wp.d[blockIdx.y];
  int tot = w.K * w.D;
  for (int i = blockIdx.x * 256 + threadIdx.x; i < tot; i += gridDim.x * 256) {
    if (w.trans) {
      int d = i / w.K, k = i - d * w.K;
      w.dst[i] = f2bf(w.src[(size_t)k * w.D + d]);
    } else {
      w.dst[i] = f2bf(w.src[i]);
    }
  }
}

// ---------------------------------------------------------------------------
// MFMA bf16 GEMM, A f32 (converted in staging) or bf16. 128x128 tile,
// 4 waves 2x2, mfma_f32_16x16x32_bf16. Out: f32 (+bias) or bf16.
// ---------------------------------------------------------------------------
template <typename AT>
__global__ __launch_bounds__(256) void k_mfma(
    const AT* __restrict__ A, int lda, int aOffZ, int M, int K,
    const unsigned short* __restrict__ Bt, int btOffY, int btOffZ,
    float* __restrict__ outF, int ldc, int cOffY, int cOffZ,
    const float* __restrict__ bias,
    unsigned short* __restrict__ outH, int hStride, int hOffY, int hOffZ)
{
  const int bx = blockIdx.x, by = blockIdx.y, bz = blockIdx.z;
  A += (size_t)bz * aOffZ;
  const unsigned short* Bp = Bt + (size_t)by * btOffY + (size_t)bz * btOffZ;
  const int rowBase = bx * 128;
  __shared__ unsigned short As[128][40];
  __shared__ unsigned short Bs[128][40];
  const int t = threadIdx.x;
  const int w = t >> 6, l = t & 63;
  const int wr = w >> 1, wc = w & 1;
  const int fr = l & 15, fq = l >> 4;
  f32x4 acc[4][4];
#pragma unroll
  for (int m = 0; m < 4; m++)
#pragma unroll
    for (int n = 0; n < 4; n++) acc[m][n] = (f32x4){0.f, 0.f, 0.f, 0.f};

  const int sr = t >> 1, sh = t & 1;
  const int arow = rowBase + sr;
  const AT* aBase = A + (size_t)arow * lda;

  for (int k0 = 0; k0 < K; k0 += 32) {
    int kb = k0 + sh * 16;
    if constexpr (sizeof(AT) == 4) {
      unsigned short tmp[16];
      if (arow < M && kb + 16 <= K) {
        const AT* ap = aBase + kb;
#pragma unroll
        for (int i = 0; i < 16; i++) tmp[i] = f2bf(ap[i]);
      } else {
#pragma unroll
        for (int i = 0; i < 16; i++) {
          int gk = kb + i;
          float v = (arow < M && gk < K) ? (float)aBase[gk] : 0.f;
          tmp[i] = f2bf(v);
        }
      }
      *(uint4*)&As[sr][sh * 16]     = *(const uint4*)&tmp[0];
      *(uint4*)&As[sr][sh * 16 + 8] = *(const uint4*)&tmp[8];
    } else {
      if (arow < M && kb + 16 <= K) {
        const unsigned short* ap = (const unsigned short*)aBase + kb;
        *(uint4*)&As[sr][sh * 16]     = *(const uint4*)(ap);
        *(uint4*)&As[sr][sh * 16 + 8] = *(const uint4*)(ap + 8);
      } else {
#pragma unroll
        for (int i = 0; i < 16; i++) {
          int gk = kb + i;
          As[sr][sh * 16 + i] = (arow < M && gk < K)
              ? ((const unsigned short*)aBase)[gk] : (unsigned short)0;
        }
      }
    }
    if (t < 128) {
      unsigned short tmp[32];
      if (k0 + 32 <= K) {
        const unsigned short* bp = Bp + (size_t)t * K + k0;
#pragma unroll
        for (int i = 0; i < 32; i++) tmp[i] = bp[i];
      } else {
#pragma unroll
        for (int i = 0; i < 32; i++) {
          int gk = k0 + i;
          tmp[i] = (gk < K) ? Bp[(size_t)t * K + gk] : (unsigned short)0;
        }
      }
#pragma unroll
      for (int i = 0; i < 4; i++) *(uint4*)&Bs[t][i * 8] = *(const uint4*)&tmp[i * 8];
    }
    __syncthreads();
    bf16x8 af[4], bfr[4];
#pragma unroll
    for (int m = 0; m < 4; m++) af[m]  = *(const bf16x8*)&As[wr * 64 + m * 16 + fr][fq * 8];
#pragma unroll
    for (int n = 0; n < 4; n++) bfr[n] = *(const bf16x8*)&Bs[wc * 64 + n * 16 + fr][fq * 8];
#pragma unroll
    for (int m = 0; m < 4; m++)
#pragma unroll
      for (int n = 0; n < 4; n++)
        acc[m][n] = __builtin_amdgcn_mfma_f32_16x16x32_bf16(af[m], bfr[n], acc[m][n], 0, 0, 0);
    __syncthreads();
  }
#pragma unroll
  for (int m = 0; m < 4; m++) {
    int row0 = rowBase + wr * 64 + m * 16 + fq * 4;
#pragma unroll
    for (int n = 0; n < 4; n++) {
      int col = wc * 64 + n * 16 + fr;
#pragma unroll
      for (int r = 0; r < 4; r++) {
        int row = row0 + r;
        if (row < M) {
          float v = acc[m][n][r];
          if (outH) {
            outH[(size_t)row * hStride + by * hOffY + bz * hOffZ + col] = f2bf(v);
          } else {
            if (bias) v += bias[col];
            outF[(size_t)row * ldc + by * cOffY + bz * cOffZ + col] = v;
          }
        }
      }
    }
  }
}

// ---------------------------------------------------------------------------
// CSR build (by dst) + permuted metadata
// ---------------------------------------------------------------------------
__global__ void k_hist(const int* __restrict__ dst, int* __restrict__ deg, int E)
{
  int e = blockIdx.x * blockDim.x + threadIdx.x;
  if (e < E) atomicAdd(&deg[dst[e]], 1);
}

__global__ __launch_bounds__(1024) void k_scan(const int* __restrict__ deg,
                                               int* __restrict__ rowp, int N)
{
  __shared__ int part[1024];
  int t = threadIdx.x;
  int chunk = (N + 1023) / 1024;
  int base = t * chunk;
  int s = 0;
  for (int i = 0; i < chunk; i++) { int idx = base + i; if (idx < N) s += deg[idx]; }
  part[t] = s;
  __syncthreads();
  for (int off = 1; off < 1024; off <<= 1) {
    int v = (t >= off) ? part[t - off] : 0;
    __syncthreads();
    part[t] += v;
    __syncthreads();
  }
  int run = part[t] - s;
  for (int i = 0; i < chunk; i++) {
    int idx = base + i;
    if (idx < N) { rowp[idx] = run; run += deg[idx]; }
  }
  if (t == 1023) rowp[N] = part[1023];
}

__global__ void k_fill(const int* __restrict__ src, const int* __restrict__ dst,
                       const int* __restrict__ rowp, int* __restrict__ cursor,
                       int* __restrict__ eids, int* __restrict__ src_perm,
                       int* __restrict__ dst_perm, int E)
{
  int e = blockIdx.x * blockDim.x + threadIdx.x;
  if (e < E) {
    int d = dst[e];
    int pos = atomicAdd(&cursor[d], 1);
    int slot = rowp[d] + pos;
    eids[slot] = e;
    src_perm[slot] = src[e];
    dst_perm[slot] = d;
  }
}

__global__ void k_efperm(const float* __restrict__ e_f, const int* __restrict__ eids,
                         float* __restrict__ ef_perm, int E)
{
  int i = blockIdx.x * blockDim.x + threadIdx.x;
  if (i < E * EF_) {
    int idx = i / EF_, f = i - idx * EF_;
    ef_perm[i] = e_f[(size_t)eids[idx] * EF_ + f];
  }
}

// ---------------------------------------------------------------------------
// Small weight folding: WeQ/WeK/WeV = We@W{q,k,v} [11,128]; M2 = WeQ@WeK^T;
// GqT[f][d] = (Wq WeK^T)^T, GcT[f][d] = (Wk WeQ^T)^T  (for B/C from Z).
// ---------------------------------------------------------------------------
__global__ __launch_bounds__(128) void k_small(
    const float* __restrict__ WeW, const float* __restrict__ WqW,
    const float* __restrict__ WkW, const float* __restrict__ WvW,
    float* __restrict__ WeQ, float* __restrict__ WeK, float* __restrict__ WeV,
    float* __restrict__ M2, float* __restrict__ GqT, float* __restrict__ GcT)
{
  int ch = blockIdx.x;
  const float* We = WeW + (size_t)ch * EF_ * 128;
  const float* Wq = WqW + (size_t)ch * 128 * 128;
  const float* Wk = WkW + (size_t)ch * 128 * 128;
  const float* Wv = WvW + (size_t)ch * 128 * 128;
  __shared__ float sWe[EF_ * 128], sQ[EF_ * 128], sK[EF_ * 128];
  int d = threadIdx.x;
  for (int i = d; i < EF_ * 128; i += 128) sWe[i] = We[i];
  __syncthreads();
  for (int f = 0; f < EF_; f++) {
    float aq = 0.f, ak = 0.f, av = 0.f;
    for (int k = 0; k < 128; k++) {
      float w = sWe[f * 128 + k];
      aq += w * Wq[k * 128 + d];
      ak += w * Wk[k * 128 + d];
      av += w * Wv[k * 128 + d];
    }
    WeQ[(size_t)ch * EF_ * 128 + f * 128 + d] = aq;
    WeK[(size_t)ch * EF_ * 128 + f * 128 + d] = ak;
    WeV[(size_t)ch * EF_ * 128 + f * 128 + d] = av;
    sQ[f * 128 + d] = aq;
    sK[f * 128 + d] = ak;
  }
  __syncthreads();
  if (d < EF_ * EF_) {
    int a = d / EF_, b = d % EF_;
    float s = 0.f;
    for (int k = 0; k < 128; k++) s += sQ[a * 128 + k] * sK[b * 128 + k];
    M2[(size_t)ch * (EF_ * EF_) + d] = s;
  }
  // GqT[f][d] = sum_k Wq[d][k]*WeK[f][k]; GcT[f][d] = sum_k Wk[d][k]*WeQ[f][k]
  for (int f = 0; f < EF_; f++) {
    float aq = 0.f, ac = 0.f;
    for (int k = 0; k < 128; k++) {
      aq += Wq[(size_t)d * 128 + k] * sK[f * 128 + k];
      ac += Wk[(size_t)d * 128 + k] * sQ[f * 128 + k];
    }
    GqT[(size_t)ch * EF_ * 128 + f * 128 + d] = aq;
    GcT[(size_t)ch * EF_ * 128 + f * 128 + d] = ac;
  }
}

// ---------------------------------------------------------------------------
// Build combined post-message weight: WvE[ch][out d][k160]:
// k<128 -> Wv[k][d]; 128<=k<139 -> WeV[k-128][d]; else 0.
// ---------------------------------------------------------------------------
__global__ __launch_bounds__(128) void k_wve(
    const float* __restrict__ WvW, const float* __restrict__ WeV,
    unsigned short* __restrict__ WvE)
{
  int ch = blockIdx.x;
  const float* Wv  = WvW + (size_t)ch * 16384;
  const float* wev = WeV + (size_t)ch * EF_ * 128;
  unsigned short* dst = WvE + (size_t)ch * 20480;
  for (int i = threadIdx.x; i < 20480; i += 128) {
    int d = i / 160, k = i - d * 160;
    float v = (k < 128) ? Wv[(size_t)k * 128 + d]
            : (k < 128 + EF_) ? wev[(size_t)(k - 128) * 128 + d] : 0.f;
    dst[i] = f2bf(v);
  }
}

// ---------------------------------------------------------------------------
// Per-node: ss = Z.u ; B[f] = Z.GqT[f] ; C[f] = Z.GcT[f]. Wave per (n,h).
// ---------------------------------------------------------------------------
__global__ __launch_bounds__(256) void k_bc(
    const unsigned short* __restrict__ Zb, const float* __restrict__ UT,
    const float* __restrict__ GqT, const float* __restrict__ GcT,
    float* __restrict__ Bm, float* __restrict__ Cm, float* __restrict__ ss,
    int N, int layer)
{
  int h = threadIdx.x >> 6, lane = threadIdx.x & 63;
  int n = blockIdx.x;
  size_t nb = (size_t)n * 512 + h * 128 + 2 * lane;
  unsigned uz = *(const unsigned*)(Zb + nb);
  float2 z;
  z.x = __uint_as_float(uz << 16); z.y = __uint_as_float(uz & 0xffff0000u);
  float2 u = *(const float2*)(UT + (size_t)n * 1024 + h * 256 + 2 * lane);
  const float* gq = GqT + (size_t)(layer * H_ + h) * EF_ * 128;
  const float* gc = GcT + (size_t)(layer * H_ + h) * EF_ * 128;
  int task = n * H_ + h;
  float pss = z.x * u.x + z.y * u.y;
#pragma unroll
  for (int m = 32; m; m >>= 1) pss += __shfl_xor(pss, m, 64);
  if (lane == 0) ss[task] = pss;
  for (int f = 0; f < EF_; f++) {
    float2 a = *(const float2*)&gq[f * 128 + 2 * lane];
    float2 b = *(const float2*)&gc[f * 128 + 2 * lane];
    float pb = z.x * a.x + z.y * a.y;
    float pc = z.x * b.x + z.y * b.y;
#pragma unroll
    for (int m = 32; m; m >>= 1) {
      pb += __shfl_xor(pb, m, 64);
      pc += __shfl_xor(pc, m, 64);
    }
    if (lane == 0) {
      Bm[(size_t)task * EF_ + f] = pb;
      Cm[(size_t)task * EF_ + f] = pc;
    }
  }
}

// ---------------------------------------------------------------------------
// Per-edge precomputed logits: elog[idx][h][6] = {ss_s, se, de, es, ed, ee}
// ---------------------------------------------------------------------------
__global__ __launch_bounds__(256) void k_elog(
    const float* __restrict__ Bm, const float* __restrict__ Cm,
    const float* __restrict__ ss, const float* __restrict__ M2,
    const float* __restrict__ ef_perm, const int* __restrict__ src_perm,
    const int* __restrict__ dst_perm, float* __restrict__ elog,
    int E, int layer)
{
  int i0 = blockIdx.x * 64;
  __shared__ float efs[64 * EF_];
  __shared__ float m2s[4 * EF_ * EF_];
  int t = threadIdx.x;
  for (int i = t; i < 64 * EF_; i += 256) {
    int gi = i0 * EF_ + i;
    efs[i] = (gi < E * EF_) ? ef_perm[gi] : 0.f;
  }
  for (int i = t; i < 4 * EF_ * EF_; i += 256)
    m2s[i] = M2[(size_t)layer * 4 * EF_ * EF_ + i];
  __syncthreads();
  int sl = t >> 2, h = t & 3;
  int idx = i0 + sl;
  if (idx < E) {
    int s = src_perm[idx], d = dst_perm[idx];
    const float* ef = &efs[sl * EF_];
    const float* m2 = &m2s[h * EF_ * EF_];
    float ee = 0.f;
#pragma unroll
    for (int a = 0; a < EF_; a++) {
      float r = 0.f;
#pragma unroll
      for (int b = 0; b < EF_; b++) r += m2[a * EF_ + b] * ef[b];
      ee += ef[a] * r;
    }
    const float* bs = Bm + (size_t)(s * H_ + h) * EF_;
    const float* cs = Cm + (size_t)(s * H_ + h) * EF_;
    const float* bd = Bm + (size_t)(d * H_ + h) * EF_;
    const float* cd = Cm + (size_t)(d * H_ + h) * EF_;
    float se = 0.f, es = 0.f, de = 0.f, ed = 0.f;
#pragma unroll
    for (int f = 0; f < EF_; f++) {
      float e = ef[f];
      se += bs[f] * e;
      es += cs[f] * e;
      de += bd[f] * e;
      ed += cd[f] * e;
    }
    float* o = elog + ((size_t)idx * H_ + h) * 6;
    o[0] = ss[s * H_ + h];
    o[1] = se; o[2] = de; o[3] = es; o[4] = ed; o[5] = ee;
  }
}

// ---------------------------------------------------------------------------
// Edge aggregation in Z-space: wave per (dst,head); gathers ONLY Z_s (256 B).
// v1 = Zs.u_d, v2 = Zs.t_d. Writes aggZE[n][h][160] = [aggZ(128)|a11(11)|0].
// ---------------------------------------------------------------------------
__global__ __launch_bounds__(256) void k_edge(
    const unsigned short* __restrict__ Zb, const float* __restrict__ UT,
    const float* __restrict__ ss, const float* __restrict__ elog,
    const float* __restrict__ ef_perm, const int* __restrict__ rowp,
    const int* __restrict__ src_perm, float* __restrict__ aggZE, int N)
{
  const int h = threadIdx.x >> 6;
  const int lane = threadIdx.x & 63;
  const int q = lane & 15;
  const int g = lane >> 4;
  const int lb = lane & 48;
  const int n = blockIdx.x;

  float zd[8], ud[8], td[8];
  unpack8(*(const uint4*)(Zb + (size_t)n * 512 + h * 128 + q * 8), zd);
  const float* utp = UT + (size_t)n * 1024 + h * 256 + q * 8;
  {
    float4 a = *(const float4*)(utp), b = *(const float4*)(utp + 4);
    ud[0] = a.x; ud[1] = a.y; ud[2] = a.z; ud[3] = a.w;
    ud[4] = b.x; ud[5] = b.y; ud[6] = b.z; ud[7] = b.w;
    float4 c = *(const float4*)(utp + 128), e = *(const float4*)(utp + 132);
    td[0] = c.x; td[1] = c.y; td[2] = c.z; td[3] = c.w;
    td[4] = e.x; td[5] = e.y; td[6] = e.z; td[7] = e.w;
  }
  const float ssd = ss[n * H_ + h];
  const int beg = rowp[n], end = rowp[n + 1];
  float acc[8];
#pragma unroll
  for (int i = 0; i < 8; i++) acc[i] = 0.f;
  float wdsum = 0.f, a11 = 0.f;

  for (int idx0 = beg; idx0 < end; idx0 += 4) {
    int idxg = idx0 + g;
    bool act = idxg < end;
    int idxc = act ? idxg : beg;
    int s = src_perm[idxc];
    float zs[8];
    unpack8(*(const uint4*)(Zb + (size_t)s * 512 + h * 128 + q * 8), zs);
    float v1 = 0.f, v2 = 0.f;
#pragma unroll
    for (int i = 0; i < 8; i++) {
      v1 += zs[i] * ud[i];
      v2 += zs[i] * td[i];
    }
#pragma unroll
    for (int m = 1; m < 16; m <<= 1) {
      v1 += __shfl_xor(v1, m, 64);
      v2 += __shfl_xor(v2, m, 64);
    }
    float lv = (q < 6) ? elog[((size_t)idxc * H_ + h) * 6 + q] : 0.f;
    float S00 = __shfl(lv, lb + 0, 64);
    float S02 = __shfl(lv, lb + 1, 64);
    float S12 = __shfl(lv, lb + 2, 64);
    float S20 = __shfl(lv, lb + 3, 64);
    float S21 = __shfl(lv, lb + 4, 64);
    float S22 = __shfl(lv, lb + 5, 64);
    float m0 = fmaxf(fmaxf(S00, v1), S02);
    float e00 = __expf(S00 - m0), e01 = __expf(v1 - m0), e02 = __expf(S02 - m0);
    float i0r = 1.f / (e00 + e01 + e02);
    float m1 = fmaxf(fmaxf(v2, ssd), S12);
    float e10 = __expf(v2 - m1), e11 = __expf(ssd - m1), e12 = __expf(S12 - m1);
    float i1r = 1.f / (e10 + e11 + e12);
    float m2 = fmaxf(fmaxf(S20, S21), S22);
    float e20 = __expf(S20 - m2), e21 = __expf(S21 - m2), e22 = __expf(S22 - m2);
    float i2r = 1.f / (e20 + e21 + e22);
    float w0 = e00 * i0r + e10 * i1r + e20 * i2r;
    float w1 = e01 * i0r + e11 * i1r + e21 * i2r;
    float w2 = e02 * i0r + e12 * i1r + e22 * i2r;
    if (!act) { w0 = 0.f; w1 = 0.f; w2 = 0.f; }
#pragma unroll
    for (int i = 0; i < 8; i++) acc[i] += w0 * zs[i];
    wdsum += w1;
    float efl = (q < EF_) ? ef_perm[(size_t)idxc * EF_ + q] : 0.f;
    a11 += w2 * efl;
  }
#pragma unroll
  for (int m = 16; m < 64; m <<= 1) {
#pragma unroll
    for (int i = 0; i < 8; i++) acc[i] += __shfl_xor(acc[i], m, 64);
    wdsum += __shfl_xor(wdsum, m, 64);
    a11 += __shfl_xor(a11, m, 64);
  }
  int cnt = end - beg;
  float invc = (cnt > 0) ? 1.f / (float)cnt : 1.f;
  float* ob = aggZE + (size_t)n * 640 + h * 160;
  if (g == 0) {
    float4 o1, o2;
    o1.x = (acc[0] + wdsum * zd[0]) * invc;
    o1.y = (acc[1] + wdsum * zd[1]) * invc;
    o1.z = (acc[2] + wdsum * zd[2]) * invc;
    o1.w = (acc[3] + wdsum * zd[3]) * invc;
    o2.x = (acc[4] + wdsum * zd[4]) * invc;
    o2.y = (acc[5] + wdsum * zd[5]) * invc;
    o2.z = (acc[6] + wdsum * zd[6]) * invc;
    o2.w = (acc[7] + wdsum * zd[7]) * invc;
    *(float4*)(ob + q * 8) = o1;
    *(float4*)(ob + q * 8 + 4) = o2;
    ob[128 + q] = (q < EF_) ? a11 * invc : 0.f;   // 128..143
  } else if (g == 1) {
    ob[144 + q] = 0.f;                             // 144..159
  }
}

// ---------------------------------------------------------------------------
// Fused ReLU + LayerNorm per (node, head), in place on zh[N,512].
// ---------------------------------------------------------------------------
__global__ __launch_bounds__(256) void k_ln(
    float* __restrict__ zh, const float* __restrict__ lng,
    const float* __restrict__ lnb, int N, int layer)
{
  int h = threadIdx.x >> 6, lane = threadIdx.x & 63;
  int n = blockIdx.x;
  float* p = zh + (size_t)n * 512 + h * 128 + 2 * lane;
  float2 v = *(const float2*)p;
  v.x = fmaxf(v.x, 0.f); v.y = fmaxf(v.y, 0.f);
  float s1 = v.x + v.y;
#pragma unroll
  for (int m = 32; m; m >>= 1) s1 += __shfl_xor(s1, m, 64);
  float mean = s1 * (1.f / 128.f);
  float dx = v.x - mean, dy = v.y - mean;
  float s2 = dx * dx + dy * dy;
#pragma unroll
  for (int m = 32; m; m >>= 1) s2 += __shfl_xor(s2, m, 64);
  float rstd = rsqrtf(s2 * (1.f / 128.f) + 1e-5f);
  int gi = (layer * H_ + h) * 128 + 2 * lane;
  float2 g2 = *(const float2*)&lng[gi];
  float2 b2 = *(const float2*)&lnb[gi];
  float2 o;
  o.x = dx * rstd * g2.x + b2.x;
  o.y = dy * rstd * g2.y + b2.y;
  *(float2*)p = o;
}

// ---------------------------------------------------------------------------
// Segment mean by graph id (node_gid sorted): one block per graph.
// ---------------------------------------------------------------------------
__global__ void k_gmean(const float* __restrict__ X, const int* __restrict__ gid,
                        float* __restrict__ outp, int N, int ld)
{
  int g = blockIdx.x;
  int lo = 0, hi = N;
  while (lo < hi) { int m = (lo + hi) >> 1; if (gid[m] < g) lo = m + 1; else hi = m; }
  int s0 = lo;
  lo = s0; hi = N;
  while (lo < hi) { int m = (lo + hi) >> 1; if (gid[m] < g + 1) lo = m + 1; else hi = m; }
  int s1 = lo;
  float inv = 1.f / (float)((s1 - s0) > 0 ? (s1 - s0) : 1);
  for (int d = threadIdx.x; d < ld; d += blockDim.x) {
    float s = 0.f;
    for (int n = s0; n < s1; n++) s += X[(size_t)n * ld + d];
    outp[(size_t)g * ld + d] = s * inv;
  }
}

// ---------------------------------------------------------------------------
// GRU pass: block = (graph, dir), 128 threads.
// ---------------------------------------------------------------------------
__global__ __launch_bounds__(128) void k_gru(
    const float* __restrict__ seq, int inDim,
    const float* __restrict__ Wih, const float* __restrict__ Whh,
    const float* __restrict__ bih, const float* __restrict__ bhh,
    float* __restrict__ yout, float* __restrict__ hfinal)
{
  int g = blockIdx.x, dir = blockIdx.y, d = threadIdx.x;
  const float* Wih_d = Wih + (size_t)dir * inDim * 384;
  const float* Whh_d = Whh + (size_t)dir * 128 * 384;
  const float* bih_d = bih + dir * 384;
  const float* bhh_d = bhh + dir * 384;
  __shared__ float xb[256];
  __shared__ float hb[128];
  float h = 0.f;
  for (int st = 0; st < T_; st++) {
    int t = dir ? (T_ - 1 - st) : st;
    for (int k = d; k < inDim; k += 128) xb[k] = seq[((size_t)t * G_ + g) * inDim + k];
    hb[d] = h;
    __syncthreads();
    float gr = bih_d[d], gz = bih_d[128 + d], gn = bih_d[256 + d];
    for (int k = 0; k < inDim; k++) {
      float xv = xb[k];
      const float* wr = Wih_d + (size_t)k * 384;
      gr += xv * wr[d];
      gz += xv * wr[128 + d];
      gn += xv * wr[256 + d];
    }
    float hr = bhh_d[d], hz = bhh_d[128 + d], hn = bhh_d[256 + d];
    for (int k = 0; k < 128; k++) {
      float hv = hb[k];
      const float* wr = Whh_d + (size_t)k * 384;
      hr += hv * wr[d];
      hz += hv * wr[128 + d];
      hn += hv * wr[256 + d];
    }
    float r  = 1.f / (1.f + __expf(-(gr + hr)));
    float zg = 1.f / (1.f + __expf(-(gz + hz)));
    float ng = tanhf(gn + r * hn);
    h = (1.f - zg) * ng + zg * h;
    if (yout) yout[((size_t)t * G_ + g) * 256 + dir * 128 + d] = h;
    __syncthreads();
  }
  hfinal[((size_t)dir * G_ + g) * 128 + d] = h;
}

__global__ void k_final(const float* __restrict__ fp, float* __restrict__ outp, int n)
{
  int i = blockIdx.x * blockDim.x + threadIdx.x;
  if (i < n) {
    outp[i] = fp[i] + fp[G_ * 128 + i] + fp[2 * G_ * 128 + i] + fp[3 * G_ * 128 + i];
  }
}

// ---------------------------------------------------------------------------
extern "C" void kernel_launch(void* const* d_in, const int* in_sizes, int n_in,
                              void* d_out, int out_size, void* d_ws, size_t ws_size,
                              hipStream_t stream)
{
  (void)n_in; (void)ws_size;
  const float* h0   = (const float*)d_in[0];
  const float* e_f  = (const float*)d_in[1];
  const int*   srcI = (const int*)d_in[2];
  const int*   dstI = (const int*)d_in[3];
  const int*   gid  = (const int*)d_in[4];
  const float* lin0 = (const float*)d_in[6];
  const float* linW = (const float*)d_in[7];
  const float* WeW  = (const float*)d_in[8];
  const float* WqW  = (const float*)d_in[9];
  const float* WkW  = (const float*)d_in[10];
  const float* WvW  = (const float*)d_in[11];
  const float* lng  = (const float*)d_in[12];
  const float* lnb  = (const float*)d_in[13];
  const float* outW = (const float*)d_in[14];
  const float* outb = (const float*)d_in[15];
  const float* projW= (const float*)d_in[16];
  const float* projb= (const float*)d_in[17];
  const float* Wih0 = (const float*)d_in[18];
  const float* Whh0 = (const float*)d_in[19];
  const float* bih0 = (const float*)d_in[20];
  const float* bhh0 = (const float*)d_in[21];
  const float* Wih1 = (const float*)d_in[22];
  const float* Whh1 = (const float*)d_in[23];
  const float* bih1 = (const float*)d_in[24];
  const float* bhh1 = (const float*)d_in[25];
  float* outp = (float*)d_out;

  const int N = in_sizes[0] / INF_;
  const int E = in_sizes[2];

  char* wp = (char*)d_ws;
  auto alloc = [&](size_t bytes) -> void* {
    void* p = (void*)wp;
    wp += (bytes + 255) & ~(size_t)255;
    return p;
  };
  unsigned short* Zb = (unsigned short*)alloc((size_t)N * 512 * 2);  // per-head Z bf16
  float* UT   = (float*)alloc((size_t)N * 1024 * 4);                 // u,t per head f32
  float* aggZE= (float*)alloc((size_t)N * 640 * 4);                  // [aggZ|a11|0] x4 heads
  float* zh   = (float*)alloc((size_t)N * 512 * 4);                  // messages -> LN'd heads
  float* hcur = (float*)alloc((size_t)N * 128 * 4);
  float* Bm   = (float*)alloc((size_t)N * H_ * EF_ * 4);
  float* Cm   = (float*)alloc((size_t)N * H_ * EF_ * 4);
  float* ssb  = (float*)alloc((size_t)N * H_ * 4);
  float* elog = (float*)alloc((size_t)E * H_ * 6 * 4);
  float* efp  = (float*)alloc((size_t)E * EF_ * 4);
  float* WeQ  = (float*)alloc((size_t)C_ * H_ * EF_ * 128 * 4);
  float* WeK  = (float*)alloc((size_t)C_ * H_ * EF_ * 128 * 4);
  float* WeV  = (float*)alloc((size_t)C_ * H_ * EF_ * 128 * 4);
  float* M2   = (float*)alloc((size_t)C_ * H_ * EF_ * EF_ * 4);
  float* GqT  = (float*)alloc((size_t)C_ * H_ * EF_ * 128 * 4);
  float* GcT  = (float*)alloc((size_t)C_ * H_ * EF_ * 128 * 4);
  float* Mbuf = (float*)alloc((size_t)C_ * H_ * 16384 * 4);
  unsigned short* WkPl  = (unsigned short*)alloc((size_t)C_ * H_ * 16384 * 2);
  unsigned short* UTBt  = (unsigned short*)alloc((size_t)C_ * H_ * 2 * 16384 * 2);
  unsigned short* WvE   = (unsigned short*)alloc((size_t)C_ * H_ * 20480 * 2);
  unsigned short* linBt0 = (unsigned short*)alloc((size_t)4 * 128 * INF_ * 2);
  unsigned short* linBt12= (unsigned short*)alloc((size_t)2 * 512 * 128 * 2);
  unsigned short* outBt  = (unsigned short*)alloc((size_t)C_ * 128 * 512 * 2);
  unsigned short* projBt = (unsigned short*)alloc((size_t)128 * INF_ * 2);
  int* deg    = (int*)alloc((size_t)N * 4);
  int* cursor = (int*)alloc((size_t)N * 4);
  int* rowp   = (int*)alloc((size_t)(N + 1) * 4);
  int* eids   = (int*)alloc((size_t)E * 4);
  int* srcp   = (int*)alloc((size_t)E * 4);
  int* dstp   = (int*)alloc((size_t)E * 4);
  float* gm74 = (float*)alloc((size_t)G_ * INF_ * 4);
  float* seq  = (float*)alloc((size_t)T_ * G_ * 128 * 4);
  float* seq1 = (float*)alloc((size_t)T_ * G_ * 256 * 4);
  float* fparts=(float*)alloc((size_t)4 * G_ * 128 * 4);

  const int gM = (N + 127) / 128;

  // --- CSR build + permuted metadata ---
  hipMemsetAsync(deg, 0, (size_t)N * 4, stream);
  hipMemsetAsync(cursor, 0, (size_t)N * 4, stream);
  k_hist<<<(E + 255) / 256, 256, 0, stream>>>(dstI, deg, E);
  k_scan<<<1, 1024, 0, stream>>>(deg, rowp, N);
  k_fill<<<(E + 255) / 256, 256, 0, stream>>>(srcI, dstI, rowp, cursor,
                                              eids, srcp, dstp, E);
  k_efperm<<<(E * EF_ + 255) / 256, 256, 0, stream>>>(e_f, eids, efp, E);

  // --- small weight folding ---
  k_small<<<C_ * H_, 128, 0, stream>>>(WeW, WqW, WkW, WvW, WeQ, WeK, WeV, M2,
                                       GqT, GcT);
  k_wve<<<C_ * H_, 128, 0, stream>>>(WvW, WeV, WvE);

  // --- weight conversions pass 1 ---
  {
    WPack w{};
    int nw = 0;
    auto addw = [&](const float* s, unsigned short* d, int K, int D, int tr) {
      w.d[nw].src = s; w.d[nw].dst = d; w.d[nw].K = K; w.d[nw].D = D;
      w.d[nw].trans = tr; nw++;
    };
    for (int h = 0; h < 4; h++)
      addw(lin0 + (size_t)h * INF_ * 128, linBt0 + (size_t)h * 128 * INF_, INF_, 128, 1);
    for (int j = 1; j < 3; j++)
      for (int h = 0; h < 4; h++)
        addw(linW + ((size_t)(j - 1) * 4 + h) * 16384,
             linBt12 + (size_t)(j - 1) * 65536 + (size_t)h * 16384, 128, 128, 1);
    for (int j = 0; j < 3; j++)
      addw(outW + (size_t)j * 65536, outBt + (size_t)j * 65536, 512, 128, 1);
    addw(projW, projBt, INF_, 128, 1);
    for (int ch = 0; ch < 12; ch++)
      addw(WkW + (size_t)ch * 16384, WkPl + (size_t)ch * 16384, 128, 128, 0);
    k_wcvt<<<dim3(64, nw), 256, 0, stream>>>(w);
  }

  // --- M = Wq @ Wk^T per (layer,head), f32 out ---
  k_mfma<float><<<dim3(1, 1, 12), 256, 0, stream>>>(
      WqW, 128, 16384, 128, 128, WkPl, 0, 16384,
      Mbuf, 128, 0, 16384, nullptr, nullptr, 0, 0, 0);

  // --- pass 2: UTBt = [M | M^T] bf16 ---
  {
    WPack w{};
    int nw = 0;
    for (int ch = 0; ch < 12; ch++) {
      w.d[nw++] = { Mbuf + (size_t)ch * 16384, UTBt + (size_t)ch * 32768,
                    128, 128, 0 };
      w.d[nw++] = { Mbuf + (size_t)ch * 16384, UTBt + (size_t)ch * 32768 + 16384,
                    128, 128, 1 };
    }
    k_wcvt<<<dim3(64, nw), 256, 0, stream>>>(w);
  }

  // --- GRU input t=0: seg-mean(h0) then proj ---
  k_gmean<<<G_, 128, 0, stream>>>(h0, gid, gm74, N, INF_);
  k_mfma<float><<<dim3(4, 1, 1), 256, 0, stream>>>(
      gm74, INF_, 0, G_, INF_, projBt, 0, 0,
      seq, 128, 0, 0, projb, nullptr, 0, 0, 0);

  // --- conv layers ---
  for (int j = 0; j < C_; j++) {
    // lin -> Zb bf16 [N][H][128]
    if (j == 0)
      k_mfma<float><<<dim3(gM, 4, 1), 256, 0, stream>>>(
          h0, INF_, 0, N, INF_, linBt0, 128 * INF_, 0,
          nullptr, 0, 0, 0, nullptr, Zb, 512, 128, 0);
    else
      k_mfma<float><<<dim3(gM, 4, 1), 256, 0, stream>>>(
          hcur, 128, 0, N, 128, linBt12 + (size_t)(j - 1) * 65536, 16384, 0,
          nullptr, 0, 0, 0, nullptr, Zb, 512, 128, 0);
    // u,t = [M|M^T] Z -> UT f32 [N][H][2][128]
    k_mfma<unsigned short><<<dim3(gM, 2, 4), 256, 0, stream>>>(
        Zb, 512, 128, N, 128, UTBt + (size_t)j * 4 * 32768, 16384, 32768,
        UT, 1024, 128, 256, nullptr, nullptr, 0, 0, 0);
    k_bc<<<N, 256, 0, stream>>>(Zb, UT, GqT, GcT, Bm, Cm, ssb, N, j);
    k_elog<<<(E + 63) / 64, 256, 0, stream>>>(Bm, Cm, ssb, M2, efp, srcp, dstp,
                                              elog, E, j);
    k_edge<<<N, 256, 0, stream>>>(Zb, UT, ssb, elog, efp, rowp, srcp, aggZE, N);
    // messages: zh[N][h*128+d] = aggZE @ [Wv;WeV]
    k_mfma<float><<<dim3(gM, 1, 4), 256, 0, stream>>>(
        aggZE, 640, 160, N, 160, WvE + (size_t)j * 4 * 20480, 0, 20480,
        zh, 512, 0, 128, nullptr, nullptr, 0, 0, 0);
    k_ln<<<N, 256, 0, stream>>>(zh, lng, lnb, N, j);
    // out GEMM
    k_mfma<float><<<dim3(gM, 1, 1), 256, 0, stream>>>(
        zh, 512, 0, N, 512, outBt + (size_t)j * 65536, 0, 0,
        hcur, 128, 0, 0, outb + j * 128, nullptr, 0, 0, 0);
    k_gmean<<<G_, 128, 0, stream>>>(hcur, gid, seq + (size_t)(j + 1) * G_ * 128, N, 128);
  }

  // --- GRU readout ---
  k_gru<<<dim3(G_, 2), 128, 0, stream>>>(seq, 128, Wih0, Whh0, bih0, bhh0,
                                         seq1, fparts);
  k_gru<<<dim3(G_, 2), 128, 0, stream>>>(seq1, 256, Wih1, Whh1, bih1, bhh1,
                                         nullptr, fparts + 2 * G_ * 128);
  k_final<<<(out_size + 255) / 256, 256, 0, stream>>>(fparts, outp, out_size);
}

// Round 7
// 1392.274 us; speedup vs baseline: 2.4288x; 1.1833x over previous
//
#include <hip/hip_runtime.h>
#include <cstdint>

#define D_   128
#define H_   4
#define C_   3
#define G_   512
#define INF_ 74
#define EF_  11
#define T_   4
#define NW_  48

typedef __attribute__((ext_vector_type(8))) short bf16x8;
typedef __attribute__((ext_vector_type(4))) float f32x4;

__device__ inline unsigned short f2bf(float x) {
  unsigned u = __float_as_uint(x);
  unsigned r = u + 0x7fffu + ((u >> 16) & 1u);
  return (unsigned short)(r >> 16);
}
__device__ inline float bf2f(unsigned short x) {
  return __uint_as_float(((unsigned)x) << 16);
}
__device__ inline void unpack8(uint4 u, float* f) {
  f[0] = __uint_as_float(u.x << 16); f[1] = __uint_as_float(u.x & 0xffff0000u);
  f[2] = __uint_as_float(u.y << 16); f[3] = __uint_as_float(u.y & 0xffff0000u);
  f[4] = __uint_as_float(u.z << 16); f[5] = __uint_as_float(u.z & 0xffff0000u);
  f[6] = __uint_as_float(u.w << 16); f[7] = __uint_as_float(u.w & 0xffff0000u);
}

// ---------------------------------------------------------------------------
// Weight convert: trans ? dst[d*K+k]=bf16(src[k*D+d]) : dst[i]=bf16(src[i])
// ---------------------------------------------------------------------------
struct WDesc { const float* src; unsigned short* dst; int K; int D; int trans; };
struct WPack { WDesc d[NW_]; };

__global__ __launch_bounds__(256) void k_wcvt(WPack wp)
{
  WDesc w = wp.d[blockIdx.y];
  int tot = w.K * w.D;
  for (int i = blockIdx.x * 256 + threadIdx.x; i < tot; i += gridDim.x * 256) {
    if (w.trans) {
      int d = i / w.K, k = i - d * w.K;
      w.dst[i] = f2bf(w.src[(size_t)k * w.D + d]);
    } else {
      w.dst[i] = f2bf(w.src[i]);
    }
  }
}

// ---------------------------------------------------------------------------
// Build UTBt third col-block: rows 0..10 = GqT[ch], 11..21 = GcT[ch], else 0.
// ---------------------------------------------------------------------------
__global__ __launch_bounds__(256) void k_bcw(
    const float* __restrict__ GqT, const float* __restrict__ GcT,
    unsigned short* __restrict__ UTBt)
{
  int ch = blockIdx.x;
  unsigned short* dst = UTBt + (size_t)ch * 49152 + 32768;
  const float* gq = GqT + (size_t)ch * EF_ * 128;
  const float* gc = GcT + (size_t)ch * EF_ * 128;
  for (int i = threadIdx.x; i < 16384; i += 256) {
    int r = i >> 7, k = i & 127;
    float v = (r < EF_) ? gq[r * 128 + k]
            : (r < 2 * EF_) ? gc[(r - EF_) * 128 + k] : 0.f;
    dst[i] = f2bf(v);
  }
}

// ---------------------------------------------------------------------------
// MFMA bf16 GEMM, A f32 (converted in staging) or bf16. 128x128 tile,
// 4 waves 2x2, mfma_f32_16x16x32_bf16. Out: f32 (+bias) or bf16.
// ---------------------------------------------------------------------------
template <typename AT>
__global__ __launch_bounds__(256) void k_mfma(
    const AT* __restrict__ A, int lda, int aOffZ, int M, int K,
    const unsigned short* __restrict__ Bt, int btOffY, int btOffZ,
    float* __restrict__ outF, int ldc, int cOffY, int cOffZ,
    const float* __restrict__ bias,
    unsigned short* __restrict__ outH, int hStride, int hOffY, int hOffZ)
{
  const int bx = blockIdx.x, by = blockIdx.y, bz = blockIdx.z;
  A += (size_t)bz * aOffZ;
  const unsigned short* Bp = Bt + (size_t)by * btOffY + (size_t)bz * btOffZ;
  const int rowBase = bx * 128;
  __shared__ unsigned short As[128][40];
  __shared__ unsigned short Bs[128][40];
  const int t = threadIdx.x;
  const int w = t >> 6, l = t & 63;
  const int wr = w >> 1, wc = w & 1;
  const int fr = l & 15, fq = l >> 4;
  f32x4 acc[4][4];
#pragma unroll
  for (int m = 0; m < 4; m++)
#pragma unroll
    for (int n = 0; n < 4; n++) acc[m][n] = (f32x4){0.f, 0.f, 0.f, 0.f};

  const int sr = t >> 1, sh = t & 1;
  const int arow = rowBase + sr;
  const AT* aBase = A + (size_t)arow * lda;

  for (int k0 = 0; k0 < K; k0 += 32) {
    int kb = k0 + sh * 16;
    if constexpr (sizeof(AT) == 4) {
      unsigned short tmp[16];
      if (arow < M && kb + 16 <= K) {
        const AT* ap = aBase + kb;
#pragma unroll
        for (int i = 0; i < 16; i++) tmp[i] = f2bf(ap[i]);
      } else {
#pragma unroll
        for (int i = 0; i < 16; i++) {
          int gk = kb + i;
          float v = (arow < M && gk < K) ? (float)aBase[gk] : 0.f;
          tmp[i] = f2bf(v);
        }
      }
      *(uint4*)&As[sr][sh * 16]     = *(const uint4*)&tmp[0];
      *(uint4*)&As[sr][sh * 16 + 8] = *(const uint4*)&tmp[8];
    } else {
      if (arow < M && kb + 16 <= K) {
        const unsigned short* ap = (const unsigned short*)aBase + kb;
        *(uint4*)&As[sr][sh * 16]     = *(const uint4*)(ap);
        *(uint4*)&As[sr][sh * 16 + 8] = *(const uint4*)(ap + 8);
      } else {
#pragma unroll
        for (int i = 0; i < 16; i++) {
          int gk = kb + i;
          As[sr][sh * 16 + i] = (arow < M && gk < K)
              ? ((const unsigned short*)aBase)[gk] : (unsigned short)0;
        }
      }
    }
    if (t < 128) {
      unsigned short tmp[32];
      if (k0 + 32 <= K) {
        const unsigned short* bp = Bp + (size_t)t * K + k0;
#pragma unroll
        for (int i = 0; i < 32; i++) tmp[i] = bp[i];
      } else {
#pragma unroll
        for (int i = 0; i < 32; i++) {
          int gk = k0 + i;
          tmp[i] = (gk < K) ? Bp[(size_t)t * K + gk] : (unsigned short)0;
        }
      }
#pragma unroll
      for (int i = 0; i < 4; i++) *(uint4*)&Bs[t][i * 8] = *(const uint4*)&tmp[i * 8];
    }
    __syncthreads();
    bf16x8 af[4], bfr[4];
#pragma unroll
    for (int m = 0; m < 4; m++) af[m]  = *(const bf16x8*)&As[wr * 64 + m * 16 + fr][fq * 8];
#pragma unroll
    for (int n = 0; n < 4; n++) bfr[n] = *(const bf16x8*)&Bs[wc * 64 + n * 16 + fr][fq * 8];
#pragma unroll
    for (int m = 0; m < 4; m++)
#pragma unroll
      for (int n = 0; n < 4; n++)
        acc[m][n] = __builtin_amdgcn_mfma_f32_16x16x32_bf16(af[m], bfr[n], acc[m][n], 0, 0, 0);
    __syncthreads();
  }
#pragma unroll
  for (int m = 0; m < 4; m++) {
    int row0 = rowBase + wr * 64 + m * 16 + fq * 4;
#pragma unroll
    for (int n = 0; n < 4; n++) {
      int col = wc * 64 + n * 16 + fr;
#pragma unroll
      for (int r = 0; r < 4; r++) {
        int row = row0 + r;
        if (row < M) {
          float v = acc[m][n][r];
          if (outH) {
            outH[(size_t)row * hStride + by * hOffY + bz * hOffZ + col] = f2bf(v);
          } else {
            if (bias) v += bias[col];
            outF[(size_t)row * ldc + by * cOffY + bz * cOffZ + col] = v;
          }
        }
      }
    }
  }
}

// ---------------------------------------------------------------------------
// CSR build (by dst) + permuted metadata
// ---------------------------------------------------------------------------
__global__ void k_hist(const int* __restrict__ dst, int* __restrict__ deg, int E)
{
  int e = blockIdx.x * blockDim.x + threadIdx.x;
  if (e < E) atomicAdd(&deg[dst[e]], 1);
}

__global__ __launch_bounds__(1024) void k_scan(const int* __restrict__ deg,
                                               int* __restrict__ rowp, int N)
{
  __shared__ int part[1024];
  int t = threadIdx.x;
  int chunk = (N + 1023) / 1024;
  int base = t * chunk;
  int s = 0;
  for (int i = 0; i < chunk; i++) { int idx = base + i; if (idx < N) s += deg[idx]; }
  part[t] = s;
  __syncthreads();
  for (int off = 1; off < 1024; off <<= 1) {
    int v = (t >= off) ? part[t - off] : 0;
    __syncthreads();
    part[t] += v;
    __syncthreads();
  }
  int run = part[t] - s;
  for (int i = 0; i < chunk; i++) {
    int idx = base + i;
    if (idx < N) { rowp[idx] = run; run += deg[idx]; }
  }
  if (t == 1023) rowp[N] = part[1023];
}

__global__ void k_fill(const int* __restrict__ src, const int* __restrict__ dst,
                       const int* __restrict__ rowp, int* __restrict__ cursor,
                       int* __restrict__ eids, int* __restrict__ src_perm,
                       int* __restrict__ dst_perm, int E)
{
  int e = blockIdx.x * blockDim.x + threadIdx.x;
  if (e < E) {
    int d = dst[e];
    int pos = atomicAdd(&cursor[d], 1);
    int slot = rowp[d] + pos;
    eids[slot] = e;
    src_perm[slot] = src[e];
    dst_perm[slot] = d;
  }
}

__global__ void k_efperm(const float* __restrict__ e_f, const int* __restrict__ eids,
                         float* __restrict__ ef_perm, int E)
{
  int i = blockIdx.x * blockDim.x + threadIdx.x;
  if (i < E * EF_) {
    int idx = i / EF_, f = i - idx * EF_;
    ef_perm[i] = e_f[(size_t)eids[idx] * EF_ + f];
  }
}

// ---------------------------------------------------------------------------
// Small weight folding: WeQ/WeK/WeV = We@W{q,k,v} [11,128]; M2 = WeQ@WeK^T;
// GqT[f][d] = (Wq WeK^T)^T, GcT[f][d] = (Wk WeQ^T)^T  (for B/C from Z).
// ---------------------------------------------------------------------------
__global__ __launch_bounds__(128) void k_small(
    const float* __restrict__ WeW, const float* __restrict__ WqW,
    const float* __restrict__ WkW, const float* __restrict__ WvW,
    float* __restrict__ WeQ, float* __restrict__ WeK, float* __restrict__ WeV,
    float* __restrict__ M2, float* __restrict__ GqT, float* __restrict__ GcT)
{
  int ch = blockIdx.x;
  const float* We = WeW + (size_t)ch * EF_ * 128;
  const float* Wq = WqW + (size_t)ch * 128 * 128;
  const float* Wk = WkW + (size_t)ch * 128 * 128;
  const float* Wv = WvW + (size_t)ch * 128 * 128;
  __shared__ float sWe[EF_ * 128], sQ[EF_ * 128], sK[EF_ * 128];
  int d = threadIdx.x;
  for (int i = d; i < EF_ * 128; i += 128) sWe[i] = We[i];
  __syncthreads();
  for (int f = 0; f < EF_; f++) {
    float aq = 0.f, ak = 0.f, av = 0.f;
    for (int k = 0; k < 128; k++) {
      float w = sWe[f * 128 + k];
      aq += w * Wq[k * 128 + d];
      ak += w * Wk[k * 128 + d];
      av += w * Wv[k * 128 + d];
    }
    WeQ[(size_t)ch * EF_ * 128 + f * 128 + d] = aq;
    WeK[(size_t)ch * EF_ * 128 + f * 128 + d] = ak;
    WeV[(size_t)ch * EF_ * 128 + f * 128 + d] = av;
    sQ[f * 128 + d] = aq;
    sK[f * 128 + d] = ak;
  }
  __syncthreads();
  if (d < EF_ * EF_) {
    int a = d / EF_, b = d % EF_;
    float s = 0.f;
    for (int k = 0; k < 128; k++) s += sQ[a * 128 + k] * sK[b * 128 + k];
    M2[(size_t)ch * (EF_ * EF_) + d] = s;
  }
  // GqT[f][d] = sum_k Wq[d][k]*WeK[f][k]; GcT[f][d] = sum_k Wk[d][k]*WeQ[f][k]
  for (int f = 0; f < EF_; f++) {
    float aq = 0.f, ac = 0.f;
    for (int k = 0; k < 128; k++) {
      aq += Wq[(size_t)d * 128 + k] * sK[f * 128 + k];
      ac += Wk[(size_t)d * 128 + k] * sQ[f * 128 + k];
    }
    GqT[(size_t)ch * EF_ * 128 + f * 128 + d] = aq;
    GcT[(size_t)ch * EF_ * 128 + f * 128 + d] = ac;
  }
}

// ---------------------------------------------------------------------------
// Build combined post-message weight: WvE[ch][out d][k160]:
// k<128 -> Wv[k][d]; 128<=k<139 -> WeV[k-128][d]; else 0.
// ---------------------------------------------------------------------------
__global__ __launch_bounds__(128) void k_wve(
    const float* __restrict__ WvW, const float* __restrict__ WeV,
    unsigned short* __restrict__ WvE)
{
  int ch = blockIdx.x;
  const float* Wv  = WvW + (size_t)ch * 16384;
  const float* wev = WeV + (size_t)ch * EF_ * 128;
  unsigned short* dst = WvE + (size_t)ch * 20480;
  for (int i = threadIdx.x; i < 20480; i += 128) {
    int d = i / 160, k = i - d * 160;
    float v = (k < 128) ? Wv[(size_t)k * 128 + d]
            : (k < 128 + EF_) ? wev[(size_t)(k - 128) * 128 + d] : 0.f;
    dst[i] = f2bf(v);
  }
}

// ---------------------------------------------------------------------------
// Per-node ss = Z.u (UTb bf16: [N][H][3][128] = [u|t|B,C,junk]). Wave per (n,h).
// ---------------------------------------------------------------------------
__global__ __launch_bounds__(256) void k_ss(
    const unsigned short* __restrict__ Zb, const unsigned short* __restrict__ UTb,
    float* __restrict__ ss, int N)
{
  int h = threadIdx.x >> 6, lane = threadIdx.x & 63;
  int n = blockIdx.x;
  unsigned uz = *(const unsigned*)(Zb + (size_t)n * 512 + h * 128 + 2 * lane);
  unsigned uu = *(const unsigned*)(UTb + (size_t)n * 1536 + h * 384 + 2 * lane);
  float zx = __uint_as_float(uz << 16), zy = __uint_as_float(uz & 0xffff0000u);
  float ux = __uint_as_float(uu << 16), uy = __uint_as_float(uu & 0xffff0000u);
  float p = zx * ux + zy * uy;
#pragma unroll
  for (int m = 32; m; m >>= 1) p += __shfl_xor(p, m, 64);
  if (lane == 0) ss[n * H_ + h] = p;
}

// ---------------------------------------------------------------------------
// Per-edge precomputed logits: elog[idx][h][6] = {ss_s, se, de, es, ed, ee}
// B/C read from UTb slot 2 (bf16).
// ---------------------------------------------------------------------------
__global__ __launch_bounds__(256) void k_elog(
    const unsigned short* __restrict__ UTb, const float* __restrict__ ss,
    const float* __restrict__ M2, const float* __restrict__ ef_perm,
    const int* __restrict__ src_perm, const int* __restrict__ dst_perm,
    float* __restrict__ elog, int E, int layer)
{
  int i0 = blockIdx.x * 64;
  __shared__ float efs[64 * EF_];
  __shared__ float m2s[4 * EF_ * EF_];
  int t = threadIdx.x;
  for (int i = t; i < 64 * EF_; i += 256) {
    int gi = i0 * EF_ + i;
    efs[i] = (gi < E * EF_) ? ef_perm[gi] : 0.f;
  }
  for (int i = t; i < 4 * EF_ * EF_; i += 256)
    m2s[i] = M2[(size_t)layer * 4 * EF_ * EF_ + i];
  __syncthreads();
  int sl = t >> 2, h = t & 3;
  int idx = i0 + sl;
  if (idx < E) {
    int s = src_perm[idx], d = dst_perm[idx];
    const float* ef = &efs[sl * EF_];
    const float* m2 = &m2s[h * EF_ * EF_];
    float ee = 0.f;
#pragma unroll
    for (int a = 0; a < EF_; a++) {
      float r = 0.f;
#pragma unroll
      for (int b = 0; b < EF_; b++) r += m2[a * EF_ + b] * ef[b];
      ee += ef[a] * r;
    }
    const unsigned short* bs = UTb + (size_t)s * 1536 + h * 384 + 256;
    const unsigned short* cs = bs + EF_;
    const unsigned short* bd = UTb + (size_t)d * 1536 + h * 384 + 256;
    const unsigned short* cd = bd + EF_;
    float se = 0.f, es = 0.f, de = 0.f, ed = 0.f;
#pragma unroll
    for (int f = 0; f < EF_; f++) {
      float e = ef[f];
      se += bf2f(bs[f]) * e;
      es += bf2f(cs[f]) * e;
      de += bf2f(bd[f]) * e;
      ed += bf2f(cd[f]) * e;
    }
    float* o = elog + ((size_t)idx * H_ + h) * 6;
    o[0] = ss[s * H_ + h];
    o[1] = se; o[2] = de; o[3] = es; o[4] = ed; o[5] = ee;
  }
}

// ---------------------------------------------------------------------------
// Edge aggregation in Z-space: wave per (dst,head); gathers ONLY Z_s (256 B).
// v1 = Zs.u_d, v2 = Zs.t_d (u/t bf16, dst-side). Writes aggZE bf16
// [n][h][160] = [aggZ(128)|a11(11)|0].
// ---------------------------------------------------------------------------
__global__ __launch_bounds__(256) void k_edge(
    const unsigned short* __restrict__ Zb, const unsigned short* __restrict__ UTb,
    const float* __restrict__ ss, const float* __restrict__ elog,
    const float* __restrict__ ef_perm, const int* __restrict__ rowp,
    const int* __restrict__ src_perm, unsigned short* __restrict__ aggZE, int N)
{
  const int h = threadIdx.x >> 6;
  const int lane = threadIdx.x & 63;
  const int q = lane & 15;
  const int g = lane >> 4;
  const int lb = lane & 48;
  const int n = blockIdx.x;

  float zd[8], ud[8], td[8];
  unpack8(*(const uint4*)(Zb + (size_t)n * 512 + h * 128 + q * 8), zd);
  const unsigned short* utp = UTb + (size_t)n * 1536 + h * 384 + q * 8;
  unpack8(*(const uint4*)(utp), ud);
  unpack8(*(const uint4*)(utp + 128), td);
  const float ssd = ss[n * H_ + h];
  const int beg = rowp[n], end = rowp[n + 1];
  float acc[8];
#pragma unroll
  for (int i = 0; i < 8; i++) acc[i] = 0.f;
  float wdsum = 0.f, a11 = 0.f;

  for (int idx0 = beg; idx0 < end; idx0 += 4) {
    int idxg = idx0 + g;
    bool act = idxg < end;
    int idxc = act ? idxg : beg;
    int s = src_perm[idxc];
    float zs[8];
    unpack8(*(const uint4*)(Zb + (size_t)s * 512 + h * 128 + q * 8), zs);
    float v1 = 0.f, v2 = 0.f;
#pragma unroll
    for (int i = 0; i < 8; i++) {
      v1 += zs[i] * ud[i];
      v2 += zs[i] * td[i];
    }
#pragma unroll
    for (int m = 1; m < 16; m <<= 1) {
      v1 += __shfl_xor(v1, m, 64);
      v2 += __shfl_xor(v2, m, 64);
    }
    float lv = (q < 6) ? elog[((size_t)idxc * H_ + h) * 6 + q] : 0.f;
    float S00 = __shfl(lv, lb + 0, 64);
    float S02 = __shfl(lv, lb + 1, 64);
    float S12 = __shfl(lv, lb + 2, 64);
    float S20 = __shfl(lv, lb + 3, 64);
    float S21 = __shfl(lv, lb + 4, 64);
    float S22 = __shfl(lv, lb + 5, 64);
    float m0 = fmaxf(fmaxf(S00, v1), S02);
    float e00 = __expf(S00 - m0), e01 = __expf(v1 - m0), e02 = __expf(S02 - m0);
    float i0r = 1.f / (e00 + e01 + e02);
    float m1 = fmaxf(fmaxf(v2, ssd), S12);
    float e10 = __expf(v2 - m1), e11 = __expf(ssd - m1), e12 = __expf(S12 - m1);
    float i1r = 1.f / (e10 + e11 + e12);
    float m2 = fmaxf(fmaxf(S20, S21), S22);
    float e20 = __expf(S20 - m2), e21 = __expf(S21 - m2), e22 = __expf(S22 - m2);
    float i2r = 1.f / (e20 + e21 + e22);
    float w0 = e00 * i0r + e10 * i1r + e20 * i2r;
    float w1 = e01 * i0r + e11 * i1r + e21 * i2r;
    float w2 = e02 * i0r + e12 * i1r + e22 * i2r;
    if (!act) { w0 = 0.f; w1 = 0.f; w2 = 0.f; }
#pragma unroll
    for (int i = 0; i < 8; i++) acc[i] += w0 * zs[i];
    wdsum += w1;
    float efl = (q < EF_) ? ef_perm[(size_t)idxc * EF_ + q] : 0.f;
    a11 += w2 * efl;
  }
#pragma unroll
  for (int m = 16; m < 64; m <<= 1) {
#pragma unroll
    for (int i = 0; i < 8; i++) acc[i] += __shfl_xor(acc[i], m, 64);
    wdsum += __shfl_xor(wdsum, m, 64);
    a11 += __shfl_xor(a11, m, 64);
  }
  int cnt = end - beg;
  float invc = (cnt > 0) ? 1.f / (float)cnt : 1.f;
  unsigned short* ob = aggZE + (size_t)n * 640 + h * 160;
  if (g == 0) {
    unsigned short tmp[8];
#pragma unroll
    for (int i = 0; i < 8; i++) tmp[i] = f2bf((acc[i] + wdsum * zd[i]) * invc);
    *(uint4*)(ob + q * 8) = *(const uint4*)&tmp[0];
    ob[128 + q] = (q < EF_) ? f2bf(a11 * invc) : (unsigned short)0;  // 128..143
  } else if (g == 1) {
    ob[144 + q] = 0;                                                 // 144..159
  }
}

// ---------------------------------------------------------------------------
// Fused ReLU + LayerNorm per (node, head), in place on zh[N,512].
// ---------------------------------------------------------------------------
__global__ __launch_bounds__(256) void k_ln(
    float* __restrict__ zh, const float* __restrict__ lng,
    const float* __restrict__ lnb, int N, int layer)
{
  int h = threadIdx.x >> 6, lane = threadIdx.x & 63;
  int n = blockIdx.x;
  float* p = zh + (size_t)n * 512 + h * 128 + 2 * lane;
  float2 v = *(const float2*)p;
  v.x = fmaxf(v.x, 0.f); v.y = fmaxf(v.y, 0.f);
  float s1 = v.x + v.y;
#pragma unroll
  for (int m = 32; m; m >>= 1) s1 += __shfl_xor(s1, m, 64);
  float mean = s1 * (1.f / 128.f);
  float dx = v.x - mean, dy = v.y - mean;
  float s2 = dx * dx + dy * dy;
#pragma unroll
  for (int m = 32; m; m >>= 1) s2 += __shfl_xor(s2, m, 64);
  float rstd = rsqrtf(s2 * (1.f / 128.f) + 1e-5f);
  int gi = (layer * H_ + h) * 128 + 2 * lane;
  float2 g2 = *(const float2*)&lng[gi];
  float2 b2 = *(const float2*)&lnb[gi];
  float2 o;
  o.x = dx * rstd * g2.x + b2.x;
  o.y = dy * rstd * g2.y + b2.y;
  *(float2*)p = o;
}

// ---------------------------------------------------------------------------
// Segment mean by graph id (node_gid sorted): one block per graph.
// ---------------------------------------------------------------------------
__global__ void k_gmean(const float* __restrict__ X, const int* __restrict__ gid,
                        float* __restrict__ outp, int N, int ld)
{
  int g = blockIdx.x;
  int lo = 0, hi = N;
  while (lo < hi) { int m = (lo + hi) >> 1; if (gid[m] < g) lo = m + 1; else hi = m; }
  int s0 = lo;
  lo = s0; hi = N;
  while (lo < hi) { int m = (lo + hi) >> 1; if (gid[m] < g + 1) lo = m + 1; else hi = m; }
  int s1 = lo;
  float inv = 1.f / (float)((s1 - s0) > 0 ? (s1 - s0) : 1);
  for (int d = threadIdx.x; d < ld; d += blockDim.x) {
    float s = 0.f;
    for (int n = s0; n < s1; n++) s += X[(size_t)n * ld + d];
    outp[(size_t)g * ld + d] = s * inv;
  }
}

// ---------------------------------------------------------------------------
// GRU pass: block = (graph, dir), 128 threads.
// ---------------------------------------------------------------------------
__global__ __launch_bounds__(128) void k_gru(
    const float* __restrict__ seq, int inDim,
    const float* __restrict__ Wih, const float* __restrict__ Whh,
    const float* __restrict__ bih, const float* __restrict__ bhh,
    float* __restrict__ yout, float* __restrict__ hfinal)
{
  int g = blockIdx.x, dir = blockIdx.y, d = threadIdx.x;
  const float* Wih_d = Wih + (size_t)dir * inDim * 384;
  const float* Whh_d = Whh + (size_t)dir * 128 * 384;
  const float* bih_d = bih + dir * 384;
  const float* bhh_d = bhh + dir * 384;
  __shared__ float xb[256];
  __shared__ float hb[128];
  float h = 0.f;
  for (int st = 0; st < T_; st++) {
    int t = dir ? (T_ - 1 - st) : st;
    for (int k = d; k < inDim; k += 128) xb[k] = seq[((size_t)t * G_ + g) * inDim + k];
    hb[d] = h;
    __syncthreads();
    float gr = bih_d[d], gz = bih_d[128 + d], gn = bih_d[256 + d];
    for (int k = 0; k < inDim; k++) {
      float xv = xb[k];
      const float* wr = Wih_d + (size_t)k * 384;
      gr += xv * wr[d];
      gz += xv * wr[128 + d];
      gn += xv * wr[256 + d];
    }
    float hr = bhh_d[d], hz = bhh_d[128 + d], hn = bhh_d[256 + d];
    for (int k = 0; k < 128; k++) {
      float hv = hb[k];
      const float* wr = Whh_d + (size_t)k * 384;
      hr += hv * wr[d];
      hz += hv * wr[128 + d];
      hn += hv * wr[256 + d];
    }
    float r  = 1.f / (1.f + __expf(-(gr + hr)));
    float zg = 1.f / (1.f + __expf(-(gz + hz)));
    float ng = tanhf(gn + r * hn);
    h = (1.f - zg) * ng + zg * h;
    if (yout) yout[((size_t)t * G_ + g) * 256 + dir * 128 + d] = h;
    __syncthreads();
  }
  hfinal[((size_t)dir * G_ + g) * 128 + d] = h;
}

__global__ void k_final(const float* __restrict__ fp, float* __restrict__ outp, int n)
{
  int i = blockIdx.x * blockDim.x + threadIdx.x;
  if (i < n) {
    outp[i] = fp[i] + fp[G_ * 128 + i] + fp[2 * G_ * 128 + i] + fp[3 * G_ * 128 + i];
  }
}

// ---------------------------------------------------------------------------
extern "C" void kernel_launch(void* const* d_in, const int* in_sizes, int n_in,
                              void* d_out, int out_size, void* d_ws, size_t ws_size,
                              hipStream_t stream)
{
  (void)n_in; (void)ws_size;
  const float* h0   = (const float*)d_in[0];
  const float* e_f  = (const float*)d_in[1];
  const int*   srcI = (const int*)d_in[2];
  const int*   dstI = (const int*)d_in[3];
  const int*   gid  = (const int*)d_in[4];
  const float* lin0 = (const float*)d_in[6];
  const float* linW = (const float*)d_in[7];
  const float* WeW  = (const float*)d_in[8];
  const float* WqW  = (const float*)d_in[9];
  const float* WkW  = (const float*)d_in[10];
  const float* WvW  = (const float*)d_in[11];
  const float* lng  = (const float*)d_in[12];
  const float* lnb  = (const float*)d_in[13];
  const float* outW = (const float*)d_in[14];
  const float* outb = (const float*)d_in[15];
  const float* projW= (const float*)d_in[16];
  const float* projb= (const float*)d_in[17];
  const float* Wih0 = (const float*)d_in[18];
  const float* Whh0 = (const float*)d_in[19];
  const float* bih0 = (const float*)d_in[20];
  const float* bhh0 = (const float*)d_in[21];
  const float* Wih1 = (const float*)d_in[22];
  const float* Whh1 = (const float*)d_in[23];
  const float* bih1 = (const float*)d_in[24];
  const float* bhh1 = (const float*)d_in[25];
  float* outp = (float*)d_out;

  const int N = in_sizes[0] / INF_;
  const int E = in_sizes[2];

  // Workspace ledger (N=20000, E=160000): ~192 MB total — keep under 256 MiB.
  char* wp = (char*)d_ws;
  auto alloc = [&](size_t bytes) -> void* {
    void* p = (void*)wp;
    wp += (bytes + 255) & ~(size_t)255;
    return p;
  };
  unsigned short* Zb  = (unsigned short*)alloc((size_t)N * 512 * 2);   // 20.5 MB
  unsigned short* UTb = (unsigned short*)alloc((size_t)N * 1536 * 2);  // 61.4 MB
  unsigned short* aggZE = (unsigned short*)alloc((size_t)N * 640 * 2); // 25.6 MB
  float* zh   = (float*)alloc((size_t)N * 512 * 4);                    // 41.0 MB
  float* hcur = (float*)alloc((size_t)N * 128 * 4);                    // 10.2 MB
  float* ssb  = (float*)alloc((size_t)N * H_ * 4);
  float* elog = (float*)alloc((size_t)E * H_ * 6 * 4);                 // 15.4 MB
  float* efp  = (float*)alloc((size_t)E * EF_ * 4);                    //  7.0 MB
  float* WeQ  = (float*)alloc((size_t)C_ * H_ * EF_ * 128 * 4);
  float* WeK  = (float*)alloc((size_t)C_ * H_ * EF_ * 128 * 4);
  float* WeV  = (float*)alloc((size_t)C_ * H_ * EF_ * 128 * 4);
  float* M2   = (float*)alloc((size_t)C_ * H_ * EF_ * EF_ * 4);
  float* GqT  = (float*)alloc((size_t)C_ * H_ * EF_ * 128 * 4);
  float* GcT  = (float*)alloc((size_t)C_ * H_ * EF_ * 128 * 4);
  float* Mbuf = (float*)alloc((size_t)C_ * H_ * 16384 * 4);
  unsigned short* WkPl  = (unsigned short*)alloc((size_t)C_ * H_ * 16384 * 2);
  unsigned short* UTBt  = (unsigned short*)alloc((size_t)C_ * H_ * 3 * 16384 * 2);
  unsigned short* WvE   = (unsigned short*)alloc((size_t)C_ * H_ * 20480 * 2);
  unsigned short* linBt0 = (unsigned short*)alloc((size_t)4 * 128 * INF_ * 2);
  unsigned short* linBt12= (unsigned short*)alloc((size_t)2 * 512 * 128 * 2);
  unsigned short* outBt  = (unsigned short*)alloc((size_t)C_ * 128 * 512 * 2);
  unsigned short* projBt = (unsigned short*)alloc((size_t)128 * INF_ * 2);
  int* deg    = (int*)alloc((size_t)N * 4);
  int* cursor = (int*)alloc((size_t)N * 4);
  int* rowp   = (int*)alloc((size_t)(N + 1) * 4);
  int* eids   = (int*)alloc((size_t)E * 4);
  int* srcp   = (int*)alloc((size_t)E * 4);
  int* dstp   = (int*)alloc((size_t)E * 4);
  float* gm74 = (float*)alloc((size_t)G_ * INF_ * 4);
  float* seq  = (float*)alloc((size_t)T_ * G_ * 128 * 4);
  float* seq1 = (float*)alloc((size_t)T_ * G_ * 256 * 4);
  float* fparts=(float*)alloc((size_t)4 * G_ * 128 * 4);

  const int gM = (N + 127) / 128;

  // --- CSR build + permuted metadata ---
  hipMemsetAsync(deg, 0, (size_t)N * 4, stream);
  hipMemsetAsync(cursor, 0, (size_t)N * 4, stream);
  k_hist<<<(E + 255) / 256, 256, 0, stream>>>(dstI, deg, E);
  k_scan<<<1, 1024, 0, stream>>>(deg, rowp, N);
  k_fill<<<(E + 255) / 256, 256, 0, stream>>>(srcI, dstI, rowp, cursor,
                                              eids, srcp, dstp, E);
  k_efperm<<<(E * EF_ + 255) / 256, 256, 0, stream>>>(e_f, eids, efp, E);

  // --- small weight folding ---
  k_small<<<C_ * H_, 128, 0, stream>>>(WeW, WqW, WkW, WvW, WeQ, WeK, WeV, M2,
                                       GqT, GcT);
  k_wve<<<C_ * H_, 128, 0, stream>>>(WvW, WeV, WvE);

  // --- weight conversions pass 1 ---
  {
    WPack w{};
    int nw = 0;
    auto addw = [&](const float* s, unsigned short* d, int K, int D, int tr) {
      w.d[nw].src = s; w.d[nw].dst = d; w.d[nw].K = K; w.d[nw].D = D;
      w.d[nw].trans = tr; nw++;
    };
    for (int h = 0; h < 4; h++)
      addw(lin0 + (size_t)h * INF_ * 128, linBt0 + (size_t)h * 128 * INF_, INF_, 128, 1);
    for (int j = 1; j < 3; j++)
      for (int h = 0; h < 4; h++)
        addw(linW + ((size_t)(j - 1) * 4 + h) * 16384,
             linBt12 + (size_t)(j - 1) * 65536 + (size_t)h * 16384, 128, 128, 1);
    for (int j = 0; j < 3; j++)
      addw(outW + (size_t)j * 65536, outBt + (size_t)j * 65536, 512, 128, 1);
    addw(projW, projBt, INF_, 128, 1);
    for (int ch = 0; ch < 12; ch++)
      addw(WkW + (size_t)ch * 16384, WkPl + (size_t)ch * 16384, 128, 128, 0);
    k_wcvt<<<dim3(64, nw), 256, 0, stream>>>(w);
  }

  // --- M = Wq @ Wk^T per (layer,head), f32 out ---
  k_mfma<float><<<dim3(1, 1, 12), 256, 0, stream>>>(
      WqW, 128, 16384, 128, 128, WkPl, 0, 16384,
      Mbuf, 128, 0, 16384, nullptr, nullptr, 0, 0, 0);

  // --- pass 2: UTBt = [M | M^T | Gq/Gc] bf16 ---
  {
    WPack w{};
    int nw = 0;
    for (int ch = 0; ch < 12; ch++) {
      w.d[nw++] = { Mbuf + (size_t)ch * 16384, UTBt + (size_t)ch * 49152,
                    128, 128, 0 };
      w.d[nw++] = { Mbuf + (size_t)ch * 16384, UTBt + (size_t)ch * 49152 + 16384,
                    128, 128, 1 };
    }
    k_wcvt<<<dim3(64, nw), 256, 0, stream>>>(w);
    k_bcw<<<12, 256, 0, stream>>>(GqT, GcT, UTBt);
  }

  // --- GRU input t=0: seg-mean(h0) then proj ---
  k_gmean<<<G_, 128, 0, stream>>>(h0, gid, gm74, N, INF_);
  k_mfma<float><<<dim3(4, 1, 1), 256, 0, stream>>>(
      gm74, INF_, 0, G_, INF_, projBt, 0, 0,
      seq, 128, 0, 0, projb, nullptr, 0, 0, 0);

  // --- conv layers ---
  for (int j = 0; j < C_; j++) {
    // lin -> Zb bf16 [N][H][128]
    if (j == 0)
      k_mfma<float><<<dim3(gM, 4, 1), 256, 0, stream>>>(
          h0, INF_, 0, N, INF_, linBt0, 128 * INF_, 0,
          nullptr, 0, 0, 0, nullptr, Zb, 512, 128, 0);
    else
      k_mfma<float><<<dim3(gM, 4, 1), 256, 0, stream>>>(
          hcur, 128, 0, N, 128, linBt12 + (size_t)(j - 1) * 65536, 16384, 0,
          nullptr, 0, 0, 0, nullptr, Zb, 512, 128, 0);
    // u,t,B/C = [M|M^T|G] Z -> UTb bf16 [N][H][3][128]
    k_mfma<unsigned short><<<dim3(gM, 3, 4), 256, 0, stream>>>(
        Zb, 512, 128, N, 128, UTBt + (size_t)j * 4 * 49152, 16384, 49152,
        nullptr, 0, 0, 0, nullptr, UTb, 1536, 128, 384);
    k_ss<<<N, 256, 0, stream>>>(Zb, UTb, ssb, N);
    k_elog<<<(E + 63) / 64, 256, 0, stream>>>(UTb, ssb, M2, efp, srcp, dstp,
                                              elog, E, j);
    k_edge<<<N, 256, 0, stream>>>(Zb, UTb, ssb, elog, efp, rowp, srcp, aggZE, N);
    // messages: zh[N][h*128+d] = aggZE @ [Wv;WeV]
    k_mfma<unsigned short><<<dim3(gM, 1, 4), 256, 0, stream>>>(
        aggZE, 640, 160, N, 160, WvE + (size_t)j * 4 * 20480, 0, 20480,
        zh, 512, 0, 128, nullptr, nullptr, 0, 0, 0);
    k_ln<<<N, 256, 0, stream>>>(zh, lng, lnb, N, j);
    // out GEMM
    k_mfma<float><<<dim3(gM, 1, 1), 256, 0, stream>>>(
        zh, 512, 0, N, 512, outBt + (size_t)j * 65536, 0, 0,
        hcur, 128, 0, 0, outb + j * 128, nullptr, 0, 0, 0);
    k_gmean<<<G_, 128, 0, stream>>>(hcur, gid, seq + (size_t)(j + 1) * G_ * 128, N, 128);
  }

  // --- GRU readout ---
  k_gru<<<dim3(G_, 2), 128, 0, stream>>>(seq, 128, Wih0, Whh0, bih0, bhh0,
                                         seq1, fparts);
  k_gru<<<dim3(G_, 2), 128, 0, stream>>>(seq1, 256, Wih1, Whh1, bih1, bhh1,
                                         nullptr, fparts + 2 * G_ * 128);
  k_final<<<(out_size + 255) / 256, 256, 0, stream>>>(fparts, outp, out_size);
}

// Round 8
// 1333.945 us; speedup vs baseline: 2.5351x; 1.0437x over previous
//
#include <hip/hip_runtime.h>
#include <cstdint>

#define D_   128
#define H_   4
#define C_   3
#define G_   512
#define INF_ 74
#define EF_  11
#define T_   4
#define NW_  48

typedef __attribute__((ext_vector_type(8))) short bf16x8;
typedef __attribute__((ext_vector_type(4))) float f32x4;

__device__ inline unsigned short f2bf(float x) {
  unsigned u = __float_as_uint(x);
  unsigned r = u + 0x7fffu + ((u >> 16) & 1u);
  return (unsigned short)(r >> 16);
}
__device__ inline float bf2f(unsigned short x) {
  return __uint_as_float(((unsigned)x) << 16);
}
__device__ inline void unpack8(uint4 u, float* f) {
  f[0] = __uint_as_float(u.x << 16); f[1] = __uint_as_float(u.x & 0xffff0000u);
  f[2] = __uint_as_float(u.y << 16); f[3] = __uint_as_float(u.y & 0xffff0000u);
  f[4] = __uint_as_float(u.z << 16); f[5] = __uint_as_float(u.z & 0xffff0000u);
  f[6] = __uint_as_float(u.w << 16); f[7] = __uint_as_float(u.w & 0xffff0000u);
}

// ---------------------------------------------------------------------------
// Weight convert: trans ? dst[d*K+k]=bf16(src[k*D+d]) : dst[i]=bf16(src[i])
// ---------------------------------------------------------------------------
struct WDesc { const float* src; unsigned short* dst; int K; int D; int trans; };
struct WPack { WDesc d[NW_]; };

__global__ __launch_bounds__(256) void k_wcvt(WPack wp)
{
  WDesc w = wp.d[blockIdx.y];
  int tot = w.K * w.D;
  for (int i = blockIdx.x * 256 + threadIdx.x; i < tot; i += gridDim.x * 256) {
    if (w.trans) {
      int d = i / w.K, k = i - d * w.K;
      w.dst[i] = f2bf(w.src[(size_t)k * w.D + d]);
    } else {
      w.dst[i] = f2bf(w.src[i]);
    }
  }
}

// ---------------------------------------------------------------------------
// Build UTBt third col-block: rows 0..10 = GqT[ch], 11..21 = GcT[ch], else 0.
// ---------------------------------------------------------------------------
__global__ __launch_bounds__(256) void k_bcw(
    const float* __restrict__ GqT, const float* __restrict__ GcT,
    unsigned short* __restrict__ UTBt)
{
  int ch = blockIdx.x;
  unsigned short* dst = UTBt + (size_t)ch * 49152 + 32768;
  const float* gq = GqT + (size_t)ch * EF_ * 128;
  const float* gc = GcT + (size_t)ch * EF_ * 128;
  for (int i = threadIdx.x; i < 16384; i += 256) {
    int r = i >> 7, k = i & 127;
    float v = (r < EF_) ? gq[r * 128 + k]
            : (r < 2 * EF_) ? gc[(r - EF_) * 128 + k] : 0.f;
    dst[i] = f2bf(v);
  }
}

// ---------------------------------------------------------------------------
// MFMA bf16 GEMM, A f32 (converted in staging) or bf16. 128x128 tile,
// 4 waves 2x2, mfma_f32_16x16x32_bf16. Out: f32 (+bias) or bf16.
// ---------------------------------------------------------------------------
template <typename AT>
__global__ __launch_bounds__(256) void k_mfma(
    const AT* __restrict__ A, int lda, int aOffZ, int M, int K,
    const unsigned short* __restrict__ Bt, int btOffY, int btOffZ,
    float* __restrict__ outF, int ldc, int cOffY, int cOffZ,
    const float* __restrict__ bias,
    unsigned short* __restrict__ outH, int hStride, int hOffY, int hOffZ)
{
  const int bx = blockIdx.x, by = blockIdx.y, bz = blockIdx.z;
  A += (size_t)bz * aOffZ;
  const unsigned short* Bp = Bt + (size_t)by * btOffY + (size_t)bz * btOffZ;
  const int rowBase = bx * 128;
  __shared__ unsigned short As[128][40];
  __shared__ unsigned short Bs[128][40];
  const int t = threadIdx.x;
  const int w = t >> 6, l = t & 63;
  const int wr = w >> 1, wc = w & 1;
  const int fr = l & 15, fq = l >> 4;
  f32x4 acc[4][4];
#pragma unroll
  for (int m = 0; m < 4; m++)
#pragma unroll
    for (int n = 0; n < 4; n++) acc[m][n] = (f32x4){0.f, 0.f, 0.f, 0.f};

  const int sr = t >> 1, sh = t & 1;
  const int arow = rowBase + sr;
  const AT* aBase = A + (size_t)arow * lda;

  for (int k0 = 0; k0 < K; k0 += 32) {
    int kb = k0 + sh * 16;
    if constexpr (sizeof(AT) == 4) {
      unsigned short tmp[16];
      if (arow < M && kb + 16 <= K) {
        const AT* ap = aBase + kb;
#pragma unroll
        for (int i = 0; i < 16; i++) tmp[i] = f2bf(ap[i]);
      } else {
#pragma unroll
        for (int i = 0; i < 16; i++) {
          int gk = kb + i;
          float v = (arow < M && gk < K) ? (float)aBase[gk] : 0.f;
          tmp[i] = f2bf(v);
        }
      }
      *(uint4*)&As[sr][sh * 16]     = *(const uint4*)&tmp[0];
      *(uint4*)&As[sr][sh * 16 + 8] = *(const uint4*)&tmp[8];
    } else {
      if (arow < M && kb + 16 <= K) {
        const unsigned short* ap = (const unsigned short*)aBase + kb;
        *(uint4*)&As[sr][sh * 16]     = *(const uint4*)(ap);
        *(uint4*)&As[sr][sh * 16 + 8] = *(const uint4*)(ap + 8);
      } else {
#pragma unroll
        for (int i = 0; i < 16; i++) {
          int gk = kb + i;
          As[sr][sh * 16 + i] = (arow < M && gk < K)
              ? ((const unsigned short*)aBase)[gk] : (unsigned short)0;
        }
      }
    }
    if (t < 128) {
      unsigned short tmp[32];
      if (k0 + 32 <= K) {
        const unsigned short* bp = Bp + (size_t)t * K + k0;
#pragma unroll
        for (int i = 0; i < 32; i++) tmp[i] = bp[i];
      } else {
#pragma unroll
        for (int i = 0; i < 32; i++) {
          int gk = k0 + i;
          tmp[i] = (gk < K) ? Bp[(size_t)t * K + gk] : (unsigned short)0;
        }
      }
#pragma unroll
      for (int i = 0; i < 4; i++) *(uint4*)&Bs[t][i * 8] = *(const uint4*)&tmp[i * 8];
    }
    __syncthreads();
    bf16x8 af[4], bfr[4];
#pragma unroll
    for (int m = 0; m < 4; m++) af[m]  = *(const bf16x8*)&As[wr * 64 + m * 16 + fr][fq * 8];
#pragma unroll
    for (int n = 0; n < 4; n++) bfr[n] = *(const bf16x8*)&Bs[wc * 64 + n * 16 + fr][fq * 8];
#pragma unroll
    for (int m = 0; m < 4; m++)
#pragma unroll
      for (int n = 0; n < 4; n++)
        acc[m][n] = __builtin_amdgcn_mfma_f32_16x16x32_bf16(af[m], bfr[n], acc[m][n], 0, 0, 0);
    __syncthreads();
  }
#pragma unroll
  for (int m = 0; m < 4; m++) {
    int row0 = rowBase + wr * 64 + m * 16 + fq * 4;
#pragma unroll
    for (int n = 0; n < 4; n++) {
      int col = wc * 64 + n * 16 + fr;
#pragma unroll
      for (int r = 0; r < 4; r++) {
        int row = row0 + r;
        if (row < M) {
          float v = acc[m][n][r];
          if (outH) {
            outH[(size_t)row * hStride + by * hOffY + bz * hOffZ + col] = f2bf(v);
          } else {
            if (bias) v += bias[col];
            outF[(size_t)row * ldc + by * cOffY + bz * cOffZ + col] = v;
          }
        }
      }
    }
  }
}

// ---------------------------------------------------------------------------
// CSR build (by dst) + permuted metadata
// ---------------------------------------------------------------------------
__global__ void k_hist(const int* __restrict__ dst, int* __restrict__ deg, int E)
{
  int e = blockIdx.x * blockDim.x + threadIdx.x;
  if (e < E) atomicAdd(&deg[dst[e]], 1);
}

__global__ __launch_bounds__(1024) void k_scan(const int* __restrict__ deg,
                                               int* __restrict__ rowp, int N)
{
  __shared__ int part[1024];
  int t = threadIdx.x;
  int chunk = (N + 1023) / 1024;
  int base = t * chunk;
  int s = 0;
  for (int i = 0; i < chunk; i++) { int idx = base + i; if (idx < N) s += deg[idx]; }
  part[t] = s;
  __syncthreads();
  for (int off = 1; off < 1024; off <<= 1) {
    int v = (t >= off) ? part[t - off] : 0;
    __syncthreads();
    part[t] += v;
    __syncthreads();
  }
  int run = part[t] - s;
  for (int i = 0; i < chunk; i++) {
    int idx = base + i;
    if (idx < N) { rowp[idx] = run; run += deg[idx]; }
  }
  if (t == 1023) rowp[N] = part[1023];
}

__global__ void k_fill(const int* __restrict__ src, const int* __restrict__ dst,
                       const int* __restrict__ rowp, int* __restrict__ cursor,
                       int* __restrict__ eids, int* __restrict__ src_perm,
                       int* __restrict__ dst_perm, int E)
{
  int e = blockIdx.x * blockDim.x + threadIdx.x;
  if (e < E) {
    int d = dst[e];
    int pos = atomicAdd(&cursor[d], 1);
    int slot = rowp[d] + pos;
    eids[slot] = e;
    src_perm[slot] = src[e];
    dst_perm[slot] = d;
  }
}

__global__ void k_efperm(const float* __restrict__ e_f, const int* __restrict__ eids,
                         float* __restrict__ ef_perm, int E)
{
  int i = blockIdx.x * blockDim.x + threadIdx.x;
  if (i < E * EF_) {
    int idx = i / EF_, f = i - idx * EF_;
    ef_perm[i] = e_f[(size_t)eids[idx] * EF_ + f];
  }
}

// ---------------------------------------------------------------------------
// Small weight folding: WeQ/WeK/WeV = We@W{q,k,v} [11,128]; M2 = WeQ@WeK^T;
// GqT[f][d] = (Wq WeK^T)^T, GcT[f][d] = (Wk WeQ^T)^T  (for B/C from Z).
// ---------------------------------------------------------------------------
__global__ __launch_bounds__(128) void k_small(
    const float* __restrict__ WeW, const float* __restrict__ WqW,
    const float* __restrict__ WkW, const float* __restrict__ WvW,
    float* __restrict__ WeQ, float* __restrict__ WeK, float* __restrict__ WeV,
    float* __restrict__ M2, float* __restrict__ GqT, float* __restrict__ GcT)
{
  int ch = blockIdx.x;
  const float* We = WeW + (size_t)ch * EF_ * 128;
  const float* Wq = WqW + (size_t)ch * 128 * 128;
  const float* Wk = WkW + (size_t)ch * 128 * 128;
  const float* Wv = WvW + (size_t)ch * 128 * 128;
  __shared__ float sWe[EF_ * 128], sQ[EF_ * 128], sK[EF_ * 128];
  int d = threadIdx.x;
  for (int i = d; i < EF_ * 128; i += 128) sWe[i] = We[i];
  __syncthreads();
  for (int f = 0; f < EF_; f++) {
    float aq = 0.f, ak = 0.f, av = 0.f;
    for (int k = 0; k < 128; k++) {
      float w = sWe[f * 128 + k];
      aq += w * Wq[k * 128 + d];
      ak += w * Wk[k * 128 + d];
      av += w * Wv[k * 128 + d];
    }
    WeQ[(size_t)ch * EF_ * 128 + f * 128 + d] = aq;
    WeK[(size_t)ch * EF_ * 128 + f * 128 + d] = ak;
    WeV[(size_t)ch * EF_ * 128 + f * 128 + d] = av;
    sQ[f * 128 + d] = aq;
    sK[f * 128 + d] = ak;
  }
  __syncthreads();
  if (d < EF_ * EF_) {
    int a = d / EF_, b = d % EF_;
    float s = 0.f;
    for (int k = 0; k < 128; k++) s += sQ[a * 128 + k] * sK[b * 128 + k];
    M2[(size_t)ch * (EF_ * EF_) + d] = s;
  }
  // GqT[f][d] = sum_k Wq[d][k]*WeK[f][k]; GcT[f][d] = sum_k Wk[d][k]*WeQ[f][k]
  for (int f = 0; f < EF_; f++) {
    float aq = 0.f, ac = 0.f;
    for (int k = 0; k < 128; k++) {
      aq += Wq[(size_t)d * 128 + k] * sK[f * 128 + k];
      ac += Wk[(size_t)d * 128 + k] * sQ[f * 128 + k];
    }
    GqT[(size_t)ch * EF_ * 128 + f * 128 + d] = aq;
    GcT[(size_t)ch * EF_ * 128 + f * 128 + d] = ac;
  }
}

// ---------------------------------------------------------------------------
// Build combined post-message weight: WvE[ch][out d][k160]:
// k<128 -> Wv[k][d]; 128<=k<139 -> WeV[k-128][d]; else 0.
// ---------------------------------------------------------------------------
__global__ __launch_bounds__(128) void k_wve(
    const float* __restrict__ WvW, const float* __restrict__ WeV,
    unsigned short* __restrict__ WvE)
{
  int ch = blockIdx.x;
  const float* Wv  = WvW + (size_t)ch * 16384;
  const float* wev = WeV + (size_t)ch * EF_ * 128;
  unsigned short* dst = WvE + (size_t)ch * 20480;
  for (int i = threadIdx.x; i < 20480; i += 128) {
    int d = i / 160, k = i - d * 160;
    float v = (k < 128) ? Wv[(size_t)k * 128 + d]
            : (k < 128 + EF_) ? wev[(size_t)(k - 128) * 128 + d] : 0.f;
    dst[i] = f2bf(v);
  }
}

// ---------------------------------------------------------------------------
// Per-node ss = Z.u (UTb bf16: [N][H][3][128] = [u|t|B,C,junk]). Wave per (n,h).
// ---------------------------------------------------------------------------
__global__ __launch_bounds__(256) void k_ss(
    const unsigned short* __restrict__ Zb, const unsigned short* __restrict__ UTb,
    float* __restrict__ ss, int N)
{
  int h = threadIdx.x >> 6, lane = threadIdx.x & 63;
  int n = blockIdx.x;
  unsigned uz = *(const unsigned*)(Zb + (size_t)n * 512 + h * 128 + 2 * lane);
  unsigned uu = *(const unsigned*)(UTb + (size_t)n * 1536 + h * 384 + 2 * lane);
  float zx = __uint_as_float(uz << 16), zy = __uint_as_float(uz & 0xffff0000u);
  float ux = __uint_as_float(uu << 16), uy = __uint_as_float(uu & 0xffff0000u);
  float p = zx * ux + zy * uy;
#pragma unroll
  for (int m = 32; m; m >>= 1) p += __shfl_xor(p, m, 64);
  if (lane == 0) ss[n * H_ + h] = p;
}

// ---------------------------------------------------------------------------
// Per-edge precomputed logits: elog[idx][h][6] = {ss_s, se, de, es, ed, ee}
// B/C read from UTb slot 2 (bf16).
// ---------------------------------------------------------------------------
__global__ __launch_bounds__(256) void k_elog(
    const unsigned short* __restrict__ UTb, const float* __restrict__ ss,
    const float* __restrict__ M2, const float* __restrict__ ef_perm,
    const int* __restrict__ src_perm, const int* __restrict__ dst_perm,
    float* __restrict__ elog, int E, int layer)
{
  int i0 = blockIdx.x * 64;
  __shared__ float efs[64 * EF_];
  __shared__ float m2s[4 * EF_ * EF_];
  int t = threadIdx.x;
  for (int i = t; i < 64 * EF_; i += 256) {
    int gi = i0 * EF_ + i;
    efs[i] = (gi < E * EF_) ? ef_perm[gi] : 0.f;
  }
  for (int i = t; i < 4 * EF_ * EF_; i += 256)
    m2s[i] = M2[(size_t)layer * 4 * EF_ * EF_ + i];
  __syncthreads();
  int sl = t >> 2, h = t & 3;
  int idx = i0 + sl;
  if (idx < E) {
    int s = src_perm[idx], d = dst_perm[idx];
    const float* ef = &efs[sl * EF_];
    const float* m2 = &m2s[h * EF_ * EF_];
    float ee = 0.f;
#pragma unroll
    for (int a = 0; a < EF_; a++) {
      float r = 0.f;
#pragma unroll
      for (int b = 0; b < EF_; b++) r += m2[a * EF_ + b] * ef[b];
      ee += ef[a] * r;
    }
    const unsigned short* bs = UTb + (size_t)s * 1536 + h * 384 + 256;
    const unsigned short* cs = bs + EF_;
    const unsigned short* bd = UTb + (size_t)d * 1536 + h * 384 + 256;
    const unsigned short* cd = bd + EF_;
    float se = 0.f, es = 0.f, de = 0.f, ed = 0.f;
#pragma unroll
    for (int f = 0; f < EF_; f++) {
      float e = ef[f];
      se += bf2f(bs[f]) * e;
      es += bf2f(cs[f]) * e;
      de += bf2f(bd[f]) * e;
      ed += bf2f(cd[f]) * e;
    }
    float* o = elog + ((size_t)idx * H_ + h) * 6;
    o[0] = ss[s * H_ + h];
    o[1] = se; o[2] = de; o[3] = es; o[4] = ed; o[5] = ee;
  }
}

// ---------------------------------------------------------------------------
// Edge aggregation in Z-space: wave per (dst,head); gathers ONLY Z_s (256 B).
// v1 = Zs.u_d, v2 = Zs.t_d (u/t bf16, dst-side). Writes aggZE bf16
// [n][h][160] = [aggZ(128)|a11(11)|0].
// ---------------------------------------------------------------------------
__global__ __launch_bounds__(256) void k_edge(
    const unsigned short* __restrict__ Zb, const unsigned short* __restrict__ UTb,
    const float* __restrict__ ss, const float* __restrict__ elog,
    const float* __restrict__ ef_perm, const int* __restrict__ rowp,
    const int* __restrict__ src_perm, unsigned short* __restrict__ aggZE, int N)
{
  const int h = threadIdx.x >> 6;
  const int lane = threadIdx.x & 63;
  const int q = lane & 15;
  const int g = lane >> 4;
  const int lb = lane & 48;
  const int n = blockIdx.x;

  float zd[8], ud[8], td[8];
  unpack8(*(const uint4*)(Zb + (size_t)n * 512 + h * 128 + q * 8), zd);
  const unsigned short* utp = UTb + (size_t)n * 1536 + h * 384 + q * 8;
  unpack8(*(const uint4*)(utp), ud);
  unpack8(*(const uint4*)(utp + 128), td);
  const float ssd = ss[n * H_ + h];
  const int beg = rowp[n], end = rowp[n + 1];
  float acc[8];
#pragma unroll
  for (int i = 0; i < 8; i++) acc[i] = 0.f;
  float wdsum = 0.f, a11 = 0.f;

  for (int idx0 = beg; idx0 < end; idx0 += 4) {
    int idxg = idx0 + g;
    bool act = idxg < end;
    int idxc = act ? idxg : beg;
    int s = src_perm[idxc];
    float zs[8];
    unpack8(*(const uint4*)(Zb + (size_t)s * 512 + h * 128 + q * 8), zs);
    float v1 = 0.f, v2 = 0.f;
#pragma unroll
    for (int i = 0; i < 8; i++) {
      v1 += zs[i] * ud[i];
      v2 += zs[i] * td[i];
    }
#pragma unroll
    for (int m = 1; m < 16; m <<= 1) {
      v1 += __shfl_xor(v1, m, 64);
      v2 += __shfl_xor(v2, m, 64);
    }
    float lv = (q < 6) ? elog[((size_t)idxc * H_ + h) * 6 + q] : 0.f;
    float S00 = __shfl(lv, lb + 0, 64);
    float S02 = __shfl(lv, lb + 1, 64);
    float S12 = __shfl(lv, lb + 2, 64);
    float S20 = __shfl(lv, lb + 3, 64);
    float S21 = __shfl(lv, lb + 4, 64);
    float S22 = __shfl(lv, lb + 5, 64);
    float m0 = fmaxf(fmaxf(S00, v1), S02);
    float e00 = __expf(S00 - m0), e01 = __expf(v1 - m0), e02 = __expf(S02 - m0);
    float i0r = 1.f / (e00 + e01 + e02);
    float m1 = fmaxf(fmaxf(v2, ssd), S12);
    float e10 = __expf(v2 - m1), e11 = __expf(ssd - m1), e12 = __expf(S12 - m1);
    float i1r = 1.f / (e10 + e11 + e12);
    float m2 = fmaxf(fmaxf(S20, S21), S22);
    float e20 = __expf(S20 - m2), e21 = __expf(S21 - m2), e22 = __expf(S22 - m2);
    float i2r = 1.f / (e20 + e21 + e22);
    float w0 = e00 * i0r + e10 * i1r + e20 * i2r;
    float w1 = e01 * i0r + e11 * i1r + e21 * i2r;
    float w2 = e02 * i0r + e12 * i1r + e22 * i2r;
    if (!act) { w0 = 0.f; w1 = 0.f; w2 = 0.f; }
#pragma unroll
    for (int i = 0; i < 8; i++) acc[i] += w0 * zs[i];
    wdsum += w1;
    float efl = (q < EF_) ? ef_perm[(size_t)idxc * EF_ + q] : 0.f;
    a11 += w2 * efl;
  }
#pragma unroll
  for (int m = 16; m < 64; m <<= 1) {
#pragma unroll
    for (int i = 0; i < 8; i++) acc[i] += __shfl_xor(acc[i], m, 64);
    wdsum += __shfl_xor(wdsum, m, 64);
    a11 += __shfl_xor(a11, m, 64);
  }
  int cnt = end - beg;
  float invc = (cnt > 0) ? 1.f / (float)cnt : 1.f;
  unsigned short* ob = aggZE + (size_t)n * 640 + h * 160;
  if (g == 0) {
    unsigned short tmp[8];
#pragma unroll
    for (int i = 0; i < 8; i++) tmp[i] = f2bf((acc[i] + wdsum * zd[i]) * invc);
    *(uint4*)(ob + q * 8) = *(const uint4*)&tmp[0];
    ob[128 + q] = (q < EF_) ? f2bf(a11 * invc) : (unsigned short)0;  // 128..143
  } else if (g == 1) {
    ob[144 + q] = 0;                                                 // 144..159
  }
}

// ---------------------------------------------------------------------------
// Fused ReLU + LayerNorm per (node, head), in place on zh[N,512].
// ---------------------------------------------------------------------------
__global__ __launch_bounds__(256) void k_ln(
    float* __restrict__ zh, const float* __restrict__ lng,
    const float* __restrict__ lnb, int N, int layer)
{
  int h = threadIdx.x >> 6, lane = threadIdx.x & 63;
  int n = blockIdx.x;
  float* p = zh + (size_t)n * 512 + h * 128 + 2 * lane;
  float2 v = *(const float2*)p;
  v.x = fmaxf(v.x, 0.f); v.y = fmaxf(v.y, 0.f);
  float s1 = v.x + v.y;
#pragma unroll
  for (int m = 32; m; m >>= 1) s1 += __shfl_xor(s1, m, 64);
  float mean = s1 * (1.f / 128.f);
  float dx = v.x - mean, dy = v.y - mean;
  float s2 = dx * dx + dy * dy;
#pragma unroll
  for (int m = 32; m; m >>= 1) s2 += __shfl_xor(s2, m, 64);
  float rstd = rsqrtf(s2 * (1.f / 128.f) + 1e-5f);
  int gi = (layer * H_ + h) * 128 + 2 * lane;
  float2 g2 = *(const float2*)&lng[gi];
  float2 b2 = *(const float2*)&lnb[gi];
  float2 o;
  o.x = dx * rstd * g2.x + b2.x;
  o.y = dy * rstd * g2.y + b2.y;
  *(float2*)p = o;
}

// ---------------------------------------------------------------------------
// Segment mean by graph id (node_gid sorted): one block per graph.
// ---------------------------------------------------------------------------
__global__ void k_gmean(const float* __restrict__ X, const int* __restrict__ gid,
                        float* __restrict__ outp, int N, int ld)
{
  int g = blockIdx.x;
  int lo = 0, hi = N;
  while (lo < hi) { int m = (lo + hi) >> 1; if (gid[m] < g) lo = m + 1; else hi = m; }
  int s0 = lo;
  lo = s0; hi = N;
  while (lo < hi) { int m = (lo + hi) >> 1; if (gid[m] < g + 1) lo = m + 1; else hi = m; }
  int s1 = lo;
  float inv = 1.f / (float)((s1 - s0) > 0 ? (s1 - s0) : 1);
  for (int d = threadIdx.x; d < ld; d += blockDim.x) {
    float s = 0.f;
    for (int n = s0; n < s1; n++) s += X[(size_t)n * ld + d];
    outp[(size_t)g * ld + d] = s * inv;
  }
}

// ---------------------------------------------------------------------------
// GRU recurrent-only pass. Input gates gi = seq @ Wih^T precomputed by MFMA
// (gi[T*G][768], dir*384+t). Block = (graph, dir), 384 threads: thread t owns
// gate output t (t<128: r, <256: z, else n). Inner loop: 1 coalesced Whh load
// + 1 FMA per k. Gates exchanged via LDS.
// ---------------------------------------------------------------------------
__global__ __launch_bounds__(384) void k_gruR(
    const float* __restrict__ gi, const float* __restrict__ Whh,
    const float* __restrict__ bih, const float* __restrict__ bhh,
    float* __restrict__ yout, float* __restrict__ hfinal)
{
  const int g = blockIdx.x, dir = blockIdx.y, t = threadIdx.x;
  const float* W = Whh + (size_t)dir * 128 * 384 + t;
  const float bi = bih[dir * 384 + t];
  const float bh = bhh[dir * 384 + t];
  __shared__ float hb[128];
  __shared__ float rb[128], zb[128], nb[128];
  if (t < 128) hb[t] = 0.f;
  __syncthreads();
  for (int st = 0; st < T_; st++) {
    int ts = dir ? (T_ - 1 - st) : st;
    float acc = bh;
    for (int k = 0; k < 128; k++) acc += hb[k] * W[(size_t)k * 384];
    float gv = gi[((size_t)ts * G_ + g) * 768 + dir * 384 + t] + bi;
    if (t < 128) {
      rb[t] = 1.f / (1.f + __expf(-(gv + acc)));
    } else if (t < 256) {
      zb[t - 128] = 1.f / (1.f + __expf(-(gv + acc)));
    }
    __syncthreads();
    if (t >= 256) nb[t - 256] = tanhf(gv + rb[t - 256] * acc);
    __syncthreads();
    if (t < 128) {
      float z = zb[t];
      float h = (1.f - z) * nb[t] + z * hb[t];
      hb[t] = h;
      if (yout) yout[((size_t)ts * G_ + g) * 256 + dir * 128 + t] = h;
    }
    __syncthreads();
  }
  if (t < 128) hfinal[((size_t)dir * G_ + g) * 128 + t] = hb[t];
}

__global__ void k_final(const float* __restrict__ fp, float* __restrict__ outp, int n)
{
  int i = blockIdx.x * blockDim.x + threadIdx.x;
  if (i < n) {
    outp[i] = fp[i] + fp[G_ * 128 + i] + fp[2 * G_ * 128 + i] + fp[3 * G_ * 128 + i];
  }
}

// ---------------------------------------------------------------------------
extern "C" void kernel_launch(void* const* d_in, const int* in_sizes, int n_in,
                              void* d_out, int out_size, void* d_ws, size_t ws_size,
                              hipStream_t stream)
{
  (void)n_in; (void)ws_size;
  const float* h0   = (const float*)d_in[0];
  const float* e_f  = (const float*)d_in[1];
  const int*   srcI = (const int*)d_in[2];
  const int*   dstI = (const int*)d_in[3];
  const int*   gid  = (const int*)d_in[4];
  const float* lin0 = (const float*)d_in[6];
  const float* linW = (const float*)d_in[7];
  const float* WeW  = (const float*)d_in[8];
  const float* WqW  = (const float*)d_in[9];
  const float* WkW  = (const float*)d_in[10];
  const float* WvW  = (const float*)d_in[11];
  const float* lng  = (const float*)d_in[12];
  const float* lnb  = (const float*)d_in[13];
  const float* outW = (const float*)d_in[14];
  const float* outb = (const float*)d_in[15];
  const float* projW= (const float*)d_in[16];
  const float* projb= (const float*)d_in[17];
  const float* Wih0 = (const float*)d_in[18];
  const float* Whh0 = (const float*)d_in[19];
  const float* bih0 = (const float*)d_in[20];
  const float* bhh0 = (const float*)d_in[21];
  const float* Wih1 = (const float*)d_in[22];
  const float* Whh1 = (const float*)d_in[23];
  const float* bih1 = (const float*)d_in[24];
  const float* bhh1 = (const float*)d_in[25];
  float* outp = (float*)d_out;

  const int N = in_sizes[0] / INF_;
  const int E = in_sizes[2];

  // Workspace ledger (N=20000, E=160000): ~199 MB total — keep under 256 MiB.
  char* wp = (char*)d_ws;
  auto alloc = [&](size_t bytes) -> void* {
    void* p = (void*)wp;
    wp += (bytes + 255) & ~(size_t)255;
    return p;
  };
  unsigned short* Zb  = (unsigned short*)alloc((size_t)N * 512 * 2);   // 20.5 MB
  unsigned short* UTb = (unsigned short*)alloc((size_t)N * 1536 * 2);  // 61.4 MB
  unsigned short* aggZE = (unsigned short*)alloc((size_t)N * 640 * 2); // 25.6 MB
  float* zh   = (float*)alloc((size_t)N * 512 * 4);                    // 41.0 MB
  float* hcur = (float*)alloc((size_t)N * 128 * 4);                    // 10.2 MB
  float* ssb  = (float*)alloc((size_t)N * H_ * 4);
  float* elog = (float*)alloc((size_t)E * H_ * 6 * 4);                 // 15.4 MB
  float* efp  = (float*)alloc((size_t)E * EF_ * 4);                    //  7.0 MB
  float* WeQ  = (float*)alloc((size_t)C_ * H_ * EF_ * 128 * 4);
  float* WeK  = (float*)alloc((size_t)C_ * H_ * EF_ * 128 * 4);
  float* WeV  = (float*)alloc((size_t)C_ * H_ * EF_ * 128 * 4);
  float* M2   = (float*)alloc((size_t)C_ * H_ * EF_ * EF_ * 4);
  float* GqT  = (float*)alloc((size_t)C_ * H_ * EF_ * 128 * 4);
  float* GcT  = (float*)alloc((size_t)C_ * H_ * EF_ * 128 * 4);
  float* Mbuf = (float*)alloc((size_t)C_ * H_ * 16384 * 4);
  unsigned short* WkPl  = (unsigned short*)alloc((size_t)C_ * H_ * 16384 * 2);
  unsigned short* UTBt  = (unsigned short*)alloc((size_t)C_ * H_ * 3 * 16384 * 2);
  unsigned short* WvE   = (unsigned short*)alloc((size_t)C_ * H_ * 20480 * 2);
  unsigned short* linBt0 = (unsigned short*)alloc((size_t)4 * 128 * INF_ * 2);
  unsigned short* linBt12= (unsigned short*)alloc((size_t)2 * 512 * 128 * 2);
  unsigned short* outBt  = (unsigned short*)alloc((size_t)C_ * 128 * 512 * 2);
  unsigned short* projBt = (unsigned short*)alloc((size_t)128 * INF_ * 2);
  unsigned short* WihBt0 = (unsigned short*)alloc((size_t)768 * 128 * 2);
  unsigned short* WihBt1 = (unsigned short*)alloc((size_t)768 * 256 * 2);
  float* gibuf = (float*)alloc((size_t)T_ * G_ * 768 * 4);             //  6.3 MB
  int* deg    = (int*)alloc((size_t)N * 4);
  int* cursor = (int*)alloc((size_t)N * 4);
  int* rowp   = (int*)alloc((size_t)(N + 1) * 4);
  int* eids   = (int*)alloc((size_t)E * 4);
  int* srcp   = (int*)alloc((size_t)E * 4);
  int* dstp   = (int*)alloc((size_t)E * 4);
  float* gm74 = (float*)alloc((size_t)G_ * INF_ * 4);
  float* seq  = (float*)alloc((size_t)T_ * G_ * 128 * 4);
  float* seq1 = (float*)alloc((size_t)T_ * G_ * 256 * 4);
  float* fparts=(float*)alloc((size_t)4 * G_ * 128 * 4);

  const int gM = (N + 127) / 128;

  // --- CSR build + permuted metadata ---
  hipMemsetAsync(deg, 0, (size_t)N * 4, stream);
  hipMemsetAsync(cursor, 0, (size_t)N * 4, stream);
  k_hist<<<(E + 255) / 256, 256, 0, stream>>>(dstI, deg, E);
  k_scan<<<1, 1024, 0, stream>>>(deg, rowp, N);
  k_fill<<<(E + 255) / 256, 256, 0, stream>>>(srcI, dstI, rowp, cursor,
                                              eids, srcp, dstp, E);
  k_efperm<<<(E * EF_ + 255) / 256, 256, 0, stream>>>(e_f, eids, efp, E);

  // --- small weight folding ---
  k_small<<<C_ * H_, 128, 0, stream>>>(WeW, WqW, WkW, WvW, WeQ, WeK, WeV, M2,
                                       GqT, GcT);
  k_wve<<<C_ * H_, 128, 0, stream>>>(WvW, WeV, WvE);

  // --- weight conversions pass 1 ---
  {
    WPack w{};
    int nw = 0;
    auto addw = [&](const float* s, unsigned short* d, int K, int D, int tr) {
      w.d[nw].src = s; w.d[nw].dst = d; w.d[nw].K = K; w.d[nw].D = D;
      w.d[nw].trans = tr; nw++;
    };
    for (int h = 0; h < 4; h++)
      addw(lin0 + (size_t)h * INF_ * 128, linBt0 + (size_t)h * 128 * INF_, INF_, 128, 1);
    for (int j = 1; j < 3; j++)
      for (int h = 0; h < 4; h++)
        addw(linW + ((size_t)(j - 1) * 4 + h) * 16384,
             linBt12 + (size_t)(j - 1) * 65536 + (size_t)h * 16384, 128, 128, 1);
    for (int j = 0; j < 3; j++)
      addw(outW + (size_t)j * 65536, outBt + (size_t)j * 65536, 512, 128, 1);
    addw(projW, projBt, INF_, 128, 1);
    for (int ch = 0; ch < 12; ch++)
      addw(WkW + (size_t)ch * 16384, WkPl + (size_t)ch * 16384, 128, 128, 0);
    // GRU input-gate weights: WihBt = Wih^T bf16 per dir -> [768][inDim]
    for (int dir = 0; dir < 2; dir++) {
      addw(Wih0 + (size_t)dir * 128 * 384, WihBt0 + (size_t)dir * 384 * 128,
           128, 384, 1);
      addw(Wih1 + (size_t)dir * 256 * 384, WihBt1 + (size_t)dir * 384 * 256,
           256, 384, 1);
    }
    k_wcvt<<<dim3(64, nw), 256, 0, stream>>>(w);
  }

  // --- M = Wq @ Wk^T per (layer,head), f32 out ---
  k_mfma<float><<<dim3(1, 1, 12), 256, 0, stream>>>(
      WqW, 128, 16384, 128, 128, WkPl, 0, 16384,
      Mbuf, 128, 0, 16384, nullptr, nullptr, 0, 0, 0);

  // --- pass 2: UTBt = [M | M^T | Gq/Gc] bf16 ---
  {
    WPack w{};
    int nw = 0;
    for (int ch = 0; ch < 12; ch++) {
      w.d[nw++] = { Mbuf + (size_t)ch * 16384, UTBt + (size_t)ch * 49152,
                    128, 128, 0 };
      w.d[nw++] = { Mbuf + (size_t)ch * 16384, UTBt + (size_t)ch * 49152 + 16384,
                    128, 128, 1 };
    }
    k_wcvt<<<dim3(64, nw), 256, 0, stream>>>(w);
    k_bcw<<<12, 256, 0, stream>>>(GqT, GcT, UTBt);
  }

  // --- GRU input t=0: seg-mean(h0) then proj ---
  k_gmean<<<G_, 128, 0, stream>>>(h0, gid, gm74, N, INF_);
  k_mfma<float><<<dim3(4, 1, 1), 256, 0, stream>>>(
      gm74, INF_, 0, G_, INF_, projBt, 0, 0,
      seq, 128, 0, 0, projb, nullptr, 0, 0, 0);

  // --- conv layers ---
  for (int j = 0; j < C_; j++) {
    // lin -> Zb bf16 [N][H][128]
    if (j == 0)
      k_mfma<float><<<dim3(gM, 4, 1), 256, 0, stream>>>(
          h0, INF_, 0, N, INF_, linBt0, 128 * INF_, 0,
          nullptr, 0, 0, 0, nullptr, Zb, 512, 128, 0);
    else
      k_mfma<float><<<dim3(gM, 4, 1), 256, 0, stream>>>(
          hcur, 128, 0, N, 128, linBt12 + (size_t)(j - 1) * 65536, 16384, 0,
          nullptr, 0, 0, 0, nullptr, Zb, 512, 128, 0);
    // u,t,B/C = [M|M^T|G] Z -> UTb bf16 [N][H][3][128]
    k_mfma<unsigned short><<<dim3(gM, 3, 4), 256, 0, stream>>>(
        Zb, 512, 128, N, 128, UTBt + (size_t)j * 4 * 49152, 16384, 49152,
        nullptr, 0, 0, 0, nullptr, UTb, 1536, 128, 384);
    k_ss<<<N, 256, 0, stream>>>(Zb, UTb, ssb, N);
    k_elog<<<(E + 63) / 64, 256, 0, stream>>>(UTb, ssb, M2, efp, srcp, dstp,
                                              elog, E, j);
    k_edge<<<N, 256, 0, stream>>>(Zb, UTb, ssb, elog, efp, rowp, srcp, aggZE, N);
    // messages: zh[N][h*128+d] = aggZE @ [Wv;WeV]
    k_mfma<unsigned short><<<dim3(gM, 1, 4), 256, 0, stream>>>(
        aggZE, 640, 160, N, 160, WvE + (size_t)j * 4 * 20480, 0, 20480,
        zh, 512, 0, 128, nullptr, nullptr, 0, 0, 0);
    k_ln<<<N, 256, 0, stream>>>(zh, lng, lnb, N, j);
    // out GEMM
    k_mfma<float><<<dim3(gM, 1, 1), 256, 0, stream>>>(
        zh, 512, 0, N, 512, outBt + (size_t)j * 65536, 0, 0,
        hcur, 128, 0, 0, outb + j * 128, nullptr, 0, 0, 0);
    k_gmean<<<G_, 128, 0, stream>>>(hcur, gid, seq + (size_t)(j + 1) * G_ * 128, N, 128);
  }

  // --- GRU readout: input gates via MFMA, recurrent via k_gruR ---
  k_mfma<float><<<dim3(16, 6, 1), 256, 0, stream>>>(
      seq, 128, 0, T_ * G_, 128, WihBt0, 128 * 128, 0,
      gibuf, 768, 128, 0, nullptr, nullptr, 0, 0, 0);
  k_gruR<<<dim3(G_, 2), 384, 0, stream>>>(gibuf, Whh0, bih0, bhh0,
                                          seq1, fparts);
  k_mfma<float><<<dim3(16, 6, 1), 256, 0, stream>>>(
      seq1, 256, 0, T_ * G_, 256, WihBt1, 128 * 256, 0,
      gibuf, 768, 128, 0, nullptr, nullptr, 0, 0, 0);
  k_gruR<<<dim3(G_, 2), 384, 0, stream>>>(gibuf, Whh1, bih1, bhh1,
                                          nullptr, fparts + 2 * G_ * 128);
  k_final<<<(out_size + 255) / 256, 256, 0, stream>>>(fparts, outp, out_size);
}

// Round 9
// 1236.647 us; speedup vs baseline: 2.7345x; 1.0787x over previous
//
#include <hip/hip_runtime.h>
#include <cstdint>

#define D_   128
#define H_   4
#define C_   3
#define G_   512
#define INF_ 74
#define EF_  11
#define T_   4
#define NW_  48

typedef __attribute__((ext_vector_type(8))) short bf16x8;
typedef __attribute__((ext_vector_type(4))) float f32x4;

__device__ inline unsigned short f2bf(float x) {
  unsigned u = __float_as_uint(x);
  unsigned r = u + 0x7fffu + ((u >> 16) & 1u);
  return (unsigned short)(r >> 16);
}
__device__ inline float bf2f(unsigned short x) {
  return __uint_as_float(((unsigned)x) << 16);
}
__device__ inline void unpack8(uint4 u, float* f) {
  f[0] = __uint_as_float(u.x << 16); f[1] = __uint_as_float(u.x & 0xffff0000u);
  f[2] = __uint_as_float(u.y << 16); f[3] = __uint_as_float(u.y & 0xffff0000u);
  f[4] = __uint_as_float(u.z << 16); f[5] = __uint_as_float(u.z & 0xffff0000u);
  f[6] = __uint_as_float(u.w << 16); f[7] = __uint_as_float(u.w & 0xffff0000u);
}

// ---------------------------------------------------------------------------
// Weight convert: trans ? dst[d*K+k]=bf16(src[k*D+d]) : dst[i]=bf16(src[i])
// ---------------------------------------------------------------------------
struct WDesc { const float* src; unsigned short* dst; int K; int D; int trans; };
struct WPack { WDesc d[NW_]; };

__global__ __launch_bounds__(256) void k_wcvt(WPack wp)
{
  WDesc w = wp.d[blockIdx.y];
  int tot = w.K * w.D;
  for (int i = blockIdx.x * 256 + threadIdx.x; i < tot; i += gridDim.x * 256) {
    if (w.trans) {
      int d = i / w.K, k = i - d * w.K;
      w.dst[i] = f2bf(w.src[(size_t)k * w.D + d]);
    } else {
      w.dst[i] = f2bf(w.src[i]);
    }
  }
}

// ---------------------------------------------------------------------------
// Small weight folding, f-parallel: grid (12, EF_), block 128.
// WeQ/WeK/WeV rows = We[f] @ W{q,k,v}; GqT[f][d] = Wq[d]·WeK[f],
// GcT[f][d] = Wk[d]·WeQ[f].
// ---------------------------------------------------------------------------
__global__ __launch_bounds__(128) void k_small1(
    const float* __restrict__ WeW, const float* __restrict__ WqW,
    const float* __restrict__ WkW, const float* __restrict__ WvW,
    float* __restrict__ WeQ, float* __restrict__ WeK, float* __restrict__ WeV,
    float* __restrict__ GqT, float* __restrict__ GcT)
{
  int ch = blockIdx.x, f = blockIdx.y;
  const float* We = WeW + (size_t)ch * EF_ * 128 + f * 128;
  const float* Wq = WqW + (size_t)ch * 16384;
  const float* Wk = WkW + (size_t)ch * 16384;
  const float* Wv = WvW + (size_t)ch * 16384;
  __shared__ float sWe[128], sQ[128], sK[128];
  int d = threadIdx.x;
  sWe[d] = We[d];
  __syncthreads();
  float aq = 0.f, ak = 0.f, av = 0.f;
  for (int k = 0; k < 128; k++) {
    float w = sWe[k];
    aq += w * Wq[k * 128 + d];
    ak += w * Wk[k * 128 + d];
    av += w * Wv[k * 128 + d];
  }
  size_t off = (size_t)ch * EF_ * 128 + f * 128 + d;
  WeQ[off] = aq; WeK[off] = ak; WeV[off] = av;
  sQ[d] = aq; sK[d] = ak;
  __syncthreads();
  float gq = 0.f, gc = 0.f;
  for (int k = 0; k < 128; k++) {
    gq += Wq[(size_t)d * 128 + k] * sK[k];
    gc += Wk[(size_t)d * 128 + k] * sQ[k];
  }
  GqT[off] = gq; GcT[off] = gc;
}

// M2[a][b] = WeQ[a]·WeK[b], LDS-staged. grid 12, block 128.
__global__ __launch_bounds__(128) void k_small2(
    const float* __restrict__ WeQ, const float* __restrict__ WeK,
    float* __restrict__ M2)
{
  int ch = blockIdx.x;
  __shared__ float sQ[EF_ * 128], sK[EF_ * 128];
  int t = threadIdx.x;
  for (int i = t; i < EF_ * 128; i += 128) {
    sQ[i] = WeQ[(size_t)ch * EF_ * 128 + i];
    sK[i] = WeK[(size_t)ch * EF_ * 128 + i];
  }
  __syncthreads();
  if (t < EF_ * EF_) {
    int a = t / EF_, b = t % EF_;
    float s = 0.f;
    for (int k = 0; k < 128; k++) s += sQ[a * 128 + k] * sK[b * 128 + k];
    M2[(size_t)ch * (EF_ * EF_) + t] = s;
  }
}

// ---------------------------------------------------------------------------
// Build UTBt: slot0 = M, slot1 = M^T, slot2 = [GqT;GcT;0]. grid (12,3).
// ---------------------------------------------------------------------------
__global__ __launch_bounds__(256) void k_utbt(
    const float* __restrict__ Mbuf, const float* __restrict__ GqT,
    const float* __restrict__ GcT, unsigned short* __restrict__ UTBt)
{
  int ch = blockIdx.x, slot = blockIdx.y;
  unsigned short* dst = UTBt + (size_t)ch * 49152 + slot * 16384;
  for (int i = threadIdx.x; i < 16384; i += 256) {
    int r = i >> 7, k = i & 127;
    float v;
    if (slot == 0)      v = Mbuf[(size_t)ch * 16384 + i];
    else if (slot == 1) v = Mbuf[(size_t)ch * 16384 + k * 128 + r];
    else v = (r < EF_) ? GqT[(size_t)ch * EF_ * 128 + r * 128 + k]
          : (r < 2 * EF_) ? GcT[(size_t)ch * EF_ * 128 + (r - EF_) * 128 + k] : 0.f;
    dst[i] = f2bf(v);
  }
}

// ---------------------------------------------------------------------------
// MFMA bf16 GEMM, A f32 (converted in staging) or bf16. 128x128 tile,
// 4 waves 2x2, mfma_f32_16x16x32_bf16. Out: f32 (+bias) or bf16.
// ---------------------------------------------------------------------------
template <typename AT>
__global__ __launch_bounds__(256) void k_mfma(
    const AT* __restrict__ A, int lda, int aOffZ, int M, int K,
    const unsigned short* __restrict__ Bt, int btOffY, int btOffZ,
    float* __restrict__ outF, int ldc, int cOffY, int cOffZ,
    const float* __restrict__ bias,
    unsigned short* __restrict__ outH, int hStride, int hOffY, int hOffZ)
{
  const int bx = blockIdx.x, by = blockIdx.y, bz = blockIdx.z;
  A += (size_t)bz * aOffZ;
  const unsigned short* Bp = Bt + (size_t)by * btOffY + (size_t)bz * btOffZ;
  const int rowBase = bx * 128;
  __shared__ unsigned short As[128][40];
  __shared__ unsigned short Bs[128][40];
  const int t = threadIdx.x;
  const int w = t >> 6, l = t & 63;
  const int wr = w >> 1, wc = w & 1;
  const int fr = l & 15, fq = l >> 4;
  f32x4 acc[4][4];
#pragma unroll
  for (int m = 0; m < 4; m++)
#pragma unroll
    for (int n = 0; n < 4; n++) acc[m][n] = (f32x4){0.f, 0.f, 0.f, 0.f};

  const int sr = t >> 1, sh = t & 1;
  const int arow = rowBase + sr;
  const AT* aBase = A + (size_t)arow * lda;

  for (int k0 = 0; k0 < K; k0 += 32) {
    int kb = k0 + sh * 16;
    if constexpr (sizeof(AT) == 4) {
      unsigned short tmp[16];
      if (arow < M && kb + 16 <= K) {
        const AT* ap = aBase + kb;
#pragma unroll
        for (int i = 0; i < 16; i++) tmp[i] = f2bf(ap[i]);
      } else {
#pragma unroll
        for (int i = 0; i < 16; i++) {
          int gk = kb + i;
          float v = (arow < M && gk < K) ? (float)aBase[gk] : 0.f;
          tmp[i] = f2bf(v);
        }
      }
      *(uint4*)&As[sr][sh * 16]     = *(const uint4*)&tmp[0];
      *(uint4*)&As[sr][sh * 16 + 8] = *(const uint4*)&tmp[8];
    } else {
      if (arow < M && kb + 16 <= K) {
        const unsigned short* ap = (const unsigned short*)aBase + kb;
        *(uint4*)&As[sr][sh * 16]     = *(const uint4*)(ap);
        *(uint4*)&As[sr][sh * 16 + 8] = *(const uint4*)(ap + 8);
      } else {
#pragma unroll
        for (int i = 0; i < 16; i++) {
          int gk = kb + i;
          As[sr][sh * 16 + i] = (arow < M && gk < K)
              ? ((const unsigned short*)aBase)[gk] : (unsigned short)0;
        }
      }
    }
    if (t < 128) {
      unsigned short tmp[32];
      if (k0 + 32 <= K) {
        const unsigned short* bp = Bp + (size_t)t * K + k0;
#pragma unroll
        for (int i = 0; i < 32; i++) tmp[i] = bp[i];
      } else {
#pragma unroll
        for (int i = 0; i < 32; i++) {
          int gk = k0 + i;
          tmp[i] = (gk < K) ? Bp[(size_t)t * K + gk] : (unsigned short)0;
        }
      }
#pragma unroll
      for (int i = 0; i < 4; i++) *(uint4*)&Bs[t][i * 8] = *(const uint4*)&tmp[i * 8];
    }
    __syncthreads();
    bf16x8 af[4], bfr[4];
#pragma unroll
    for (int m = 0; m < 4; m++) af[m]  = *(const bf16x8*)&As[wr * 64 + m * 16 + fr][fq * 8];
#pragma unroll
    for (int n = 0; n < 4; n++) bfr[n] = *(const bf16x8*)&Bs[wc * 64 + n * 16 + fr][fq * 8];
#pragma unroll
    for (int m = 0; m < 4; m++)
#pragma unroll
      for (int n = 0; n < 4; n++)
        acc[m][n] = __builtin_amdgcn_mfma_f32_16x16x32_bf16(af[m], bfr[n], acc[m][n], 0, 0, 0);
    __syncthreads();
  }
#pragma unroll
  for (int m = 0; m < 4; m++) {
    int row0 = rowBase + wr * 64 + m * 16 + fq * 4;
#pragma unroll
    for (int n = 0; n < 4; n++) {
      int col = wc * 64 + n * 16 + fr;
#pragma unroll
      for (int r = 0; r < 4; r++) {
        int row = row0 + r;
        if (row < M) {
          float v = acc[m][n][r];
          if (outH) {
            outH[(size_t)row * hStride + by * hOffY + bz * hOffZ + col] = f2bf(v);
          } else {
            if (bias) v += bias[col];
            outF[(size_t)row * ldc + by * cOffY + bz * cOffZ + col] = v;
          }
        }
      }
    }
  }
}

// ---------------------------------------------------------------------------
// CSR build (by dst) + permuted metadata
// ---------------------------------------------------------------------------
__global__ void k_hist(const int* __restrict__ dst, int* __restrict__ deg, int E)
{
  int e = blockIdx.x * blockDim.x + threadIdx.x;
  if (e < E) atomicAdd(&deg[dst[e]], 1);
}

__global__ __launch_bounds__(1024) void k_scan(const int* __restrict__ deg,
                                               int* __restrict__ rowp, int N)
{
  __shared__ int part[1024];
  int t = threadIdx.x;
  int chunk = (N + 1023) / 1024;
  int base = t * chunk;
  int s = 0;
  for (int i = 0; i < chunk; i++) { int idx = base + i; if (idx < N) s += deg[idx]; }
  part[t] = s;
  __syncthreads();
  for (int off = 1; off < 1024; off <<= 1) {
    int v = (t >= off) ? part[t - off] : 0;
    __syncthreads();
    part[t] += v;
    __syncthreads();
  }
  int run = part[t] - s;
  for (int i = 0; i < chunk; i++) {
    int idx = base + i;
    if (idx < N) { rowp[idx] = run; run += deg[idx]; }
  }
  if (t == 1023) rowp[N] = part[1023];
}

__global__ void k_fill(const int* __restrict__ src, const int* __restrict__ dst,
                       const int* __restrict__ rowp, int* __restrict__ cursor,
                       int* __restrict__ eids, int* __restrict__ src_perm,
                       int* __restrict__ dst_perm, int E)
{
  int e = blockIdx.x * blockDim.x + threadIdx.x;
  if (e < E) {
    int d = dst[e];
    int pos = atomicAdd(&cursor[d], 1);
    int slot = rowp[d] + pos;
    eids[slot] = e;
    src_perm[slot] = src[e];
    dst_perm[slot] = d;
  }
}

__global__ void k_efperm(const float* __restrict__ e_f, const int* __restrict__ eids,
                         float* __restrict__ ef_perm, int E)
{
  int i = blockIdx.x * blockDim.x + threadIdx.x;
  if (i < E * EF_) {
    int idx = i / EF_, f = i - idx * EF_;
    ef_perm[i] = e_f[(size_t)eids[idx] * EF_ + f];
  }
}

// ---------------------------------------------------------------------------
// Build combined post-message weight: WvE[ch][out d][k160]:
// k<128 -> Wv[k][d]; 128<=k<139 -> WeV[k-128][d]; else 0.
// ---------------------------------------------------------------------------
__global__ __launch_bounds__(128) void k_wve(
    const float* __restrict__ WvW, const float* __restrict__ WeV,
    unsigned short* __restrict__ WvE)
{
  int ch = blockIdx.x;
  const float* Wv  = WvW + (size_t)ch * 16384;
  const float* wev = WeV + (size_t)ch * EF_ * 128;
  unsigned short* dst = WvE + (size_t)ch * 20480;
  for (int i = threadIdx.x; i < 20480; i += 128) {
    int d = i / 160, k = i - d * 160;
    float v = (k < 128) ? Wv[(size_t)k * 128 + d]
            : (k < 128 + EF_) ? wev[(size_t)(k - 128) * 128 + d] : 0.f;
    dst[i] = f2bf(v);
  }
}

// ---------------------------------------------------------------------------
// Per-node ss = Z.u (UTb bf16: [N][H][3][128] = [u|t|B,C,junk]). Wave per (n,h).
// ---------------------------------------------------------------------------
__global__ __launch_bounds__(256) void k_ss(
    const unsigned short* __restrict__ Zb, const unsigned short* __restrict__ UTb,
    float* __restrict__ ss, int N)
{
  int h = threadIdx.x >> 6, lane = threadIdx.x & 63;
  int n = blockIdx.x;
  unsigned uz = *(const unsigned*)(Zb + (size_t)n * 512 + h * 128 + 2 * lane);
  unsigned uu = *(const unsigned*)(UTb + (size_t)n * 1536 + h * 384 + 2 * lane);
  float zx = __uint_as_float(uz << 16), zy = __uint_as_float(uz & 0xffff0000u);
  float ux = __uint_as_float(uu << 16), uy = __uint_as_float(uu & 0xffff0000u);
  float p = zx * ux + zy * uy;
#pragma unroll
  for (int m = 32; m; m >>= 1) p += __shfl_xor(p, m, 64);
  if (lane == 0) ss[n * H_ + h] = p;
}

// ---------------------------------------------------------------------------
// Per-edge precomputed logits: elog[idx][h][6] = {ss_s, se, de, es, ed, ee}
// B/C read from UTb slot 2 (bf16).
// ---------------------------------------------------------------------------
__global__ __launch_bounds__(256) void k_elog(
    const unsigned short* __restrict__ UTb, const float* __restrict__ ss,
    const float* __restrict__ M2, const float* __restrict__ ef_perm,
    const int* __restrict__ src_perm, const int* __restrict__ dst_perm,
    float* __restrict__ elog, int E, int layer)
{
  int i0 = blockIdx.x * 64;
  __shared__ float efs[64 * EF_];
  __shared__ float m2s[4 * EF_ * EF_];
  int t = threadIdx.x;
  for (int i = t; i < 64 * EF_; i += 256) {
    int gi = i0 * EF_ + i;
    efs[i] = (gi < E * EF_) ? ef_perm[gi] : 0.f;
  }
  for (int i = t; i < 4 * EF_ * EF_; i += 256)
    m2s[i] = M2[(size_t)layer * 4 * EF_ * EF_ + i];
  __syncthreads();
  int sl = t >> 2, h = t & 3;
  int idx = i0 + sl;
  if (idx < E) {
    int s = src_perm[idx], d = dst_perm[idx];
    const float* ef = &efs[sl * EF_];
    const float* m2 = &m2s[h * EF_ * EF_];
    float ee = 0.f;
#pragma unroll
    for (int a = 0; a < EF_; a++) {
      float r = 0.f;
#pragma unroll
      for (int b = 0; b < EF_; b++) r += m2[a * EF_ + b] * ef[b];
      ee += ef[a] * r;
    }
    const unsigned short* bs = UTb + (size_t)s * 1536 + h * 384 + 256;
    const unsigned short* cs = bs + EF_;
    const unsigned short* bd = UTb + (size_t)d * 1536 + h * 384 + 256;
    const unsigned short* cd = bd + EF_;
    float se = 0.f, es = 0.f, de = 0.f, ed = 0.f;
#pragma unroll
    for (int f = 0; f < EF_; f++) {
      float e = ef[f];
      se += bf2f(bs[f]) * e;
      es += bf2f(cs[f]) * e;
      de += bf2f(bd[f]) * e;
      ed += bf2f(cd[f]) * e;
    }
    float* o = elog + ((size_t)idx * H_ + h) * 6;
    o[0] = ss[s * H_ + h];
    o[1] = se; o[2] = de; o[3] = es; o[4] = ed; o[5] = ee;
  }
}

// ---------------------------------------------------------------------------
// Edge aggregation in Z-space: wave per (dst,head); gathers ONLY Z_s (256 B).
// Logits are O(1) by construction -> softmax without max-subtraction.
// ---------------------------------------------------------------------------
__global__ __launch_bounds__(256) void k_edge(
    const unsigned short* __restrict__ Zb, const unsigned short* __restrict__ UTb,
    const float* __restrict__ ss, const float* __restrict__ elog,
    const float* __restrict__ ef_perm, const int* __restrict__ rowp,
    const int* __restrict__ src_perm, unsigned short* __restrict__ aggZE, int N)
{
  const int h = threadIdx.x >> 6;
  const int lane = threadIdx.x & 63;
  const int q = lane & 15;
  const int g = lane >> 4;
  const int lb = lane & 48;
  const int n = blockIdx.x;

  float zd[8], ud[8], td[8];
  unpack8(*(const uint4*)(Zb + (size_t)n * 512 + h * 128 + q * 8), zd);
  const unsigned short* utp = UTb + (size_t)n * 1536 + h * 384 + q * 8;
  unpack8(*(const uint4*)(utp), ud);
  unpack8(*(const uint4*)(utp + 128), td);
  const float essd = __expf(ss[n * H_ + h]);
  const int beg = rowp[n], end = rowp[n + 1];
  float acc[8];
#pragma unroll
  for (int i = 0; i < 8; i++) acc[i] = 0.f;
  float wdsum = 0.f, a11 = 0.f;

  for (int idx0 = beg; idx0 < end; idx0 += 4) {
    int idxg = idx0 + g;
    bool act = idxg < end;
    int idxc = act ? idxg : beg;
    int s = src_perm[idxc];
    float zs[8];
    unpack8(*(const uint4*)(Zb + (size_t)s * 512 + h * 128 + q * 8), zs);
    float v1 = 0.f, v2 = 0.f;
#pragma unroll
    for (int i = 0; i < 8; i++) {
      v1 += zs[i] * ud[i];
      v2 += zs[i] * td[i];
    }
#pragma unroll
    for (int m = 1; m < 16; m <<= 1) {
      v1 += __shfl_xor(v1, m, 64);
      v2 += __shfl_xor(v2, m, 64);
    }
    float lv = (q < 6) ? elog[((size_t)idxc * H_ + h) * 6 + q] : 0.f;
    float S00 = __shfl(lv, lb + 0, 64);
    float S02 = __shfl(lv, lb + 1, 64);
    float S12 = __shfl(lv, lb + 2, 64);
    float S20 = __shfl(lv, lb + 3, 64);
    float S21 = __shfl(lv, lb + 4, 64);
    float S22 = __shfl(lv, lb + 5, 64);
    // rows: [s: S00 v1 S02] [d: v2 ss S12] [e: S20 S21 S22]; |S| small ->
    // direct exp (no max-subtraction).
    float e00 = __expf(S00), e01 = __expf(v1), e02 = __expf(S02);
    float i0r = 1.f / (e00 + e01 + e02);
    float e10 = __expf(v2), e12 = __expf(S12);
    float i1r = 1.f / (e10 + essd + e12);
    float e20 = __expf(S20), e21 = __expf(S21), e22 = __expf(S22);
    float i2r = 1.f / (e20 + e21 + e22);
    float w0 = e00 * i0r + e10 * i1r + e20 * i2r;
    float w1 = e01 * i0r + essd * i1r + e21 * i2r;
    float w2 = e02 * i0r + e12 * i1r + e22 * i2r;
    if (!act) { w0 = 0.f; w1 = 0.f; w2 = 0.f; }
#pragma unroll
    for (int i = 0; i < 8; i++) acc[i] += w0 * zs[i];
    wdsum += w1;
    float efl = (q < EF_) ? ef_perm[(size_t)idxc * EF_ + q] : 0.f;
    a11 += w2 * efl;
  }
#pragma unroll
  for (int m = 16; m < 64; m <<= 1) {
#pragma unroll
    for (int i = 0; i < 8; i++) acc[i] += __shfl_xor(acc[i], m, 64);
    wdsum += __shfl_xor(wdsum, m, 64);
    a11 += __shfl_xor(a11, m, 64);
  }
  int cnt = end - beg;
  float invc = (cnt > 0) ? 1.f / (float)cnt : 1.f;
  unsigned short* ob = aggZE + (size_t)n * 640 + h * 160;
  if (g == 0) {
    unsigned short tmp[8];
#pragma unroll
    for (int i = 0; i < 8; i++) tmp[i] = f2bf((acc[i] + wdsum * zd[i]) * invc);
    *(uint4*)(ob + q * 8) = *(const uint4*)&tmp[0];
    ob[128 + q] = (q < EF_) ? f2bf(a11 * invc) : (unsigned short)0;  // 128..143
  } else if (g == 1) {
    ob[144 + q] = 0;                                                 // 144..159
  }
}

// ---------------------------------------------------------------------------
// Fused ReLU + LayerNorm per (node, head), in place on zh[N,512].
// ---------------------------------------------------------------------------
__global__ __launch_bounds__(256) void k_ln(
    float* __restrict__ zh, const float* __restrict__ lng,
    const float* __restrict__ lnb, int N, int layer)
{
  int h = threadIdx.x >> 6, lane = threadIdx.x & 63;
  int n = blockIdx.x;
  float* p = zh + (size_t)n * 512 + h * 128 + 2 * lane;
  float2 v = *(const float2*)p;
  v.x = fmaxf(v.x, 0.f); v.y = fmaxf(v.y, 0.f);
  float s1 = v.x + v.y;
#pragma unroll
  for (int m = 32; m; m >>= 1) s1 += __shfl_xor(s1, m, 64);
  float mean = s1 * (1.f / 128.f);
  float dx = v.x - mean, dy = v.y - mean;
  float s2 = dx * dx + dy * dy;
#pragma unroll
  for (int m = 32; m; m >>= 1) s2 += __shfl_xor(s2, m, 64);
  float rstd = rsqrtf(s2 * (1.f / 128.f) + 1e-5f);
  int gi = (layer * H_ + h) * 128 + 2 * lane;
  float2 g2 = *(const float2*)&lng[gi];
  float2 b2 = *(const float2*)&lnb[gi];
  float2 o;
  o.x = dx * rstd * g2.x + b2.x;
  o.y = dy * rstd * g2.y + b2.y;
  *(float2*)p = o;
}

// ---------------------------------------------------------------------------
// Segment mean, node-range split 4-way per graph: grid (G, 4), block 128.
// Output must be pre-zeroed; partials accumulated via atomicAdd.
// ---------------------------------------------------------------------------
__global__ void k_gmean(const float* __restrict__ X, const int* __restrict__ gid,
                        float* __restrict__ outp, int N, int ld)
{
  int g = blockIdx.x, part = blockIdx.y;
  int lo = 0, hi = N;
  while (lo < hi) { int m = (lo + hi) >> 1; if (gid[m] < g) lo = m + 1; else hi = m; }
  int s0 = lo;
  lo = s0; hi = N;
  while (lo < hi) { int m = (lo + hi) >> 1; if (gid[m] < g + 1) lo = m + 1; else hi = m; }
  int s1 = lo;
  int cnt = s1 - s0;
  float inv = 1.f / (float)(cnt > 0 ? cnt : 1);
  int r0 = s0 + (cnt * part) / 4;
  int r1 = s0 + (cnt * (part + 1)) / 4;
  if (r1 <= r0) return;
  for (int d = threadIdx.x; d < ld; d += blockDim.x) {
    float s = 0.f;
    for (int n = r0; n < r1; n++) s += X[(size_t)n * ld + d];
    atomicAdd(&outp[(size_t)g * ld + d], s * inv);
  }
}

// ---------------------------------------------------------------------------
// GRU recurrent-only pass (input gates precomputed by MFMA).
// ---------------------------------------------------------------------------
__global__ __launch_bounds__(384) void k_gruR(
    const float* __restrict__ gi, const float* __restrict__ Whh,
    const float* __restrict__ bih, const float* __restrict__ bhh,
    float* __restrict__ yout, float* __restrict__ hfinal)
{
  const int g = blockIdx.x, dir = blockIdx.y, t = threadIdx.x;
  const float* W = Whh + (size_t)dir * 128 * 384 + t;
  const float bi = bih[dir * 384 + t];
  const float bh = bhh[dir * 384 + t];
  __shared__ float hb[128];
  __shared__ float rb[128], zb[128], nb[128];
  if (t < 128) hb[t] = 0.f;
  __syncthreads();
  for (int st = 0; st < T_; st++) {
    int ts = dir ? (T_ - 1 - st) : st;
    float acc = bh;
    for (int k = 0; k < 128; k++) acc += hb[k] * W[(size_t)k * 384];
    float gv = gi[((size_t)ts * G_ + g) * 768 + dir * 384 + t] + bi;
    if (t < 128) {
      rb[t] = 1.f / (1.f + __expf(-(gv + acc)));
    } else if (t < 256) {
      zb[t - 128] = 1.f / (1.f + __expf(-(gv + acc)));
    }
    __syncthreads();
    if (t >= 256) nb[t - 256] = tanhf(gv + rb[t - 256] * acc);
    __syncthreads();
    if (t < 128) {
      float z = zb[t];
      float h = (1.f - z) * nb[t] + z * hb[t];
      hb[t] = h;
      if (yout) yout[((size_t)ts * G_ + g) * 256 + dir * 128 + t] = h;
    }
    __syncthreads();
  }
  if (t < 128) hfinal[((size_t)dir * G_ + g) * 128 + t] = hb[t];
}

__global__ void k_final(const float* __restrict__ fp, float* __restrict__ outp, int n)
{
  int i = blockIdx.x * blockDim.x + threadIdx.x;
  if (i < n) {
    outp[i] = fp[i] + fp[G_ * 128 + i] + fp[2 * G_ * 128 + i] + fp[3 * G_ * 128 + i];
  }
}

// ---------------------------------------------------------------------------
extern "C" void kernel_launch(void* const* d_in, const int* in_sizes, int n_in,
                              void* d_out, int out_size, void* d_ws, size_t ws_size,
                              hipStream_t stream)
{
  (void)n_in; (void)ws_size;
  const float* h0   = (const float*)d_in[0];
  const float* e_f  = (const float*)d_in[1];
  const int*   srcI = (const int*)d_in[2];
  const int*   dstI = (const int*)d_in[3];
  const int*   gid  = (const int*)d_in[4];
  const float* lin0 = (const float*)d_in[6];
  const float* linW = (const float*)d_in[7];
  const float* WeW  = (const float*)d_in[8];
  const float* WqW  = (const float*)d_in[9];
  const float* WkW  = (const float*)d_in[10];
  const float* WvW  = (const float*)d_in[11];
  const float* lng  = (const float*)d_in[12];
  const float* lnb  = (const float*)d_in[13];
  const float* outW = (const float*)d_in[14];
  const float* outb = (const float*)d_in[15];
  const float* projW= (const float*)d_in[16];
  const float* projb= (const float*)d_in[17];
  const float* Wih0 = (const float*)d_in[18];
  const float* Whh0 = (const float*)d_in[19];
  const float* bih0 = (const float*)d_in[20];
  const float* bhh0 = (const float*)d_in[21];
  const float* Wih1 = (const float*)d_in[22];
  const float* Whh1 = (const float*)d_in[23];
  const float* bih1 = (const float*)d_in[24];
  const float* bhh1 = (const float*)d_in[25];
  float* outp = (float*)d_out;

  const int N = in_sizes[0] / INF_;
  const int E = in_sizes[2];

  // Workspace ledger (N=20000, E=160000): ~199 MB total — keep under 256 MiB.
  char* wp = (char*)d_ws;
  auto alloc = [&](size_t bytes) -> void* {
    void* p = (void*)wp;
    wp += (bytes + 255) & ~(size_t)255;
    return p;
  };
  unsigned short* Zb  = (unsigned short*)alloc((size_t)N * 512 * 2);   // 20.5 MB
  unsigned short* UTb = (unsigned short*)alloc((size_t)N * 1536 * 2);  // 61.4 MB
  unsigned short* aggZE = (unsigned short*)alloc((size_t)N * 640 * 2); // 25.6 MB
  float* zh   = (float*)alloc((size_t)N * 512 * 4);                    // 41.0 MB
  float* hcur = (float*)alloc((size_t)N * 128 * 4);                    // 10.2 MB
  float* ssb  = (float*)alloc((size_t)N * H_ * 4);
  float* elog = (float*)alloc((size_t)E * H_ * 6 * 4);                 // 15.4 MB
  float* efp  = (float*)alloc((size_t)E * EF_ * 4);                    //  7.0 MB
  float* WeQ  = (float*)alloc((size_t)C_ * H_ * EF_ * 128 * 4);
  float* WeK  = (float*)alloc((size_t)C_ * H_ * EF_ * 128 * 4);
  float* WeV  = (float*)alloc((size_t)C_ * H_ * EF_ * 128 * 4);
  float* M2   = (float*)alloc((size_t)C_ * H_ * EF_ * EF_ * 4);
  float* GqT  = (float*)alloc((size_t)C_ * H_ * EF_ * 128 * 4);
  float* GcT  = (float*)alloc((size_t)C_ * H_ * EF_ * 128 * 4);
  float* Mbuf = (float*)alloc((size_t)C_ * H_ * 16384 * 4);
  unsigned short* WkPl  = (unsigned short*)alloc((size_t)C_ * H_ * 16384 * 2);
  unsigned short* UTBt  = (unsigned short*)alloc((size_t)C_ * H_ * 3 * 16384 * 2);
  unsigned short* WvE   = (unsigned short*)alloc((size_t)C_ * H_ * 20480 * 2);
  unsigned short* linBt0 = (unsigned short*)alloc((size_t)4 * 128 * INF_ * 2);
  unsigned short* linBt12= (unsigned short*)alloc((size_t)2 * 512 * 128 * 2);
  unsigned short* outBt  = (unsigned short*)alloc((size_t)C_ * 128 * 512 * 2);
  unsigned short* projBt = (unsigned short*)alloc((size_t)128 * INF_ * 2);
  unsigned short* WihBt0 = (unsigned short*)alloc((size_t)768 * 128 * 2);
  unsigned short* WihBt1 = (unsigned short*)alloc((size_t)768 * 256 * 2);
  float* gibuf = (float*)alloc((size_t)T_ * G_ * 768 * 4);             //  6.3 MB
  int* deg    = (int*)alloc((size_t)N * 4);
  int* cursor = (int*)alloc((size_t)N * 4);
  int* rowp   = (int*)alloc((size_t)(N + 1) * 4);
  int* eids   = (int*)alloc((size_t)E * 4);
  int* srcp   = (int*)alloc((size_t)E * 4);
  int* dstp   = (int*)alloc((size_t)E * 4);
  float* gm74 = (float*)alloc((size_t)G_ * INF_ * 4);
  float* seq  = (float*)alloc((size_t)T_ * G_ * 128 * 4);
  float* seq1 = (float*)alloc((size_t)T_ * G_ * 256 * 4);
  float* fparts=(float*)alloc((size_t)4 * G_ * 128 * 4);

  const int gM = (N + 127) / 128;

  // --- CSR build + permuted metadata ---
  hipMemsetAsync(deg, 0, (size_t)N * 4, stream);
  hipMemsetAsync(cursor, 0, (size_t)N * 4, stream);
  hipMemsetAsync(gm74, 0, (size_t)G_ * INF_ * 4, stream);
  hipMemsetAsync(seq, 0, (size_t)T_ * G_ * 128 * 4, stream);
  k_hist<<<(E + 255) / 256, 256, 0, stream>>>(dstI, deg, E);
  k_scan<<<1, 1024, 0, stream>>>(deg, rowp, N);
  k_fill<<<(E + 255) / 256, 256, 0, stream>>>(srcI, dstI, rowp, cursor,
                                              eids, srcp, dstp, E);
  k_efperm<<<(E * EF_ + 255) / 256, 256, 0, stream>>>(e_f, eids, efp, E);

  // --- small weight folding (f-parallel) ---
  k_small1<<<dim3(C_ * H_, EF_), 128, 0, stream>>>(WeW, WqW, WkW, WvW,
                                                   WeQ, WeK, WeV, GqT, GcT);
  k_small2<<<C_ * H_, 128, 0, stream>>>(WeQ, WeK, M2);
  k_wve<<<C_ * H_, 128, 0, stream>>>(WvW, WeV, WvE);

  // --- weight conversions pass 1 ---
  {
    WPack w{};
    int nw = 0;
    auto addw = [&](const float* s, unsigned short* d, int K, int D, int tr) {
      w.d[nw].src = s; w.d[nw].dst = d; w.d[nw].K = K; w.d[nw].D = D;
      w.d[nw].trans = tr; nw++;
    };
    for (int h = 0; h < 4; h++)
      addw(lin0 + (size_t)h * INF_ * 128, linBt0 + (size_t)h * 128 * INF_, INF_, 128, 1);
    for (int j = 1; j < 3; j++)
      for (int h = 0; h < 4; h++)
        addw(linW + ((size_t)(j - 1) * 4 + h) * 16384,
             linBt12 + (size_t)(j - 1) * 65536 + (size_t)h * 16384, 128, 128, 1);
    for (int j = 0; j < 3; j++)
      addw(outW + (size_t)j * 65536, outBt + (size_t)j * 65536, 512, 128, 1);
    addw(projW, projBt, INF_, 128, 1);
    for (int ch = 0; ch < 12; ch++)
      addw(WkW + (size_t)ch * 16384, WkPl + (size_t)ch * 16384, 128, 128, 0);
    for (int dir = 0; dir < 2; dir++) {
      addw(Wih0 + (size_t)dir * 128 * 384, WihBt0 + (size_t)dir * 384 * 128,
           128, 384, 1);
      addw(Wih1 + (size_t)dir * 256 * 384, WihBt1 + (size_t)dir * 384 * 256,
           256, 384, 1);
    }
    k_wcvt<<<dim3(64, nw), 256, 0, stream>>>(w);
  }

  // --- M = Wq @ Wk^T per (layer,head), f32 out ---
  k_mfma<float><<<dim3(1, 1, 12), 256, 0, stream>>>(
      WqW, 128, 16384, 128, 128, WkPl, 0, 16384,
      Mbuf, 128, 0, 16384, nullptr, nullptr, 0, 0, 0);

  // --- UTBt = [M | M^T | Gq/Gc] bf16 ---
  k_utbt<<<dim3(12, 3), 256, 0, stream>>>(Mbuf, GqT, GcT, UTBt);

  // --- GRU input t=0: seg-mean(h0) then proj ---
  k_gmean<<<dim3(G_, 4), 128, 0, stream>>>(h0, gid, gm74, N, INF_);
  k_mfma<float><<<dim3(4, 1, 1), 256, 0, stream>>>(
      gm74, INF_, 0, G_, INF_, projBt, 0, 0,
      seq, 128, 0, 0, projb, nullptr, 0, 0, 0);

  // --- conv layers ---
  for (int j = 0; j < C_; j++) {
    // lin -> Zb bf16 [N][H][128]
    if (j == 0)
      k_mfma<float><<<dim3(gM, 4, 1), 256, 0, stream>>>(
          h0, INF_, 0, N, INF_, linBt0, 128 * INF_, 0,
          nullptr, 0, 0, 0, nullptr, Zb, 512, 128, 0);
    else
      k_mfma<float><<<dim3(gM, 4, 1), 256, 0, stream>>>(
          hcur, 128, 0, N, 128, linBt12 + (size_t)(j - 1) * 65536, 16384, 0,
          nullptr, 0, 0, 0, nullptr, Zb, 512, 128, 0);
    // u,t,B/C = [M|M^T|G] Z -> UTb bf16 [N][H][3][128]
    k_mfma<unsigned short><<<dim3(gM, 3, 4), 256, 0, stream>>>(
        Zb, 512, 128, N, 128, UTBt + (size_t)j * 4 * 49152, 16384, 49152,
        nullptr, 0, 0, 0, nullptr, UTb, 1536, 128, 384);
    k_ss<<<N, 256, 0, stream>>>(Zb, UTb, ssb, N);
    k_elog<<<(E + 63) / 64, 256, 0, stream>>>(UTb, ssb, M2, efp, srcp, dstp,
                                              elog, E, j);
    k_edge<<<N, 256, 0, stream>>>(Zb, UTb, ssb, elog, efp, rowp, srcp, aggZE, N);
    // messages: zh[N][h*128+d] = aggZE @ [Wv;WeV]
    k_mfma<unsigned short><<<dim3(gM, 1, 4), 256, 0, stream>>>(
        aggZE, 640, 160, N, 160, WvE + (size_t)j * 4 * 20480, 0, 20480,
        zh, 512, 0, 128, nullptr, nullptr, 0, 0, 0);
    k_ln<<<N, 256, 0, stream>>>(zh, lng, lnb, N, j);
    // out GEMM
    k_mfma<float><<<dim3(gM, 1, 1), 256, 0, stream>>>(
        zh, 512, 0, N, 512, outBt + (size_t)j * 65536, 0, 0,
        hcur, 128, 0, 0, outb + j * 128, nullptr, 0, 0, 0);
    k_gmean<<<dim3(G_, 4), 128, 0, stream>>>(hcur, gid,
                                             seq + (size_t)(j + 1) * G_ * 128, N, 128);
  }

  // --- GRU readout: input gates via MFMA, recurrent via k_gruR ---
  k_mfma<float><<<dim3(16, 6, 1), 256, 0, stream>>>(
      seq, 128, 0, T_ * G_, 128, WihBt0, 128 * 128, 0,
      gibuf, 768, 128, 0, nullptr, nullptr, 0, 0, 0);
  k_gruR<<<dim3(G_, 2), 384, 0, stream>>>(gibuf, Whh0, bih0, bhh0,
                                          seq1, fparts);
  k_mfma<float><<<dim3(16, 6, 1), 256, 0, stream>>>(
      seq1, 256, 0, T_ * G_, 256, WihBt1, 128 * 256, 0,
      gibuf, 768, 128, 0, nullptr, nullptr, 0, 0, 0);
  k_gruR<<<dim3(G_, 2), 384, 0, stream>>>(gibuf, Whh1, bih1, bhh1,
                                          nullptr, fparts + 2 * G_ * 128);
  k_final<<<(out_size + 255) / 256, 256, 0, stream>>>(fparts, outp, out_size);
}

// Round 10
// 1168.305 us; speedup vs baseline: 2.8945x; 1.0585x over previous
//
#include <hip/hip_runtime.h>
#include <cstdint>

#define D_   128
#define H_   4
#define C_   3
#define G_   512
#define INF_ 74
#define EF_  11
#define T_   4
#define NW_  48

typedef __attribute__((ext_vector_type(8))) short bf16x8;
typedef __attribute__((ext_vector_type(4))) float f32x4;

__device__ inline unsigned short f2bf(float x) {
  unsigned u = __float_as_uint(x);
  unsigned r = u + 0x7fffu + ((u >> 16) & 1u);
  return (unsigned short)(r >> 16);
}
__device__ inline float bf2f(unsigned short x) {
  return __uint_as_float(((unsigned)x) << 16);
}
__device__ inline void unpack8(uint4 u, float* f) {
  f[0] = __uint_as_float(u.x << 16); f[1] = __uint_as_float(u.x & 0xffff0000u);
  f[2] = __uint_as_float(u.y << 16); f[3] = __uint_as_float(u.y & 0xffff0000u);
  f[4] = __uint_as_float(u.z << 16); f[5] = __uint_as_float(u.z & 0xffff0000u);
  f[6] = __uint_as_float(u.w << 16); f[7] = __uint_as_float(u.w & 0xffff0000u);
}

// ---------------------------------------------------------------------------
// Weight convert: trans ? dst[d*K+k]=bf16(src[k*D+d]) : dst[i]=bf16(src[i])
// ---------------------------------------------------------------------------
struct WDesc { const float* src; unsigned short* dst; int K; int D; int trans; };
struct WPack { WDesc d[NW_]; };

__global__ __launch_bounds__(256) void k_wcvt(WPack wp)
{
  WDesc w = wp.d[blockIdx.y];
  int tot = w.K * w.D;
  for (int i = blockIdx.x * 256 + threadIdx.x; i < tot; i += gridDim.x * 256) {
    if (w.trans) {
      int d = i / w.K, k = i - d * w.K;
      w.dst[i] = f2bf(w.src[(size_t)k * w.D + d]);
    } else {
      w.dst[i] = f2bf(w.src[i]);
    }
  }
}

// ---------------------------------------------------------------------------
// Small weight folding, f-parallel: grid (12, EF_), block 128.
// ---------------------------------------------------------------------------
__global__ __launch_bounds__(128) void k_small1(
    const float* __restrict__ WeW, const float* __restrict__ WqW,
    const float* __restrict__ WkW, const float* __restrict__ WvW,
    float* __restrict__ WeQ, float* __restrict__ WeK, float* __restrict__ WeV,
    float* __restrict__ GqT, float* __restrict__ GcT)
{
  int ch = blockIdx.x, f = blockIdx.y;
  const float* We = WeW + (size_t)ch * EF_ * 128 + f * 128;
  const float* Wq = WqW + (size_t)ch * 16384;
  const float* Wk = WkW + (size_t)ch * 16384;
  const float* Wv = WvW + (size_t)ch * 16384;
  __shared__ float sWe[128], sQ[128], sK[128];
  int d = threadIdx.x;
  sWe[d] = We[d];
  __syncthreads();
  float aq = 0.f, ak = 0.f, av = 0.f;
  for (int k = 0; k < 128; k++) {
    float w = sWe[k];
    aq += w * Wq[k * 128 + d];
    ak += w * Wk[k * 128 + d];
    av += w * Wv[k * 128 + d];
  }
  size_t off = (size_t)ch * EF_ * 128 + f * 128 + d;
  WeQ[off] = aq; WeK[off] = ak; WeV[off] = av;
  sQ[d] = aq; sK[d] = ak;
  __syncthreads();
  float gq = 0.f, gc = 0.f;
  for (int k = 0; k < 128; k++) {
    gq += Wq[(size_t)d * 128 + k] * sK[k];
    gc += Wk[(size_t)d * 128 + k] * sQ[k];
  }
  GqT[off] = gq; GcT[off] = gc;
}

// M2[a][b] = WeQ[a]·WeK[b], LDS-staged. grid 12, block 128.
__global__ __launch_bounds__(128) void k_small2(
    const float* __restrict__ WeQ, const float* __restrict__ WeK,
    float* __restrict__ M2)
{
  int ch = blockIdx.x;
  __shared__ float sQ[EF_ * 128], sK[EF_ * 128];
  int t = threadIdx.x;
  for (int i = t; i < EF_ * 128; i += 128) {
    sQ[i] = WeQ[(size_t)ch * EF_ * 128 + i];
    sK[i] = WeK[(size_t)ch * EF_ * 128 + i];
  }
  __syncthreads();
  if (t < EF_ * EF_) {
    int a = t / EF_, b = t % EF_;
    float s = 0.f;
    for (int k = 0; k < 128; k++) s += sQ[a * 128 + k] * sK[b * 128 + k];
    M2[(size_t)ch * (EF_ * EF_) + t] = s;
  }
}

// ---------------------------------------------------------------------------
// Build UTBt: slot0 = M, slot1 = M^T. grid (12, 2).
// ---------------------------------------------------------------------------
__global__ __launch_bounds__(256) void k_utbt(
    const float* __restrict__ Mbuf, unsigned short* __restrict__ UTBt)
{
  int ch = blockIdx.x, slot = blockIdx.y;
  unsigned short* dst = UTBt + (size_t)ch * 32768 + slot * 16384;
  for (int i = threadIdx.x; i < 16384; i += 256) {
    int r = i >> 7, k = i & 127;
    float v = (slot == 0) ? Mbuf[(size_t)ch * 16384 + i]
                          : Mbuf[(size_t)ch * 16384 + k * 128 + r];
    dst[i] = f2bf(v);
  }
}

// ---------------------------------------------------------------------------
// Fold BC weights: Wbc[j][col*K + k] = sum_d lin(j,h)[k][d] * G[f][d],
// col = h*32 + c2, c2<11 -> GqT(f=c2), c2<22 -> GcT(f=c2-11), else 0.
// grid (C_, 128), block 128 (threads over k).
// ---------------------------------------------------------------------------
__global__ __launch_bounds__(128) void k_bcfold(
    const float* __restrict__ lin0, const float* __restrict__ linW,
    const float* __restrict__ GqT, const float* __restrict__ GcT,
    unsigned short* __restrict__ Wbc)
{
  int j = blockIdx.x, col = blockIdx.y;
  int K = (j == 0) ? INF_ : 128;
  int h = col >> 5, c2 = col & 31;
  __shared__ float sG[128];
  int t = threadIdx.x;
  if (c2 < 2 * EF_) {
    int f = (c2 < EF_) ? c2 : c2 - EF_;
    const float* G = ((c2 < EF_) ? GqT : GcT) +
                     ((size_t)(j * H_ + h) * EF_ + f) * 128;
    sG[t] = G[t];
  }
  __syncthreads();
  if (t < K) {
    float v = 0.f;
    if (c2 < 2 * EF_) {
      const float* lin = (j == 0)
          ? lin0 + (size_t)h * INF_ * 128 + t * 128
          : linW + ((size_t)(j - 1) * H_ + h) * 16384 + t * 128;
      for (int d = 0; d < 128; d++) v += lin[d] * sG[d];
    }
    Wbc[(size_t)j * 16384 + col * K + t] = f2bf(v);
  }
}

// ---------------------------------------------------------------------------
// MFMA bf16 GEMM, A f32 (converted in staging) or bf16. 128x128 tile,
// 4 waves 2x2, mfma_f32_16x16x32_bf16. Out: f32 (+bias) or bf16.
// ---------------------------------------------------------------------------
template <typename AT>
__global__ __launch_bounds__(256) void k_mfma(
    const AT* __restrict__ A, int lda, int aOffZ, int M, int K,
    const unsigned short* __restrict__ Bt, int btOffY, int btOffZ,
    float* __restrict__ outF, int ldc, int cOffY, int cOffZ,
    const float* __restrict__ bias,
    unsigned short* __restrict__ outH, int hStride, int hOffY, int hOffZ)
{
  const int bx = blockIdx.x, by = blockIdx.y, bz = blockIdx.z;
  A += (size_t)bz * aOffZ;
  const unsigned short* Bp = Bt + (size_t)by * btOffY + (size_t)bz * btOffZ;
  const int rowBase = bx * 128;
  __shared__ unsigned short As[128][40];
  __shared__ unsigned short Bs[128][40];
  const int t = threadIdx.x;
  const int w = t >> 6, l = t & 63;
  const int wr = w >> 1, wc = w & 1;
  const int fr = l & 15, fq = l >> 4;
  f32x4 acc[4][4];
#pragma unroll
  for (int m = 0; m < 4; m++)
#pragma unroll
    for (int n = 0; n < 4; n++) acc[m][n] = (f32x4){0.f, 0.f, 0.f, 0.f};

  const int sr = t >> 1, sh = t & 1;
  const int arow = rowBase + sr;
  const AT* aBase = A + (size_t)arow * lda;

  for (int k0 = 0; k0 < K; k0 += 32) {
    int kb = k0 + sh * 16;
    if constexpr (sizeof(AT) == 4) {
      unsigned short tmp[16];
      if (arow < M && kb + 16 <= K) {
        const AT* ap = aBase + kb;
#pragma unroll
        for (int i = 0; i < 16; i++) tmp[i] = f2bf(ap[i]);
      } else {
#pragma unroll
        for (int i = 0; i < 16; i++) {
          int gk = kb + i;
          float v = (arow < M && gk < K) ? (float)aBase[gk] : 0.f;
          tmp[i] = f2bf(v);
        }
      }
      *(uint4*)&As[sr][sh * 16]     = *(const uint4*)&tmp[0];
      *(uint4*)&As[sr][sh * 16 + 8] = *(const uint4*)&tmp[8];
    } else {
      if (arow < M && kb + 16 <= K) {
        const unsigned short* ap = (const unsigned short*)aBase + kb;
        *(uint4*)&As[sr][sh * 16]     = *(const uint4*)(ap);
        *(uint4*)&As[sr][sh * 16 + 8] = *(const uint4*)(ap + 8);
      } else {
#pragma unroll
        for (int i = 0; i < 16; i++) {
          int gk = kb + i;
          As[sr][sh * 16 + i] = (arow < M && gk < K)
              ? ((const unsigned short*)aBase)[gk] : (unsigned short)0;
        }
      }
    }
    if (t < 128) {
      unsigned short tmp[32];
      if (k0 + 32 <= K) {
        const unsigned short* bp = Bp + (size_t)t * K + k0;
#pragma unroll
        for (int i = 0; i < 32; i++) tmp[i] = bp[i];
      } else {
#pragma unroll
        for (int i = 0; i < 32; i++) {
          int gk = k0 + i;
          tmp[i] = (gk < K) ? Bp[(size_t)t * K + gk] : (unsigned short)0;
        }
      }
#pragma unroll
      for (int i = 0; i < 4; i++) *(uint4*)&Bs[t][i * 8] = *(const uint4*)&tmp[i * 8];
    }
    __syncthreads();
    bf16x8 af[4], bfr[4];
#pragma unroll
    for (int m = 0; m < 4; m++) af[m]  = *(const bf16x8*)&As[wr * 64 + m * 16 + fr][fq * 8];
#pragma unroll
    for (int n = 0; n < 4; n++) bfr[n] = *(const bf16x8*)&Bs[wc * 64 + n * 16 + fr][fq * 8];
#pragma unroll
    for (int m = 0; m < 4; m++)
#pragma unroll
      for (int n = 0; n < 4; n++)
        acc[m][n] = __builtin_amdgcn_mfma_f32_16x16x32_bf16(af[m], bfr[n], acc[m][n], 0, 0, 0);
    __syncthreads();
  }
#pragma unroll
  for (int m = 0; m < 4; m++) {
    int row0 = rowBase + wr * 64 + m * 16 + fq * 4;
#pragma unroll
    for (int n = 0; n < 4; n++) {
      int col = wc * 64 + n * 16 + fr;
#pragma unroll
      for (int r = 0; r < 4; r++) {
        int row = row0 + r;
        if (row < M) {
          float v = acc[m][n][r];
          if (outH) {
            outH[(size_t)row * hStride + by * hOffY + bz * hOffZ + col] = f2bf(v);
          } else {
            if (bias) v += bias[col];
            outF[(size_t)row * ldc + by * cOffY + bz * cOffZ + col] = v;
          }
        }
      }
    }
  }
}

// ---------------------------------------------------------------------------
// CSR build (by dst) + permuted metadata
// ---------------------------------------------------------------------------
__global__ void k_hist(const int* __restrict__ dst, int* __restrict__ deg, int E)
{
  int e = blockIdx.x * blockDim.x + threadIdx.x;
  if (e < E) atomicAdd(&deg[dst[e]], 1);
}

__global__ __launch_bounds__(1024) void k_scan(const int* __restrict__ deg,
                                               int* __restrict__ rowp, int N)
{
  __shared__ int part[1024];
  int t = threadIdx.x;
  int chunk = (N + 1023) / 1024;
  int base = t * chunk;
  int s = 0;
  for (int i = 0; i < chunk; i++) { int idx = base + i; if (idx < N) s += deg[idx]; }
  part[t] = s;
  __syncthreads();
  for (int off = 1; off < 1024; off <<= 1) {
    int v = (t >= off) ? part[t - off] : 0;
    __syncthreads();
    part[t] += v;
    __syncthreads();
  }
  int run = part[t] - s;
  for (int i = 0; i < chunk; i++) {
    int idx = base + i;
    if (idx < N) { rowp[idx] = run; run += deg[idx]; }
  }
  if (t == 1023) rowp[N] = part[1023];
}

__global__ void k_fill(const int* __restrict__ src, const int* __restrict__ dst,
                       const int* __restrict__ rowp, int* __restrict__ cursor,
                       int* __restrict__ eids, int* __restrict__ src_perm,
                       int* __restrict__ dst_perm, int E)
{
  int e = blockIdx.x * blockDim.x + threadIdx.x;
  if (e < E) {
    int d = dst[e];
    int pos = atomicAdd(&cursor[d], 1);
    int slot = rowp[d] + pos;
    eids[slot] = e;
    src_perm[slot] = src[e];
    dst_perm[slot] = d;
  }
}

__global__ void k_efperm(const float* __restrict__ e_f, const int* __restrict__ eids,
                         float* __restrict__ ef_perm, int E)
{
  int i = blockIdx.x * blockDim.x + threadIdx.x;
  if (i < E * EF_) {
    int idx = i / EF_, f = i - idx * EF_;
    ef_perm[i] = e_f[(size_t)eids[idx] * EF_ + f];
  }
}

// ---------------------------------------------------------------------------
// Build combined post-message weight WvE.
// ---------------------------------------------------------------------------
__global__ __launch_bounds__(128) void k_wve(
    const float* __restrict__ WvW, const float* __restrict__ WeV,
    unsigned short* __restrict__ WvE)
{
  int ch = blockIdx.x;
  const float* Wv  = WvW + (size_t)ch * 16384;
  const float* wev = WeV + (size_t)ch * EF_ * 128;
  unsigned short* dst = WvE + (size_t)ch * 20480;
  for (int i = threadIdx.x; i < 20480; i += 128) {
    int d = i / 160, k = i - d * 160;
    float v = (k < 128) ? Wv[(size_t)k * 128 + d]
            : (k < 128 + EF_) ? wev[(size_t)(k - 128) * 128 + d] : 0.f;
    dst[i] = f2bf(v);
  }
}

// ---------------------------------------------------------------------------
// Per-node ss = Z.u (UTb bf16: [N][H][2][128] = [u|t]). Wave per (n,h).
// ---------------------------------------------------------------------------
__global__ __launch_bounds__(256) void k_ss(
    const unsigned short* __restrict__ Zb, const unsigned short* __restrict__ UTb,
    float* __restrict__ ss, int N)
{
  int h = threadIdx.x >> 6, lane = threadIdx.x & 63;
  int n = blockIdx.x;
  unsigned uz = *(const unsigned*)(Zb + (size_t)n * 512 + h * 128 + 2 * lane);
  unsigned uu = *(const unsigned*)(UTb + (size_t)n * 1024 + h * 256 + 2 * lane);
  float zx = __uint_as_float(uz << 16), zy = __uint_as_float(uz & 0xffff0000u);
  float ux = __uint_as_float(uu << 16), uy = __uint_as_float(uu & 0xffff0000u);
  float p = zx * ux + zy * uy;
#pragma unroll
  for (int m = 32; m; m >>= 1) p += __shfl_xor(p, m, 64);
  if (lane == 0) ss[n * H_ + h] = p;
}

// ---------------------------------------------------------------------------
// Per-edge precomputed logits: elog[idx][h][6] = {ss_s, se, de, es, ed, ee}
// B/C from BCb bf16 [N][128] (h*32 + f for B, +11 for C).
// ---------------------------------------------------------------------------
__global__ __launch_bounds__(256) void k_elog(
    const unsigned short* __restrict__ BCb, const float* __restrict__ ss,
    const float* __restrict__ M2, const float* __restrict__ ef_perm,
    const int* __restrict__ src_perm, const int* __restrict__ dst_perm,
    float* __restrict__ elog, int E, int layer)
{
  int i0 = blockIdx.x * 64;
  __shared__ float efs[64 * EF_];
  __shared__ float m2s[4 * EF_ * EF_];
  int t = threadIdx.x;
  for (int i = t; i < 64 * EF_; i += 256) {
    int gi = i0 * EF_ + i;
    efs[i] = (gi < E * EF_) ? ef_perm[gi] : 0.f;
  }
  for (int i = t; i < 4 * EF_ * EF_; i += 256)
    m2s[i] = M2[(size_t)layer * 4 * EF_ * EF_ + i];
  __syncthreads();
  int sl = t >> 2, h = t & 3;
  int idx = i0 + sl;
  if (idx < E) {
    int s = src_perm[idx], d = dst_perm[idx];
    const float* ef = &efs[sl * EF_];
    const float* m2 = &m2s[h * EF_ * EF_];
    float ee = 0.f;
#pragma unroll
    for (int a = 0; a < EF_; a++) {
      float r = 0.f;
#pragma unroll
      for (int b = 0; b < EF_; b++) r += m2[a * EF_ + b] * ef[b];
      ee += ef[a] * r;
    }
    const unsigned short* bs = BCb + (size_t)s * 128 + h * 32;
    const unsigned short* bd = BCb + (size_t)d * 128 + h * 32;
    float se = 0.f, es = 0.f, de = 0.f, ed = 0.f;
#pragma unroll
    for (int f = 0; f < EF_; f++) {
      float e = ef[f];
      se += bf2f(bs[f]) * e;
      es += bf2f(bs[EF_ + f]) * e;
      de += bf2f(bd[f]) * e;
      ed += bf2f(bd[EF_ + f]) * e;
    }
    float* o = elog + ((size_t)idx * H_ + h) * 6;
    o[0] = ss[s * H_ + h];
    o[1] = se; o[2] = de; o[3] = es; o[4] = ed; o[5] = ee;
  }
}

// ---------------------------------------------------------------------------
// Edge aggregation: block = dst node, 4 waves = 4 edge slots; each wave
// handles ALL 4 heads of one edge (lane: h=lane>>4, q=lane&15) -> the Zb[s]
// gather is one contiguous 1KB wave load. Cross-wave combine via LDS.
// ---------------------------------------------------------------------------
__global__ __launch_bounds__(256) void k_edge(
    const unsigned short* __restrict__ Zb, const unsigned short* __restrict__ UTb,
    const float* __restrict__ ss, const float* __restrict__ elog,
    const float* __restrict__ ef_perm, const int* __restrict__ rowp,
    const int* __restrict__ src_perm, unsigned short* __restrict__ aggZE, int N)
{
  const int w = threadIdx.x >> 6;      // wave = edge slot
  const int lane = threadIdx.x & 63;
  const int h = lane >> 4;             // head
  const int q = lane & 15;             // d-slice (8 elems)
  const int lb = lane & 48;            // group base = h*16
  const int n = blockIdx.x;

  float zd[8], ud[8], td[8];
  unpack8(*(const uint4*)(Zb + (size_t)n * 512 + lane * 8), zd);
  const unsigned short* utp = UTb + (size_t)n * 1024 + h * 256 + q * 8;
  unpack8(*(const uint4*)(utp), ud);
  unpack8(*(const uint4*)(utp + 128), td);
  const float essd = __expf(ss[n * H_ + h]);
  const int beg = rowp[n], end = rowp[n + 1];
  float acc[8];
#pragma unroll
  for (int i = 0; i < 8; i++) acc[i] = 0.f;
  float wdsum = 0.f, a11 = 0.f;

  for (int idx = beg + w; idx < end; idx += 4) {
    int s = src_perm[idx];
    float zs[8];
    unpack8(*(const uint4*)(Zb + (size_t)s * 512 + lane * 8), zs);
    float v1 = 0.f, v2 = 0.f;
#pragma unroll
    for (int i = 0; i < 8; i++) {
      v1 += zs[i] * ud[i];
      v2 += zs[i] * td[i];
    }
#pragma unroll
    for (int m = 1; m < 16; m <<= 1) {
      v1 += __shfl_xor(v1, m, 64);
      v2 += __shfl_xor(v2, m, 64);
    }
    float lv = (q < 6) ? elog[((size_t)idx * H_ + h) * 6 + q] : 0.f;
    float S00 = __shfl(lv, lb + 0, 64);
    float S02 = __shfl(lv, lb + 1, 64);
    float S12 = __shfl(lv, lb + 2, 64);
    float S20 = __shfl(lv, lb + 3, 64);
    float S21 = __shfl(lv, lb + 4, 64);
    float S22 = __shfl(lv, lb + 5, 64);
    // rows: [s: S00 v1 S02] [d: v2 ss S12] [e: S20 S21 S22]; |S| small.
    float e00 = __expf(S00), e01 = __expf(v1), e02 = __expf(S02);
    float i0r = 1.f / (e00 + e01 + e02);
    float e10 = __expf(v2), e12 = __expf(S12);
    float i1r = 1.f / (e10 + essd + e12);
    float e20 = __expf(S20), e21 = __expf(S21), e22 = __expf(S22);
    float i2r = 1.f / (e20 + e21 + e22);
    float w0 = e00 * i0r + e10 * i1r + e20 * i2r;
    float w1 = e01 * i0r + essd * i1r + e21 * i2r;
    float w2 = e02 * i0r + e12 * i1r + e22 * i2r;
#pragma unroll
    for (int i = 0; i < 8; i++) acc[i] += w0 * zs[i];
    wdsum += w1;
    float efl = (q < EF_) ? ef_perm[(size_t)idx * EF_ + q] : 0.f;
    a11 += w2 * efl;
  }
  // cross-wave combine
  __shared__ float red[4][64][10];
#pragma unroll
  for (int i = 0; i < 8; i++) red[w][lane][i] = acc[i];
  red[w][lane][8] = wdsum;
  red[w][lane][9] = a11;
  __syncthreads();
  if (w == 0) {
    float a[8], wd = 0.f, a1 = 0.f;
#pragma unroll
    for (int i = 0; i < 8; i++)
      a[i] = red[0][lane][i] + red[1][lane][i] + red[2][lane][i] + red[3][lane][i];
    wd = red[0][lane][8] + red[1][lane][8] + red[2][lane][8] + red[3][lane][8];
    a1 = red[0][lane][9] + red[1][lane][9] + red[2][lane][9] + red[3][lane][9];
    int cnt = end - beg;
    float invc = (cnt > 0) ? 1.f / (float)cnt : 1.f;
    unsigned short* ob = aggZE + (size_t)n * 640 + h * 160;
    unsigned short tmp[8];
#pragma unroll
    for (int i = 0; i < 8; i++) tmp[i] = f2bf((a[i] + wd * zd[i]) * invc);
    *(uint4*)(ob + q * 8) = *(const uint4*)&tmp[0];
    ob[128 + q] = (q < EF_) ? f2bf(a1 * invc) : (unsigned short)0;
    ob[144 + q] = 0;
  }
}

// ---------------------------------------------------------------------------
// Fused ReLU + LayerNorm per (node, head), in place on zh[N,512].
// ---------------------------------------------------------------------------
__global__ __launch_bounds__(256) void k_ln(
    float* __restrict__ zh, const float* __restrict__ lng,
    const float* __restrict__ lnb, int N, int layer)
{
  int h = threadIdx.x >> 6, lane = threadIdx.x & 63;
  int n = blockIdx.x;
  float* p = zh + (size_t)n * 512 + h * 128 + 2 * lane;
  float2 v = *(const float2*)p;
  v.x = fmaxf(v.x, 0.f); v.y = fmaxf(v.y, 0.f);
  float s1 = v.x + v.y;
#pragma unroll
  for (int m = 32; m; m >>= 1) s1 += __shfl_xor(s1, m, 64);
  float mean = s1 * (1.f / 128.f);
  float dx = v.x - mean, dy = v.y - mean;
  float s2 = dx * dx + dy * dy;
#pragma unroll
  for (int m = 32; m; m >>= 1) s2 += __shfl_xor(s2, m, 64);
  float rstd = rsqrtf(s2 * (1.f / 128.f) + 1e-5f);
  int gi = (layer * H_ + h) * 128 + 2 * lane;
  float2 g2 = *(const float2*)&lng[gi];
  float2 b2 = *(const float2*)&lnb[gi];
  float2 o;
  o.x = dx * rstd * g2.x + b2.x;
  o.y = dy * rstd * g2.y + b2.y;
  *(float2*)p = o;
}

// ---------------------------------------------------------------------------
// Segment mean, node-range split 4-way per graph (pre-zeroed output).
// ---------------------------------------------------------------------------
__global__ void k_gmean(const float* __restrict__ X, const int* __restrict__ gid,
                        float* __restrict__ outp, int N, int ld)
{
  int g = blockIdx.x, part = blockIdx.y;
  int lo = 0, hi = N;
  while (lo < hi) { int m = (lo + hi) >> 1; if (gid[m] < g) lo = m + 1; else hi = m; }
  int s0 = lo;
  lo = s0; hi = N;
  while (lo < hi) { int m = (lo + hi) >> 1; if (gid[m] < g + 1) lo = m + 1; else hi = m; }
  int s1 = lo;
  int cnt = s1 - s0;
  float inv = 1.f / (float)(cnt > 0 ? cnt : 1);
  int r0 = s0 + (cnt * part) / 4;
  int r1 = s0 + (cnt * (part + 1)) / 4;
  if (r1 <= r0) return;
  for (int d = threadIdx.x; d < ld; d += blockDim.x) {
    float s = 0.f;
    for (int n = r0; n < r1; n++) s += X[(size_t)n * ld + d];
    atomicAdd(&outp[(size_t)g * ld + d], s * inv);
  }
}

// ---------------------------------------------------------------------------
// GRU recurrent-only pass (input gates precomputed by MFMA).
// ---------------------------------------------------------------------------
__global__ __launch_bounds__(384) void k_gruR(
    const float* __restrict__ gi, const float* __restrict__ Whh,
    const float* __restrict__ bih, const float* __restrict__ bhh,
    float* __restrict__ yout, float* __restrict__ hfinal)
{
  const int g = blockIdx.x, dir = blockIdx.y, t = threadIdx.x;
  const float* W = Whh + (size_t)dir * 128 * 384 + t;
  const float bi = bih[dir * 384 + t];
  const float bh = bhh[dir * 384 + t];
  __shared__ float hb[128];
  __shared__ float rb[128], zb[128], nb[128];
  if (t < 128) hb[t] = 0.f;
  __syncthreads();
  for (int st = 0; st < T_; st++) {
    int ts = dir ? (T_ - 1 - st) : st;
    float acc = bh;
    for (int k = 0; k < 128; k++) acc += hb[k] * W[(size_t)k * 384];
    float gv = gi[((size_t)ts * G_ + g) * 768 + dir * 384 + t] + bi;
    if (t < 128) {
      rb[t] = 1.f / (1.f + __expf(-(gv + acc)));
    } else if (t < 256) {
      zb[t - 128] = 1.f / (1.f + __expf(-(gv + acc)));
    }
    __syncthreads();
    if (t >= 256) nb[t - 256] = tanhf(gv + rb[t - 256] * acc);
    __syncthreads();
    if (t < 128) {
      float z = zb[t];
      float h = (1.f - z) * nb[t] + z * hb[t];
      hb[t] = h;
      if (yout) yout[((size_t)ts * G_ + g) * 256 + dir * 128 + t] = h;
    }
    __syncthreads();
  }
  if (t < 128) hfinal[((size_t)dir * G_ + g) * 128 + t] = hb[t];
}

__global__ void k_final(const float* __restrict__ fp, float* __restrict__ outp, int n)
{
  int i = blockIdx.x * blockDim.x + threadIdx.x;
  if (i < n) {
    outp[i] = fp[i] + fp[G_ * 128 + i] + fp[2 * G_ * 128 + i] + fp[3 * G_ * 128 + i];
  }
}

// ---------------------------------------------------------------------------
extern "C" void kernel_launch(void* const* d_in, const int* in_sizes, int n_in,
                              void* d_out, int out_size, void* d_ws, size_t ws_size,
                              hipStream_t stream)
{
  (void)n_in; (void)ws_size;
  const float* h0   = (const float*)d_in[0];
  const float* e_f  = (const float*)d_in[1];
  const int*   srcI = (const int*)d_in[2];
  const int*   dstI = (const int*)d_in[3];
  const int*   gid  = (const int*)d_in[4];
  const float* lin0 = (const float*)d_in[6];
  const float* linW = (const float*)d_in[7];
  const float* WeW  = (const float*)d_in[8];
  const float* WqW  = (const float*)d_in[9];
  const float* WkW  = (const float*)d_in[10];
  const float* WvW  = (const float*)d_in[11];
  const float* lng  = (const float*)d_in[12];
  const float* lnb  = (const float*)d_in[13];
  const float* outW = (const float*)d_in[14];
  const float* outb = (const float*)d_in[15];
  const float* projW= (const float*)d_in[16];
  const float* projb= (const float*)d_in[17];
  const float* Wih0 = (const float*)d_in[18];
  const float* Whh0 = (const float*)d_in[19];
  const float* bih0 = (const float*)d_in[20];
  const float* bhh0 = (const float*)d_in[21];
  const float* Wih1 = (const float*)d_in[22];
  const float* Whh1 = (const float*)d_in[23];
  const float* bih1 = (const float*)d_in[24];
  const float* bhh1 = (const float*)d_in[25];
  float* outp = (float*)d_out;

  const int N = in_sizes[0] / INF_;
  const int E = in_sizes[2];

  // Workspace ledger (N=20000, E=160000): ~184 MB — keep under 256 MiB.
  char* wp = (char*)d_ws;
  auto alloc = [&](size_t bytes) -> void* {
    void* p = (void*)wp;
    wp += (bytes + 255) & ~(size_t)255;
    return p;
  };
  unsigned short* Zb  = (unsigned short*)alloc((size_t)N * 512 * 2);   // 20.5 MB
  unsigned short* UTb = (unsigned short*)alloc((size_t)N * 1024 * 2);  // 41.0 MB
  unsigned short* BCb = (unsigned short*)alloc((size_t)N * 128 * 2);   //  5.1 MB
  unsigned short* aggZE = (unsigned short*)alloc((size_t)N * 640 * 2); // 25.6 MB
  float* zh   = (float*)alloc((size_t)N * 512 * 4);                    // 41.0 MB
  float* hcur = (float*)alloc((size_t)N * 128 * 4);                    // 10.2 MB
  float* ssb  = (float*)alloc((size_t)N * H_ * 4);
  float* elog = (float*)alloc((size_t)E * H_ * 6 * 4);                 // 15.4 MB
  float* efp  = (float*)alloc((size_t)E * EF_ * 4);                    //  7.0 MB
  float* WeQ  = (float*)alloc((size_t)C_ * H_ * EF_ * 128 * 4);
  float* WeK  = (float*)alloc((size_t)C_ * H_ * EF_ * 128 * 4);
  float* WeV  = (float*)alloc((size_t)C_ * H_ * EF_ * 128 * 4);
  float* M2   = (float*)alloc((size_t)C_ * H_ * EF_ * EF_ * 4);
  float* GqT  = (float*)alloc((size_t)C_ * H_ * EF_ * 128 * 4);
  float* GcT  = (float*)alloc((size_t)C_ * H_ * EF_ * 128 * 4);
  float* Mbuf = (float*)alloc((size_t)C_ * H_ * 16384 * 4);
  unsigned short* WkPl  = (unsigned short*)alloc((size_t)C_ * H_ * 16384 * 2);
  unsigned short* UTBt  = (unsigned short*)alloc((size_t)C_ * H_ * 2 * 16384 * 2);
  unsigned short* WbcBt = (unsigned short*)alloc((size_t)C_ * 16384 * 2);
  unsigned short* WvE   = (unsigned short*)alloc((size_t)C_ * H_ * 20480 * 2);
  unsigned short* linBt0 = (unsigned short*)alloc((size_t)4 * 128 * INF_ * 2);
  unsigned short* linBt12= (unsigned short*)alloc((size_t)2 * 512 * 128 * 2);
  unsigned short* outBt  = (unsigned short*)alloc((size_t)C_ * 128 * 512 * 2);
  unsigned short* projBt = (unsigned short*)alloc((size_t)128 * INF_ * 2);
  unsigned short* WihBt0 = (unsigned short*)alloc((size_t)768 * 128 * 2);
  unsigned short* WihBt1 = (unsigned short*)alloc((size_t)768 * 256 * 2);
  float* gibuf = (float*)alloc((size_t)T_ * G_ * 768 * 4);             //  6.3 MB
  int* deg    = (int*)alloc((size_t)N * 4);
  int* cursor = (int*)alloc((size_t)N * 4);
  int* rowp   = (int*)alloc((size_t)(N + 1) * 4);
  int* eids   = (int*)alloc((size_t)E * 4);
  int* srcp   = (int*)alloc((size_t)E * 4);
  int* dstp   = (int*)alloc((size_t)E * 4);
  float* gm74 = (float*)alloc((size_t)G_ * INF_ * 4);
  float* seq  = (float*)alloc((size_t)T_ * G_ * 128 * 4);
  float* seq1 = (float*)alloc((size_t)T_ * G_ * 256 * 4);
  float* fparts=(float*)alloc((size_t)4 * G_ * 128 * 4);

  const int gM = (N + 127) / 128;

  // --- CSR build + permuted metadata ---
  hipMemsetAsync(deg, 0, (size_t)N * 4, stream);
  hipMemsetAsync(cursor, 0, (size_t)N * 4, stream);
  hipMemsetAsync(gm74, 0, (size_t)G_ * INF_ * 4, stream);
  hipMemsetAsync(seq, 0, (size_t)T_ * G_ * 128 * 4, stream);
  k_hist<<<(E + 255) / 256, 256, 0, stream>>>(dstI, deg, E);
  k_scan<<<1, 1024, 0, stream>>>(deg, rowp, N);
  k_fill<<<(E + 255) / 256, 256, 0, stream>>>(srcI, dstI, rowp, cursor,
                                              eids, srcp, dstp, E);
  k_efperm<<<(E * EF_ + 255) / 256, 256, 0, stream>>>(e_f, eids, efp, E);

  // --- small weight folding (f-parallel) ---
  k_small1<<<dim3(C_ * H_, EF_), 128, 0, stream>>>(WeW, WqW, WkW, WvW,
                                                   WeQ, WeK, WeV, GqT, GcT);
  k_small2<<<C_ * H_, 128, 0, stream>>>(WeQ, WeK, M2);
  k_wve<<<C_ * H_, 128, 0, stream>>>(WvW, WeV, WvE);
  k_bcfold<<<dim3(C_, 128), 128, 0, stream>>>(lin0, linW, GqT, GcT, WbcBt);

  // --- weight conversions pass 1 ---
  {
    WPack w{};
    int nw = 0;
    auto addw = [&](const float* s, unsigned short* d, int K, int D, int tr) {
      w.d[nw].src = s; w.d[nw].dst = d; w.d[nw].K = K; w.d[nw].D = D;
      w.d[nw].trans = tr; nw++;
    };
    for (int h = 0; h < 4; h++)
      addw(lin0 + (size_t)h * INF_ * 128, linBt0 + (size_t)h * 128 * INF_, INF_, 128, 1);
    for (int j = 1; j < 3; j++)
      for (int h = 0; h < 4; h++)
        addw(linW + ((size_t)(j - 1) * 4 + h) * 16384,
             linBt12 + (size_t)(j - 1) * 65536 + (size_t)h * 16384, 128, 128, 1);
    for (int j = 0; j < 3; j++)
      addw(outW + (size_t)j * 65536, outBt + (size_t)j * 65536, 512, 128, 1);
    addw(projW, projBt, INF_, 128, 1);
    for (int ch = 0; ch < 12; ch++)
      addw(WkW + (size_t)ch * 16384, WkPl + (size_t)ch * 16384, 128, 128, 0);
    for (int dir = 0; dir < 2; dir++) {
      addw(Wih0 + (size_t)dir * 128 * 384, WihBt0 + (size_t)dir * 384 * 128,
           128, 384, 1);
      addw(Wih1 + (size_t)dir * 256 * 384, WihBt1 + (size_t)dir * 384 * 256,
           256, 384, 1);
    }
    k_wcvt<<<dim3(64, nw), 256, 0, stream>>>(w);
  }

  // --- M = Wq @ Wk^T per (layer,head), f32 out ---
  k_mfma<float><<<dim3(1, 1, 12), 256, 0, stream>>>(
      WqW, 128, 16384, 128, 128, WkPl, 0, 16384,
      Mbuf, 128, 0, 16384, nullptr, nullptr, 0, 0, 0);

  // --- UTBt = [M | M^T] bf16 ---
  k_utbt<<<dim3(12, 2), 256, 0, stream>>>(Mbuf, UTBt);

  // --- GRU input t=0: seg-mean(h0) then proj ---
  k_gmean<<<dim3(G_, 4), 128, 0, stream>>>(h0, gid, gm74, N, INF_);
  k_mfma<float><<<dim3(4, 1, 1), 256, 0, stream>>>(
      gm74, INF_, 0, G_, INF_, projBt, 0, 0,
      seq, 128, 0, 0, projb, nullptr, 0, 0, 0);

  // --- conv layers ---
  for (int j = 0; j < C_; j++) {
    const float* Ain = (j == 0) ? h0 : hcur;
    const int Kin = (j == 0) ? INF_ : 128;
    // lin -> Zb bf16 [N][H][128]
    if (j == 0)
      k_mfma<float><<<dim3(gM, 4, 1), 256, 0, stream>>>(
          h0, INF_, 0, N, INF_, linBt0, 128 * INF_, 0,
          nullptr, 0, 0, 0, nullptr, Zb, 512, 128, 0);
    else
      k_mfma<float><<<dim3(gM, 4, 1), 256, 0, stream>>>(
          hcur, 128, 0, N, 128, linBt12 + (size_t)(j - 1) * 65536, 16384, 0,
          nullptr, 0, 0, 0, nullptr, Zb, 512, 128, 0);
    // BCb = Ain @ WbcBt_j -> [N][128] bf16 (packed B/C per head)
    k_mfma<float><<<dim3(gM, 1, 1), 256, 0, stream>>>(
        Ain, Kin, 0, N, Kin, WbcBt + (size_t)j * 16384, 0, 0,
        nullptr, 0, 0, 0, nullptr, BCb, 128, 0, 0);
    // u,t = [M|M^T] Z -> UTb bf16 [N][H][2][128]
    k_mfma<unsigned short><<<dim3(gM, 2, 4), 256, 0, stream>>>(
        Zb, 512, 128, N, 128, UTBt + (size_t)j * 4 * 32768, 16384, 32768,
        nullptr, 0, 0, 0, nullptr, UTb, 1024, 128, 256);
    k_ss<<<N, 256, 0, stream>>>(Zb, UTb, ssb, N);
    k_elog<<<(E + 63) / 64, 256, 0, stream>>>(BCb, ssb, M2, efp, srcp, dstp,
                                              elog, E, j);
    k_edge<<<N, 256, 0, stream>>>(Zb, UTb, ssb, elog, efp, rowp, srcp, aggZE, N);
    // messages: zh[N][h*128+d] = aggZE @ [Wv;WeV]
    k_mfma<unsigned short><<<dim3(gM, 1, 4), 256, 0, stream>>>(
        aggZE, 640, 160, N, 160, WvE + (size_t)j * 4 * 20480, 0, 20480,
        zh, 512, 0, 128, nullptr, nullptr, 0, 0, 0);
    k_ln<<<N, 256, 0, stream>>>(zh, lng, lnb, N, j);
    // out GEMM
    k_mfma<float><<<dim3(gM, 1, 1), 256, 0, stream>>>(
        zh, 512, 0, N, 512, outBt + (size_t)j * 65536, 0, 0,
        hcur, 128, 0, 0, outb + j * 128, nullptr, 0, 0, 0);
    k_gmean<<<dim3(G_, 4), 128, 0, stream>>>(hcur, gid,
                                             seq + (size_t)(j + 1) * G_ * 128, N, 128);
  }

  // --- GRU readout: input gates via MFMA, recurrent via k_gruR ---
  k_mfma<float><<<dim3(16, 6, 1), 256, 0, stream>>>(
      seq, 128, 0, T_ * G_, 128, WihBt0, 128 * 128, 0,
      gibuf, 768, 128, 0, nullptr, nullptr, 0, 0, 0);
  k_gruR<<<dim3(G_, 2), 384, 0, stream>>>(gibuf, Whh0, bih0, bhh0,
                                          seq1, fparts);
  k_mfma<float><<<dim3(16, 6, 1), 256, 0, stream>>>(
      seq1, 256, 0, T_ * G_, 256, WihBt1, 128 * 256, 0,
      gibuf, 768, 128, 0, nullptr, nullptr, 0, 0, 0);
  k_gruR<<<dim3(G_, 2), 384, 0, stream>>>(gibuf, Whh1, bih1, bhh1,
                                          nullptr, fparts + 2 * G_ * 128);
  k_final<<<(out_size + 255) / 256, 256, 0, stream>>>(fparts, outp, out_size);
}

// Round 11
// 1150.048 us; speedup vs baseline: 2.9404x; 1.0159x over previous
//
#include <hip/hip_runtime.h>
#include <cstdint>

#define D_   128
#define H_   4
#define C_   3
#define G_   512
#define INF_ 74
#define EF_  11
#define T_   4
#define NW_  48

typedef __attribute__((ext_vector_type(8))) short bf16x8;
typedef __attribute__((ext_vector_type(4))) float f32x4;

__device__ inline unsigned short f2bf(float x) {
  unsigned u = __float_as_uint(x);
  unsigned r = u + 0x7fffu + ((u >> 16) & 1u);
  return (unsigned short)(r >> 16);
}
__device__ inline float bf2f(unsigned short x) {
  return __uint_as_float(((unsigned)x) << 16);
}
__device__ inline void unpack8(uint4 u, float* f) {
  f[0] = __uint_as_float(u.x << 16); f[1] = __uint_as_float(u.x & 0xffff0000u);
  f[2] = __uint_as_float(u.y << 16); f[3] = __uint_as_float(u.y & 0xffff0000u);
  f[4] = __uint_as_float(u.z << 16); f[5] = __uint_as_float(u.z & 0xffff0000u);
  f[6] = __uint_as_float(u.w << 16); f[7] = __uint_as_float(u.w & 0xffff0000u);
}
// Bijective XCD-aware block remap (m204): each XCD gets a contiguous chunk.
__device__ inline int xcd_swz(int bid, int nwg) {
  int q = nwg >> 3, r = nwg & 7;
  int xcd = bid & 7, off = bid >> 3;
  int base = (xcd < r) ? xcd * (q + 1) : r * (q + 1) + (xcd - r) * q;
  return base + off;
}

// ---------------------------------------------------------------------------
// Weight convert: trans ? dst[d*K+k]=bf16(src[k*D+d]) : dst[i]=bf16(src[i])
// ---------------------------------------------------------------------------
struct WDesc { const float* src; unsigned short* dst; int K; int D; int trans; };
struct WPack { WDesc d[NW_]; };

__global__ __launch_bounds__(256) void k_wcvt(WPack wp)
{
  WDesc w = wp.d[blockIdx.y];
  int tot = w.K * w.D;
  for (int i = blockIdx.x * 256 + threadIdx.x; i < tot; i += gridDim.x * 256) {
    if (w.trans) {
      int d = i / w.K, k = i - d * w.K;
      w.dst[i] = f2bf(w.src[(size_t)k * w.D + d]);
    } else {
      w.dst[i] = f2bf(w.src[i]);
    }
  }
}

// ---------------------------------------------------------------------------
// Small weight folding, f-parallel: grid (12, EF_), block 128.
// ---------------------------------------------------------------------------
__global__ __launch_bounds__(128) void k_small1(
    const float* __restrict__ WeW, const float* __restrict__ WqW,
    const float* __restrict__ WkW, const float* __restrict__ WvW,
    float* __restrict__ WeQ, float* __restrict__ WeK, float* __restrict__ WeV,
    float* __restrict__ GqT, float* __restrict__ GcT)
{
  int ch = blockIdx.x, f = blockIdx.y;
  const float* We = WeW + (size_t)ch * EF_ * 128 + f * 128;
  const float* Wq = WqW + (size_t)ch * 16384;
  const float* Wk = WkW + (size_t)ch * 16384;
  const float* Wv = WvW + (size_t)ch * 16384;
  __shared__ float sWe[128], sQ[128], sK[128];
  int d = threadIdx.x;
  sWe[d] = We[d];
  __syncthreads();
  float aq = 0.f, ak = 0.f, av = 0.f;
  for (int k = 0; k < 128; k++) {
    float w = sWe[k];
    aq += w * Wq[k * 128 + d];
    ak += w * Wk[k * 128 + d];
    av += w * Wv[k * 128 + d];
  }
  size_t off = (size_t)ch * EF_ * 128 + f * 128 + d;
  WeQ[off] = aq; WeK[off] = ak; WeV[off] = av;
  sQ[d] = aq; sK[d] = ak;
  __syncthreads();
  float gq = 0.f, gc = 0.f;
  for (int k = 0; k < 128; k++) {
    gq += Wq[(size_t)d * 128 + k] * sK[k];
    gc += Wk[(size_t)d * 128 + k] * sQ[k];
  }
  GqT[off] = gq; GcT[off] = gc;
}

// M2[a][b] = WeQ[a]·WeK[b], LDS-staged. grid 12, block 128.
__global__ __launch_bounds__(128) void k_small2(
    const float* __restrict__ WeQ, const float* __restrict__ WeK,
    float* __restrict__ M2)
{
  int ch = blockIdx.x;
  __shared__ float sQ[EF_ * 128], sK[EF_ * 128];
  int t = threadIdx.x;
  for (int i = t; i < EF_ * 128; i += 128) {
    sQ[i] = WeQ[(size_t)ch * EF_ * 128 + i];
    sK[i] = WeK[(size_t)ch * EF_ * 128 + i];
  }
  __syncthreads();
  if (t < EF_ * EF_) {
    int a = t / EF_, b = t % EF_;
    float s = 0.f;
    for (int k = 0; k < 128; k++) s += sQ[a * 128 + k] * sK[b * 128 + k];
    M2[(size_t)ch * (EF_ * EF_) + t] = s;
  }
}

// ---------------------------------------------------------------------------
// Build UTBt: slot0 = M, slot1 = M^T. grid (12, 2).
// ---------------------------------------------------------------------------
__global__ __launch_bounds__(256) void k_utbt(
    const float* __restrict__ Mbuf, unsigned short* __restrict__ UTBt)
{
  int ch = blockIdx.x, slot = blockIdx.y;
  unsigned short* dst = UTBt + (size_t)ch * 32768 + slot * 16384;
  for (int i = threadIdx.x; i < 16384; i += 256) {
    int r = i >> 7, k = i & 127;
    float v = (slot == 0) ? Mbuf[(size_t)ch * 16384 + i]
                          : Mbuf[(size_t)ch * 16384 + k * 128 + r];
    dst[i] = f2bf(v);
  }
}

// ---------------------------------------------------------------------------
// Fold BC weights: Wbc[j][col*K + k] = sum_d lin(j,h)[k][d] * G[f][d].
// ---------------------------------------------------------------------------
__global__ __launch_bounds__(128) void k_bcfold(
    const float* __restrict__ lin0, const float* __restrict__ linW,
    const float* __restrict__ GqT, const float* __restrict__ GcT,
    unsigned short* __restrict__ Wbc)
{
  int j = blockIdx.x, col = blockIdx.y;
  int K = (j == 0) ? INF_ : 128;
  int h = col >> 5, c2 = col & 31;
  __shared__ float sG[128];
  int t = threadIdx.x;
  if (c2 < 2 * EF_) {
    int f = (c2 < EF_) ? c2 : c2 - EF_;
    const float* G = ((c2 < EF_) ? GqT : GcT) +
                     ((size_t)(j * H_ + h) * EF_ + f) * 128;
    sG[t] = G[t];
  }
  __syncthreads();
  if (t < K) {
    float v = 0.f;
    if (c2 < 2 * EF_) {
      const float* lin = (j == 0)
          ? lin0 + (size_t)h * INF_ * 128 + t * 128
          : linW + ((size_t)(j - 1) * H_ + h) * 16384 + t * 128;
      for (int d = 0; d < 128; d++) v += lin[d] * sG[d];
    }
    Wbc[(size_t)j * 16384 + col * K + t] = f2bf(v);
  }
}

// ---------------------------------------------------------------------------
// MFMA bf16 GEMM, A f32 (converted in staging) or bf16. 128x128 tile,
// 4 waves 2x2, mfma_f32_16x16x32_bf16. Out: f32 (+bias) or bf16.
// ---------------------------------------------------------------------------
template <typename AT>
__global__ __launch_bounds__(256) void k_mfma(
    const AT* __restrict__ A, int lda, int aOffZ, int M, int K,
    const unsigned short* __restrict__ Bt, int btOffY, int btOffZ,
    float* __restrict__ outF, int ldc, int cOffY, int cOffZ,
    const float* __restrict__ bias,
    unsigned short* __restrict__ outH, int hStride, int hOffY, int hOffZ)
{
  const int bx = blockIdx.x, by = blockIdx.y, bz = blockIdx.z;
  A += (size_t)bz * aOffZ;
  const unsigned short* Bp = Bt + (size_t)by * btOffY + (size_t)bz * btOffZ;
  const int rowBase = bx * 128;
  __shared__ unsigned short As[128][40];
  __shared__ unsigned short Bs[128][40];
  const int t = threadIdx.x;
  const int w = t >> 6, l = t & 63;
  const int wr = w >> 1, wc = w & 1;
  const int fr = l & 15, fq = l >> 4;
  f32x4 acc[4][4];
#pragma unroll
  for (int m = 0; m < 4; m++)
#pragma unroll
    for (int n = 0; n < 4; n++) acc[m][n] = (f32x4){0.f, 0.f, 0.f, 0.f};

  const int sr = t >> 1, sh = t & 1;
  const int arow = rowBase + sr;
  const AT* aBase = A + (size_t)arow * lda;

  for (int k0 = 0; k0 < K; k0 += 32) {
    int kb = k0 + sh * 16;
    if constexpr (sizeof(AT) == 4) {
      unsigned short tmp[16];
      if (arow < M && kb + 16 <= K) {
        const AT* ap = aBase + kb;
#pragma unroll
        for (int i = 0; i < 16; i++) tmp[i] = f2bf(ap[i]);
      } else {
#pragma unroll
        for (int i = 0; i < 16; i++) {
          int gk = kb + i;
          float v = (arow < M && gk < K) ? (float)aBase[gk] : 0.f;
          tmp[i] = f2bf(v);
        }
      }
      *(uint4*)&As[sr][sh * 16]     = *(const uint4*)&tmp[0];
      *(uint4*)&As[sr][sh * 16 + 8] = *(const uint4*)&tmp[8];
    } else {
      if (arow < M && kb + 16 <= K) {
        const unsigned short* ap = (const unsigned short*)aBase + kb;
        *(uint4*)&As[sr][sh * 16]     = *(const uint4*)(ap);
        *(uint4*)&As[sr][sh * 16 + 8] = *(const uint4*)(ap + 8);
      } else {
#pragma unroll
        for (int i = 0; i < 16; i++) {
          int gk = kb + i;
          As[sr][sh * 16 + i] = (arow < M && gk < K)
              ? ((const unsigned short*)aBase)[gk] : (unsigned short)0;
        }
      }
    }
    if (t < 128) {
      unsigned short tmp[32];
      if (k0 + 32 <= K) {
        const unsigned short* bp = Bp + (size_t)t * K + k0;
#pragma unroll
        for (int i = 0; i < 32; i++) tmp[i] = bp[i];
      } else {
#pragma unroll
        for (int i = 0; i < 32; i++) {
          int gk = k0 + i;
          tmp[i] = (gk < K) ? Bp[(size_t)t * K + gk] : (unsigned short)0;
        }
      }
#pragma unroll
      for (int i = 0; i < 4; i++) *(uint4*)&Bs[t][i * 8] = *(const uint4*)&tmp[i * 8];
    }
    __syncthreads();
    bf16x8 af[4], bfr[4];
#pragma unroll
    for (int m = 0; m < 4; m++) af[m]  = *(const bf16x8*)&As[wr * 64 + m * 16 + fr][fq * 8];
#pragma unroll
    for (int n = 0; n < 4; n++) bfr[n] = *(const bf16x8*)&Bs[wc * 64 + n * 16 + fr][fq * 8];
#pragma unroll
    for (int m = 0; m < 4; m++)
#pragma unroll
      for (int n = 0; n < 4; n++)
        acc[m][n] = __builtin_amdgcn_mfma_f32_16x16x32_bf16(af[m], bfr[n], acc[m][n], 0, 0, 0);
    __syncthreads();
  }
#pragma unroll
  for (int m = 0; m < 4; m++) {
    int row0 = rowBase + wr * 64 + m * 16 + fq * 4;
#pragma unroll
    for (int n = 0; n < 4; n++) {
      int col = wc * 64 + n * 16 + fr;
#pragma unroll
      for (int r = 0; r < 4; r++) {
        int row = row0 + r;
        if (row < M) {
          float v = acc[m][n][r];
          if (outH) {
            outH[(size_t)row * hStride + by * hOffY + bz * hOffZ + col] = f2bf(v);
          } else {
            if (bias) v += bias[col];
            outF[(size_t)row * ldc + by * cOffY + bz * cOffZ + col] = v;
          }
        }
      }
    }
  }
}

// ---------------------------------------------------------------------------
// msg GEMM + fused ReLU+LayerNorm epilogue -> zh bf16 [N][512].
// A = aggZE bf16 [n][head*160], Bt = WvE[head], grid (gM, H_).
// ---------------------------------------------------------------------------
__global__ __launch_bounds__(256) void k_mfmaLN(
    const unsigned short* __restrict__ A, int M,
    const unsigned short* __restrict__ Bt,
    const float* __restrict__ lng, const float* __restrict__ lnb, int layer,
    unsigned short* __restrict__ zh)
{
  const int bx = blockIdx.x, h = blockIdx.y;
  const int K = 160;
  A += (size_t)h * 160;
  const unsigned short* Bp = Bt + (size_t)h * 20480;
  const int rowBase = bx * 128;
  __shared__ unsigned short As[128][40];
  __shared__ unsigned short Bs[128][40];
  __shared__ float rsum[128][2][2];   // [row][wave-col-half][sum, sumsq]
  const int t = threadIdx.x;
  const int w = t >> 6, l = t & 63;
  const int wr = w >> 1, wc = w & 1;
  const int fr = l & 15, fq = l >> 4;
  f32x4 acc[4][4];
#pragma unroll
  for (int m = 0; m < 4; m++)
#pragma unroll
    for (int n = 0; n < 4; n++) acc[m][n] = (f32x4){0.f, 0.f, 0.f, 0.f};

  const int sr = t >> 1, sh = t & 1;
  const int arow = rowBase + sr;
  const unsigned short* aBase = A + (size_t)arow * 640;

  for (int k0 = 0; k0 < K; k0 += 32) {
    int kb = k0 + sh * 16;
    if (arow < M) {
      *(uint4*)&As[sr][sh * 16]     = *(const uint4*)(aBase + kb);
      *(uint4*)&As[sr][sh * 16 + 8] = *(const uint4*)(aBase + kb + 8);
    } else {
#pragma unroll
      for (int i = 0; i < 16; i++) As[sr][sh * 16 + i] = 0;
    }
    if (t < 128) {
      const unsigned short* bp = Bp + (size_t)t * K + k0;
#pragma unroll
      for (int i = 0; i < 4; i++) *(uint4*)&Bs[t][i * 8] = *(const uint4*)(bp + i * 8);
    }
    __syncthreads();
    bf16x8 af[4], bfr[4];
#pragma unroll
    for (int m = 0; m < 4; m++) af[m]  = *(const bf16x8*)&As[wr * 64 + m * 16 + fr][fq * 8];
#pragma unroll
    for (int n = 0; n < 4; n++) bfr[n] = *(const bf16x8*)&Bs[wc * 64 + n * 16 + fr][fq * 8];
#pragma unroll
    for (int m = 0; m < 4; m++)
#pragma unroll
      for (int n = 0; n < 4; n++)
        acc[m][n] = __builtin_amdgcn_mfma_f32_16x16x32_bf16(af[m], bfr[n], acc[m][n], 0, 0, 0);
    __syncthreads();
  }
  // ReLU in place; per-row partial sums over this wave's 64-col half.
#pragma unroll
  for (int m = 0; m < 4; m++)
#pragma unroll
    for (int n = 0; n < 4; n++)
#pragma unroll
      for (int r = 0; r < 4; r++)
        acc[m][n][r] = fmaxf(acc[m][n][r], 0.f);
#pragma unroll
  for (int m = 0; m < 4; m++) {
#pragma unroll
    for (int r = 0; r < 4; r++) {
      float s1 = 0.f, s2 = 0.f;
#pragma unroll
      for (int n = 0; n < 4; n++) {
        float v = acc[m][n][r];
        s1 += v; s2 += v * v;
      }
#pragma unroll
      for (int msk = 1; msk < 16; msk <<= 1) {
        s1 += __shfl_xor(s1, msk, 64);
        s2 += __shfl_xor(s2, msk, 64);
      }
      if (fr == 0) {
        int lr = wr * 64 + m * 16 + fq * 4 + r;
        rsum[lr][wc][0] = s1;
        rsum[lr][wc][1] = s2;
      }
    }
  }
  __syncthreads();
  // normalize + write bf16
#pragma unroll
  for (int n = 0; n < 4; n++) {
    int col = wc * 64 + n * 16 + fr;
    int gci = (layer * H_ + h) * 128 + col;
    float g = lng[gci], b = lnb[gci];
#pragma unroll
    for (int m = 0; m < 4; m++) {
#pragma unroll
      for (int r = 0; r < 4; r++) {
        int lr = wr * 64 + m * 16 + fq * 4 + r;
        int row = rowBase + lr;
        if (row < M) {
          float s1 = rsum[lr][0][0] + rsum[lr][1][0];
          float s2 = rsum[lr][0][1] + rsum[lr][1][1];
          float mean = s1 * (1.f / 128.f);
          float var = s2 * (1.f / 128.f) - mean * mean;
          float rstd = rsqrtf(var + 1e-5f);
          float v = (acc[m][n][r] - mean) * rstd * g + b;
          zh[(size_t)row * 512 + h * 128 + col] = f2bf(v);
        }
      }
    }
  }
}

// ---------------------------------------------------------------------------
// CSR build (by dst) + permuted metadata
// ---------------------------------------------------------------------------
__global__ void k_hist(const int* __restrict__ dst, int* __restrict__ deg, int E)
{
  int e = blockIdx.x * blockDim.x + threadIdx.x;
  if (e < E) atomicAdd(&deg[dst[e]], 1);
}

__global__ __launch_bounds__(1024) void k_scan(const int* __restrict__ deg,
                                               int* __restrict__ rowp, int N)
{
  __shared__ int part[1024];
  int t = threadIdx.x;
  int chunk = (N + 1023) / 1024;
  int base = t * chunk;
  int s = 0;
  for (int i = 0; i < chunk; i++) { int idx = base + i; if (idx < N) s += deg[idx]; }
  part[t] = s;
  __syncthreads();
  for (int off = 1; off < 1024; off <<= 1) {
    int v = (t >= off) ? part[t - off] : 0;
    __syncthreads();
    part[t] += v;
    __syncthreads();
  }
  int run = part[t] - s;
  for (int i = 0; i < chunk; i++) {
    int idx = base + i;
    if (idx < N) { rowp[idx] = run; run += deg[idx]; }
  }
  if (t == 1023) rowp[N] = part[1023];
}

__global__ void k_fill(const int* __restrict__ src, const int* __restrict__ dst,
                       const int* __restrict__ rowp, int* __restrict__ cursor,
                       int* __restrict__ eids, int* __restrict__ src_perm,
                       int* __restrict__ dst_perm, int E)
{
  int e = blockIdx.x * blockDim.x + threadIdx.x;
  if (e < E) {
    int d = dst[e];
    int pos = atomicAdd(&cursor[d], 1);
    int slot = rowp[d] + pos;
    eids[slot] = e;
    src_perm[slot] = src[e];
    dst_perm[slot] = d;
  }
}

__global__ void k_efperm(const float* __restrict__ e_f, const int* __restrict__ eids,
                         float* __restrict__ ef_perm, int E)
{
  int i = blockIdx.x * blockDim.x + threadIdx.x;
  if (i < E * EF_) {
    int idx = i / EF_, f = i - idx * EF_;
    ef_perm[i] = e_f[(size_t)eids[idx] * EF_ + f];
  }
}

// ---------------------------------------------------------------------------
// Build combined post-message weight WvE.
// ---------------------------------------------------------------------------
__global__ __launch_bounds__(128) void k_wve(
    const float* __restrict__ WvW, const float* __restrict__ WeV,
    unsigned short* __restrict__ WvE)
{
  int ch = blockIdx.x;
  const float* Wv  = WvW + (size_t)ch * 16384;
  const float* wev = WeV + (size_t)ch * EF_ * 128;
  unsigned short* dst = WvE + (size_t)ch * 20480;
  for (int i = threadIdx.x; i < 20480; i += 128) {
    int d = i / 160, k = i - d * 160;
    float v = (k < 128) ? Wv[(size_t)k * 128 + d]
            : (k < 128 + EF_) ? wev[(size_t)(k - 128) * 128 + d] : 0.f;
    dst[i] = f2bf(v);
  }
}

// ---------------------------------------------------------------------------
// Per-node ss = Z.u (UTb bf16: [N][H][2][128] = [u|t]). Wave per (n,h).
// ---------------------------------------------------------------------------
__global__ __launch_bounds__(256) void k_ss(
    const unsigned short* __restrict__ Zb, const unsigned short* __restrict__ UTb,
    float* __restrict__ ss, int N)
{
  int h = threadIdx.x >> 6, lane = threadIdx.x & 63;
  int n = blockIdx.x;
  unsigned uz = *(const unsigned*)(Zb + (size_t)n * 512 + h * 128 + 2 * lane);
  unsigned uu = *(const unsigned*)(UTb + (size_t)n * 1024 + h * 256 + 2 * lane);
  float zx = __uint_as_float(uz << 16), zy = __uint_as_float(uz & 0xffff0000u);
  float ux = __uint_as_float(uu << 16), uy = __uint_as_float(uu & 0xffff0000u);
  float p = zx * ux + zy * uy;
#pragma unroll
  for (int m = 32; m; m >>= 1) p += __shfl_xor(p, m, 64);
  if (lane == 0) ss[n * H_ + h] = p;
}

// ---------------------------------------------------------------------------
// Per-edge precomputed logits: elog[idx][h][6] = {ss_s, se, de, es, ed, ee}
// XCD-swizzled block order for graph-local L2 reuse of BCb.
// ---------------------------------------------------------------------------
__global__ __launch_bounds__(256) void k_elog(
    const unsigned short* __restrict__ BCb, const float* __restrict__ ss,
    const float* __restrict__ M2, const float* __restrict__ ef_perm,
    const int* __restrict__ src_perm, const int* __restrict__ dst_perm,
    float* __restrict__ elog, int E, int layer)
{
  int i0 = xcd_swz(blockIdx.x, gridDim.x) * 64;
  __shared__ float efs[64 * EF_];
  __shared__ float m2s[4 * EF_ * EF_];
  int t = threadIdx.x;
  for (int i = t; i < 64 * EF_; i += 256) {
    int gi = i0 * EF_ + i;
    efs[i] = (gi < E * EF_) ? ef_perm[gi] : 0.f;
  }
  for (int i = t; i < 4 * EF_ * EF_; i += 256)
    m2s[i] = M2[(size_t)layer * 4 * EF_ * EF_ + i];
  __syncthreads();
  int sl = t >> 2, h = t & 3;
  int idx = i0 + sl;
  if (idx < E) {
    int s = src_perm[idx], d = dst_perm[idx];
    const float* ef = &efs[sl * EF_];
    const float* m2 = &m2s[h * EF_ * EF_];
    float ee = 0.f;
#pragma unroll
    for (int a = 0; a < EF_; a++) {
      float r = 0.f;
#pragma unroll
      for (int b = 0; b < EF_; b++) r += m2[a * EF_ + b] * ef[b];
      ee += ef[a] * r;
    }
    const unsigned short* bs = BCb + (size_t)s * 128 + h * 32;
    const unsigned short* bd = BCb + (size_t)d * 128 + h * 32;
    float se = 0.f, es = 0.f, de = 0.f, ed = 0.f;
#pragma unroll
    for (int f = 0; f < EF_; f++) {
      float e = ef[f];
      se += bf2f(bs[f]) * e;
      es += bf2f(bs[EF_ + f]) * e;
      de += bf2f(bd[f]) * e;
      ed += bf2f(bd[EF_ + f]) * e;
    }
    float* o = elog + ((size_t)idx * H_ + h) * 6;
    o[0] = ss[s * H_ + h];
    o[1] = se; o[2] = de; o[3] = es; o[4] = ed; o[5] = ee;
  }
}

// ---------------------------------------------------------------------------
// Edge aggregation: block = dst node (XCD-swizzled), 4 waves = 4 edge slots;
// each wave handles all 4 heads of one edge (1KB contiguous Zb[s] load).
// ---------------------------------------------------------------------------
__global__ __launch_bounds__(256) void k_edge(
    const unsigned short* __restrict__ Zb, const unsigned short* __restrict__ UTb,
    const float* __restrict__ ss, const float* __restrict__ elog,
    const float* __restrict__ ef_perm, const int* __restrict__ rowp,
    const int* __restrict__ src_perm, unsigned short* __restrict__ aggZE, int N)
{
  const int w = threadIdx.x >> 6;      // wave = edge slot
  const int lane = threadIdx.x & 63;
  const int h = lane >> 4;             // head
  const int q = lane & 15;             // d-slice (8 elems)
  const int lb = lane & 48;            // group base = h*16
  const int n = xcd_swz(blockIdx.x, N);

  float zd[8], ud[8], td[8];
  unpack8(*(const uint4*)(Zb + (size_t)n * 512 + lane * 8), zd);
  const unsigned short* utp = UTb + (size_t)n * 1024 + h * 256 + q * 8;
  unpack8(*(const uint4*)(utp), ud);
  unpack8(*(const uint4*)(utp + 128), td);
  const float essd = __expf(ss[n * H_ + h]);
  const int beg = rowp[n], end = rowp[n + 1];
  float acc[8];
#pragma unroll
  for (int i = 0; i < 8; i++) acc[i] = 0.f;
  float wdsum = 0.f, a11 = 0.f;

  for (int idx = beg + w; idx < end; idx += 4) {
    int s = src_perm[idx];
    float zs[8];
    unpack8(*(const uint4*)(Zb + (size_t)s * 512 + lane * 8), zs);
    float v1 = 0.f, v2 = 0.f;
#pragma unroll
    for (int i = 0; i < 8; i++) {
      v1 += zs[i] * ud[i];
      v2 += zs[i] * td[i];
    }
#pragma unroll
    for (int m = 1; m < 16; m <<= 1) {
      v1 += __shfl_xor(v1, m, 64);
      v2 += __shfl_xor(v2, m, 64);
    }
    float lv = (q < 6) ? elog[((size_t)idx * H_ + h) * 6 + q] : 0.f;
    float S00 = __shfl(lv, lb + 0, 64);
    float S02 = __shfl(lv, lb + 1, 64);
    float S12 = __shfl(lv, lb + 2, 64);
    float S20 = __shfl(lv, lb + 3, 64);
    float S21 = __shfl(lv, lb + 4, 64);
    float S22 = __shfl(lv, lb + 5, 64);
    float e00 = __expf(S00), e01 = __expf(v1), e02 = __expf(S02);
    float i0r = 1.f / (e00 + e01 + e02);
    float e10 = __expf(v2), e12 = __expf(S12);
    float i1r = 1.f / (e10 + essd + e12);
    float e20 = __expf(S20), e21 = __expf(S21), e22 = __expf(S22);
    float i2r = 1.f / (e20 + e21 + e22);
    float w0 = e00 * i0r + e10 * i1r + e20 * i2r;
    float w1 = e01 * i0r + essd * i1r + e21 * i2r;
    float w2 = e02 * i0r + e12 * i1r + e22 * i2r;
#pragma unroll
    for (int i = 0; i < 8; i++) acc[i] += w0 * zs[i];
    wdsum += w1;
    float efl = (q < EF_) ? ef_perm[(size_t)idx * EF_ + q] : 0.f;
    a11 += w2 * efl;
  }
  __shared__ float red[4][64][10];
#pragma unroll
  for (int i = 0; i < 8; i++) red[w][lane][i] = acc[i];
  red[w][lane][8] = wdsum;
  red[w][lane][9] = a11;
  __syncthreads();
  if (w == 0) {
    float a[8], wd = 0.f, a1 = 0.f;
#pragma unroll
    for (int i = 0; i < 8; i++)
      a[i] = red[0][lane][i] + red[1][lane][i] + red[2][lane][i] + red[3][lane][i];
    wd = red[0][lane][8] + red[1][lane][8] + red[2][lane][8] + red[3][lane][8];
    a1 = red[0][lane][9] + red[1][lane][9] + red[2][lane][9] + red[3][lane][9];
    int cnt = end - beg;
    float invc = (cnt > 0) ? 1.f / (float)cnt : 1.f;
    unsigned short* ob = aggZE + (size_t)n * 640 + h * 160;
    unsigned short tmp[8];
#pragma unroll
    for (int i = 0; i < 8; i++) tmp[i] = f2bf((a[i] + wd * zd[i]) * invc);
    *(uint4*)(ob + q * 8) = *(const uint4*)&tmp[0];
    ob[128 + q] = (q < EF_) ? f2bf(a1 * invc) : (unsigned short)0;
    ob[144 + q] = 0;
  }
}

// ---------------------------------------------------------------------------
// Segment mean, node-range split 4-way per graph (pre-zeroed output).
// ---------------------------------------------------------------------------
__global__ void k_gmean(const float* __restrict__ X, const int* __restrict__ gid,
                        float* __restrict__ outp, int N, int ld)
{
  int g = blockIdx.x, part = blockIdx.y;
  int lo = 0, hi = N;
  while (lo < hi) { int m = (lo + hi) >> 1; if (gid[m] < g) lo = m + 1; else hi = m; }
  int s0 = lo;
  lo = s0; hi = N;
  while (lo < hi) { int m = (lo + hi) >> 1; if (gid[m] < g + 1) lo = m + 1; else hi = m; }
  int s1 = lo;
  int cnt = s1 - s0;
  float inv = 1.f / (float)(cnt > 0 ? cnt : 1);
  int r0 = s0 + (cnt * part) / 4;
  int r1 = s0 + (cnt * (part + 1)) / 4;
  if (r1 <= r0) return;
  for (int d = threadIdx.x; d < ld; d += blockDim.x) {
    float s = 0.f;
    for (int n = r0; n < r1; n++) s += X[(size_t)n * ld + d];
    atomicAdd(&outp[(size_t)g * ld + d], s * inv);
  }
}

// ---------------------------------------------------------------------------
// GRU recurrent-only pass (input gates precomputed by MFMA).
// ---------------------------------------------------------------------------
__global__ __launch_bounds__(384) void k_gruR(
    const float* __restrict__ gi, const float* __restrict__ Whh,
    const float* __restrict__ bih, const float* __restrict__ bhh,
    float* __restrict__ yout, float* __restrict__ hfinal)
{
  const int g = blockIdx.x, dir = blockIdx.y, t = threadIdx.x;
  const float* W = Whh + (size_t)dir * 128 * 384 + t;
  const float bi = bih[dir * 384 + t];
  const float bh = bhh[dir * 384 + t];
  __shared__ float hb[128];
  __shared__ float rb[128], zb[128], nb[128];
  if (t < 128) hb[t] = 0.f;
  __syncthreads();
  for (int st = 0; st < T_; st++) {
    int ts = dir ? (T_ - 1 - st) : st;
    float acc = bh;
    for (int k = 0; k < 128; k++) acc += hb[k] * W[(size_t)k * 384];
    float gv = gi[((size_t)ts * G_ + g) * 768 + dir * 384 + t] + bi;
    if (t < 128) {
      rb[t] = 1.f / (1.f + __expf(-(gv + acc)));
    } else if (t < 256) {
      zb[t - 128] = 1.f / (1.f + __expf(-(gv + acc)));
    }
    __syncthreads();
    if (t >= 256) nb[t - 256] = tanhf(gv + rb[t - 256] * acc);
    __syncthreads();
    if (t < 128) {
      float z = zb[t];
      float h = (1.f - z) * nb[t] + z * hb[t];
      hb[t] = h;
      if (yout) yout[((size_t)ts * G_ + g) * 256 + dir * 128 + t] = h;
    }
    __syncthreads();
  }
  if (t < 128) hfinal[((size_t)dir * G_ + g) * 128 + t] = hb[t];
}

__global__ void k_final(const float* __restrict__ fp, float* __restrict__ outp, int n)
{
  int i = blockIdx.x * blockDim.x + threadIdx.x;
  if (i < n) {
    outp[i] = fp[i] + fp[G_ * 128 + i] + fp[2 * G_ * 128 + i] + fp[3 * G_ * 128 + i];
  }
}

// ---------------------------------------------------------------------------
extern "C" void kernel_launch(void* const* d_in, const int* in_sizes, int n_in,
                              void* d_out, int out_size, void* d_ws, size_t ws_size,
                              hipStream_t stream)
{
  (void)n_in; (void)ws_size;
  const float* h0   = (const float*)d_in[0];
  const float* e_f  = (const float*)d_in[1];
  const int*   srcI = (const int*)d_in[2];
  const int*   dstI = (const int*)d_in[3];
  const int*   gid  = (const int*)d_in[4];
  const float* lin0 = (const float*)d_in[6];
  const float* linW = (const float*)d_in[7];
  const float* WeW  = (const float*)d_in[8];
  const float* WqW  = (const float*)d_in[9];
  const float* WkW  = (const float*)d_in[10];
  const float* WvW  = (const float*)d_in[11];
  const float* lng  = (const float*)d_in[12];
  const float* lnb  = (const float*)d_in[13];
  const float* outW = (const float*)d_in[14];
  const float* outb = (const float*)d_in[15];
  const float* projW= (const float*)d_in[16];
  const float* projb= (const float*)d_in[17];
  const float* Wih0 = (const float*)d_in[18];
  const float* Whh0 = (const float*)d_in[19];
  const float* bih0 = (const float*)d_in[20];
  const float* bhh0 = (const float*)d_in[21];
  const float* Wih1 = (const float*)d_in[22];
  const float* Whh1 = (const float*)d_in[23];
  const float* bih1 = (const float*)d_in[24];
  const float* bhh1 = (const float*)d_in[25];
  float* outp = (float*)d_out;

  const int N = in_sizes[0] / INF_;
  const int E = in_sizes[2];

  // Workspace ledger (N=20000, E=160000): ~164 MB — keep under 256 MiB.
  char* wp = (char*)d_ws;
  auto alloc = [&](size_t bytes) -> void* {
    void* p = (void*)wp;
    wp += (bytes + 255) & ~(size_t)255;
    return p;
  };
  unsigned short* Zb  = (unsigned short*)alloc((size_t)N * 512 * 2);   // 20.5 MB
  unsigned short* UTb = (unsigned short*)alloc((size_t)N * 1024 * 2);  // 41.0 MB
  unsigned short* BCb = (unsigned short*)alloc((size_t)N * 128 * 2);   //  5.1 MB
  unsigned short* aggZE = (unsigned short*)alloc((size_t)N * 640 * 2); // 25.6 MB
  unsigned short* zh  = (unsigned short*)alloc((size_t)N * 512 * 2);   // 20.5 MB
  float* hcur = (float*)alloc((size_t)N * 128 * 4);                    // 10.2 MB
  float* ssb  = (float*)alloc((size_t)N * H_ * 4);
  float* elog = (float*)alloc((size_t)E * H_ * 6 * 4);                 // 15.4 MB
  float* efp  = (float*)alloc((size_t)E * EF_ * 4);                    //  7.0 MB
  float* WeQ  = (float*)alloc((size_t)C_ * H_ * EF_ * 128 * 4);
  float* WeK  = (float*)alloc((size_t)C_ * H_ * EF_ * 128 * 4);
  float* WeV  = (float*)alloc((size_t)C_ * H_ * EF_ * 128 * 4);
  float* M2   = (float*)alloc((size_t)C_ * H_ * EF_ * EF_ * 4);
  float* GqT  = (float*)alloc((size_t)C_ * H_ * EF_ * 128 * 4);
  float* GcT  = (float*)alloc((size_t)C_ * H_ * EF_ * 128 * 4);
  float* Mbuf = (float*)alloc((size_t)C_ * H_ * 16384 * 4);
  unsigned short* WkPl  = (unsigned short*)alloc((size_t)C_ * H_ * 16384 * 2);
  unsigned short* UTBt  = (unsigned short*)alloc((size_t)C_ * H_ * 2 * 16384 * 2);
  unsigned short* WbcBt = (unsigned short*)alloc((size_t)C_ * 16384 * 2);
  unsigned short* WvE   = (unsigned short*)alloc((size_t)C_ * H_ * 20480 * 2);
  unsigned short* linBt0 = (unsigned short*)alloc((size_t)4 * 128 * INF_ * 2);
  unsigned short* linBt12= (unsigned short*)alloc((size_t)2 * 512 * 128 * 2);
  unsigned short* outBt  = (unsigned short*)alloc((size_t)C_ * 128 * 512 * 2);
  unsigned short* projBt = (unsigned short*)alloc((size_t)128 * INF_ * 2);
  unsigned short* WihBt0 = (unsigned short*)alloc((size_t)768 * 128 * 2);
  unsigned short* WihBt1 = (unsigned short*)alloc((size_t)768 * 256 * 2);
  float* gibuf = (float*)alloc((size_t)T_ * G_ * 768 * 4);             //  6.3 MB
  int* deg    = (int*)alloc((size_t)N * 4);
  int* cursor = (int*)alloc((size_t)N * 4);
  int* rowp   = (int*)alloc((size_t)(N + 1) * 4);
  int* eids   = (int*)alloc((size_t)E * 4);
  int* srcp   = (int*)alloc((size_t)E * 4);
  int* dstp   = (int*)alloc((size_t)E * 4);
  float* gm74 = (float*)alloc((size_t)G_ * INF_ * 4);
  float* seq  = (float*)alloc((size_t)T_ * G_ * 128 * 4);
  float* seq1 = (float*)alloc((size_t)T_ * G_ * 256 * 4);
  float* fparts=(float*)alloc((size_t)4 * G_ * 128 * 4);

  const int gM = (N + 127) / 128;

  // --- CSR build + permuted metadata ---
  hipMemsetAsync(deg, 0, (size_t)N * 4, stream);
  hipMemsetAsync(cursor, 0, (size_t)N * 4, stream);
  hipMemsetAsync(gm74, 0, (size_t)G_ * INF_ * 4, stream);
  hipMemsetAsync(seq, 0, (size_t)T_ * G_ * 128 * 4, stream);
  k_hist<<<(E + 255) / 256, 256, 0, stream>>>(dstI, deg, E);
  k_scan<<<1, 1024, 0, stream>>>(deg, rowp, N);
  k_fill<<<(E + 255) / 256, 256, 0, stream>>>(srcI, dstI, rowp, cursor,
                                              eids, srcp, dstp, E);
  k_efperm<<<(E * EF_ + 255) / 256, 256, 0, stream>>>(e_f, eids, efp, E);

  // --- small weight folding (f-parallel) ---
  k_small1<<<dim3(C_ * H_, EF_), 128, 0, stream>>>(WeW, WqW, WkW, WvW,
                                                   WeQ, WeK, WeV, GqT, GcT);
  k_small2<<<C_ * H_, 128, 0, stream>>>(WeQ, WeK, M2);
  k_wve<<<C_ * H_, 128, 0, stream>>>(WvW, WeV, WvE);
  k_bcfold<<<dim3(C_, 128), 128, 0, stream>>>(lin0, linW, GqT, GcT, WbcBt);

  // --- weight conversions pass 1 ---
  {
    WPack w{};
    int nw = 0;
    auto addw = [&](const float* s, unsigned short* d, int K, int D, int tr) {
      w.d[nw].src = s; w.d[nw].dst = d; w.d[nw].K = K; w.d[nw].D = D;
      w.d[nw].trans = tr; nw++;
    };
    for (int h = 0; h < 4; h++)
      addw(lin0 + (size_t)h * INF_ * 128, linBt0 + (size_t)h * 128 * INF_, INF_, 128, 1);
    for (int j = 1; j < 3; j++)
      for (int h = 0; h < 4; h++)
        addw(linW + ((size_t)(j - 1) * 4 + h) * 16384,
             linBt12 + (size_t)(j - 1) * 65536 + (size_t)h * 16384, 128, 128, 1);
    for (int j = 0; j < 3; j++)
      addw(outW + (size_t)j * 65536, outBt + (size_t)j * 65536, 512, 128, 1);
    addw(projW, projBt, INF_, 128, 1);
    for (int ch = 0; ch < 12; ch++)
      addw(WkW + (size_t)ch * 16384, WkPl + (size_t)ch * 16384, 128, 128, 0);
    for (int dir = 0; dir < 2; dir++) {
      addw(Wih0 + (size_t)dir * 128 * 384, WihBt0 + (size_t)dir * 384 * 128,
           128, 384, 1);
      addw(Wih1 + (size_t)dir * 256 * 384, WihBt1 + (size_t)dir * 384 * 256,
           256, 384, 1);
    }
    k_wcvt<<<dim3(64, nw), 256, 0, stream>>>(w);
  }

  // --- M = Wq @ Wk^T per (layer,head), f32 out ---
  k_mfma<float><<<dim3(1, 1, 12), 256, 0, stream>>>(
      WqW, 128, 16384, 128, 128, WkPl, 0, 16384,
      Mbuf, 128, 0, 16384, nullptr, nullptr, 0, 0, 0);

  // --- UTBt = [M | M^T] bf16 ---
  k_utbt<<<dim3(12, 2), 256, 0, stream>>>(Mbuf, UTBt);

  // --- GRU input t=0: seg-mean(h0) then proj ---
  k_gmean<<<dim3(G_, 4), 128, 0, stream>>>(h0, gid, gm74, N, INF_);
  k_mfma<float><<<dim3(4, 1, 1), 256, 0, stream>>>(
      gm74, INF_, 0, G_, INF_, projBt, 0, 0,
      seq, 128, 0, 0, projb, nullptr, 0, 0, 0);

  // --- conv layers ---
  for (int j = 0; j < C_; j++) {
    const float* Ain = (j == 0) ? h0 : hcur;
    const int Kin = (j == 0) ? INF_ : 128;
    // lin -> Zb bf16 [N][H][128]
    if (j == 0)
      k_mfma<float><<<dim3(gM, 4, 1), 256, 0, stream>>>(
          h0, INF_, 0, N, INF_, linBt0, 128 * INF_, 0,
          nullptr, 0, 0, 0, nullptr, Zb, 512, 128, 0);
    else
      k_mfma<float><<<dim3(gM, 4, 1), 256, 0, stream>>>(
          hcur, 128, 0, N, 128, linBt12 + (size_t)(j - 1) * 65536, 16384, 0,
          nullptr, 0, 0, 0, nullptr, Zb, 512, 128, 0);
    // BCb = Ain @ WbcBt_j -> [N][128] bf16 (packed B/C per head)
    k_mfma<float><<<dim3(gM, 1, 1), 256, 0, stream>>>(
        Ain, Kin, 0, N, Kin, WbcBt + (size_t)j * 16384, 0, 0,
        nullptr, 0, 0, 0, nullptr, BCb, 128, 0, 0);
    // u,t = [M|M^T] Z -> UTb bf16 [N][H][2][128]
    k_mfma<unsigned short><<<dim3(gM, 2, 4), 256, 0, stream>>>(
        Zb, 512, 128, N, 128, UTBt + (size_t)j * 4 * 32768, 16384, 32768,
        nullptr, 0, 0, 0, nullptr, UTb, 1024, 128, 256);
    k_ss<<<N, 256, 0, stream>>>(Zb, UTb, ssb, N);
    k_elog<<<(E + 63) / 64, 256, 0, stream>>>(BCb, ssb, M2, efp, srcp, dstp,
                                              elog, E, j);
    k_edge<<<N, 256, 0, stream>>>(Zb, UTb, ssb, elog, efp, rowp, srcp, aggZE, N);
    // messages + fused ReLU/LN -> zh bf16
    k_mfmaLN<<<dim3(gM, H_), 256, 0, stream>>>(
        aggZE, N, WvE + (size_t)j * 4 * 20480, lng, lnb, j, zh);
    // out GEMM (A = zh bf16)
    k_mfma<unsigned short><<<dim3(gM, 1, 1), 256, 0, stream>>>(
        zh, 512, 0, N, 512, outBt + (size_t)j * 65536, 0, 0,
        hcur, 128, 0, 0, outb + j * 128, nullptr, 0, 0, 0);
    k_gmean<<<dim3(G_, 4), 128, 0, stream>>>(hcur, gid,
                                             seq + (size_t)(j + 1) * G_ * 128, N, 128);
  }

  // --- GRU readout: input gates via MFMA, recurrent via k_gruR ---
  k_mfma<float><<<dim3(16, 6, 1), 256, 0, stream>>>(
      seq, 128, 0, T_ * G_, 128, WihBt0, 128 * 128, 0,
      gibuf, 768, 128, 0, nullptr, nullptr, 0, 0, 0);
  k_gruR<<<dim3(G_, 2), 384, 0, stream>>>(gibuf, Whh0, bih0, bhh0,
                                          seq1, fparts);
  k_mfma<float><<<dim3(16, 6, 1), 256, 0, stream>>>(
      seq1, 256, 0, T_ * G_, 256, WihBt1, 128 * 256, 0,
      gibuf, 768, 128, 0, nullptr, nullptr, 0, 0, 0);
  k_gruR<<<dim3(G_, 2), 384, 0, stream>>>(gibuf, Whh1, bih1, bhh1,
                                          nullptr, fparts + 2 * G_ * 128);
  k_final<<<(out_size + 255) / 256, 256, 0, stream>>>(fparts, outp, out_size);
}